// Round 12
// baseline (569.762 us; speedup 1.0000x reference)
//
#include <hip/hip_runtime.h>
#include <math.h>

#define SB 8192
#define NB 32
#define WC 64
#define NM 16
#define NKC 32   // 2*NM (cos,sin interleaved)
#define NP 24
#define NSC 16   // K-split slices per batch for k_dft
#define LP 132   // padded LDS row length (128 + 4)

// h layout: h[b][ch][s] (s contiguous)
// ws layout (float offsets):
//   h    : 0         (B*W*S = 16777216)
//   T    : 16777216  (S*32  = 262144)
//   xf   : 17039360  (B*W*32 = 65536)
//   of   : 17104896  (B*W*32 = 65536)
//   icaT : 17170432  (128*24 = 3072)
// k_dft partials (32*16*2048 = 1M floats) live in the tc output region (dead until k_final).

__global__ __launch_bounds__(256) void k_table(float* __restrict__ T) {
    int s = blockIdx.x * 256 + threadIdx.x;   // exactly 8192 threads
    float* row = T + (size_t)s * NKC;
    #pragma unroll
    for (int k = 0; k < NM; ++k) {
        int m = (k * s) & (SB - 1);           // exact phase mod S
        double ang = (double)m * (6.283185307179586476925286766559 / (double)SB);
        row[2 * k]     = (float)cos(ang);
        row[2 * k + 1] = (float)sin(ang);
    }
}

// icaT[c][p] = fc2_w[0][c] * ica_w[p][c]
__global__ __launch_bounds__(256) void k_prep(const float* __restrict__ ica_w,
                                              const float* __restrict__ fc2_w,
                                              float* __restrict__ icaT) {
    int tid = blockIdx.x * 256 + threadIdx.x;   // exactly 3072
    int c = tid / NP;
    int p = tid - c * NP;
    icaT[c * NP + p] = ica_w[p * 128 + c] * fc2_w[c];
}

// lift: h[b][w][s] = x[b][s][0]*fc0_w[w][0] + x[b][s][1]*fc0_w[w][1] + fc0_b[w]
__global__ __launch_bounds__(256) void k_lift(const float* __restrict__ x,
                                              const float* __restrict__ fc0_w,
                                              const float* __restrict__ fc0_b,
                                              float* __restrict__ h) {
    int b = blockIdx.y;
    int s = blockIdx.x * 256 + threadIdx.x;
    float2 xv = ((const float2*)x)[(size_t)b * SB + s];
    #pragma unroll
    for (int w = 0; w < WC; ++w) {
        float v = fmaf(xv.x, fc0_w[2 * w], fmaf(xv.y, fc0_w[2 * w + 1], fc0_b[w]));
        h[((size_t)(b * WC + w)) * SB + s] = v;
    }
}

// forward DFT as LDS-staged GEMM (round-5/9 structure, NSC=16).
__global__ __launch_bounds__(256) void k_dft(const float* __restrict__ h,
                                             const float* __restrict__ T,
                                             float* __restrict__ xfp) {
    __shared__ float hT[64][LP];   // 33792 B
    __shared__ float Tt[32][LP];   // 16896 B
    int blk = blockIdx.x;          // b*NSC + sc
    int b  = blk >> 4;
    int sc = blk & (NSC - 1);
    int t  = threadIdx.x;
    int g = t >> 4, j = t & 15;

    float acc[4][2];
    #pragma unroll
    for (int i = 0; i < 4; ++i) { acc[i][0] = 0.f; acc[i][1] = 0.f; }

    const float* hb = h + (size_t)b * WC * SB;
    int ch   = t >> 2;
    int part = t & 3;
    int sl   = t >> 1;
    int jj0  = (t & 1) * 16;

    for (int st = 0; st < 4; ++st) {
        int s_base = sc * 512 + st * 128;

        const float* hrow = hb + (size_t)ch * SB + s_base;
        #pragma unroll
        for (int r = 0; r < 8; ++r) {
            int so = (part + 4 * r) * 4;
            *(float4*)&hT[ch][so] = *(const float4*)(hrow + so);
        }
        {
            const float4* src = (const float4*)(T + (size_t)(s_base + sl) * NKC + jj0);
            float4 a = src[0], c4 = src[1], d = src[2], e = src[3];
            Tt[jj0 +  0][sl] = a.x;  Tt[jj0 +  1][sl] = a.y;
            Tt[jj0 +  2][sl] = a.z;  Tt[jj0 +  3][sl] = a.w;
            Tt[jj0 +  4][sl] = c4.x; Tt[jj0 +  5][sl] = c4.y;
            Tt[jj0 +  6][sl] = c4.z; Tt[jj0 +  7][sl] = c4.w;
            Tt[jj0 +  8][sl] = d.x;  Tt[jj0 +  9][sl] = d.y;
            Tt[jj0 + 10][sl] = d.z;  Tt[jj0 + 11][sl] = d.w;
            Tt[jj0 + 12][sl] = e.x;  Tt[jj0 + 13][sl] = e.y;
            Tt[jj0 + 14][sl] = e.z;  Tt[jj0 + 15][sl] = e.w;
        }
        __syncthreads();

        #pragma unroll 4
        for (int step = 0; step < 32; ++step) {
            int s4 = step * 4;
            float4 ta = *(const float4*)&Tt[j][s4];
            float4 tb = *(const float4*)&Tt[j + 16][s4];
            #pragma unroll
            for (int i = 0; i < 4; ++i) {
                float4 hv = *(const float4*)&hT[g * 4 + i][s4];
                acc[i][0] = fmaf(hv.x, ta.x, fmaf(hv.y, ta.y,
                            fmaf(hv.z, ta.z, fmaf(hv.w, ta.w, acc[i][0]))));
                acc[i][1] = fmaf(hv.x, tb.x, fmaf(hv.y, tb.y,
                            fmaf(hv.z, tb.z, fmaf(hv.w, tb.w, acc[i][1]))));
            }
        }
        __syncthreads();
    }

    float* dst = xfp + ((size_t)(sc * NB + b)) * 2048;
    #pragma unroll
    for (int i = 0; i < 4; ++i) {
        dst[(g * 4 + i) * 32 + j]      = acc[i][0];
        dst[(g * 4 + i) * 32 + j + 16] = acc[i][1];
    }
}

// reduce K-split partials
__global__ __launch_bounds__(256) void k_red(const float* __restrict__ xfp,
                                             float* __restrict__ xf) {
    int idx = blockIdx.x * 256 + threadIdx.x;   // exactly 65536
    int b = idx >> 11;
    int r = idx & 2047;
    float s = 0.f;
    #pragma unroll
    for (int sc = 0; sc < NSC; ++sc)
        s += xfp[((size_t)(sc * NB + b)) * 2048 + r];
    xf[idx] = s;
}

// mode mix: of[b][o][2k] = alpha*Re, of[b][o][2k+1] = -alpha*Im
__global__ __launch_bounds__(256) void k_mix(const float* __restrict__ xf,
                                             const float* __restrict__ wr,
                                             const float* __restrict__ wi,
                                             float* __restrict__ of) {
    int tid = blockIdx.x * 256 + threadIdx.x;   // exactly 32768
    int k = tid & 15;
    int o = (tid >> 4) & 63;
    int b = tid >> 10;
    float orr = 0.f, oii = 0.f;
    const float2* xfb = (const float2*)(xf + (size_t)b * WC * NKC);
    #pragma unroll 4
    for (int i = 0; i < WC; ++i) {
        float2 cs = xfb[i * NM + k];
        float wrv = wr[(i * WC + o) * NM + k];
        float wiv = wi[(i * WC + o) * NM + k];
        orr = fmaf(cs.x, wrv, fmaf(cs.y, wiv, orr));    // xfr*wr - xfi*wi
        oii = fmaf(cs.x, wiv, fmaf(-cs.y, wrv, oii));   // xfr*wi + xfi*wr
    }
    float alpha = (k == 0 ? 1.f : 2.f) / (float)SB;
    float2 res = make_float2(alpha * orr, -alpha * oii);
    ((float2*)of)[(size_t)(b * WC + o) * NM + k] = res;
}

// fused inverse-DFT + pointwise conv + bias + relu, in-place on h
// (round-9 best-known form: full-o LDS weight block + 2-col register blocking).
__global__ __launch_bounds__(256) void k_update(float* __restrict__ h,
                                                const float* __restrict__ T,
                                                const float* __restrict__ of,
                                                const float* __restrict__ pw,
                                                const float* __restrict__ pwb,
                                                int relu) {
    __shared__ float At[96][64];   // 24 KB; At[k][o]
    int b = blockIdx.y;
    int s0 = blockIdx.x * 512 + threadIdx.x;   // second column: s0 + 256

    const float* ofb = of + (size_t)b * WC * NKC;
    for (int e = threadIdx.x; e < 96 * 64; e += 256) {
        int k = e >> 6, o = e & 63;
        At[k][o] = (k < 64) ? pw[o * 64 + k] : ofb[o * 32 + (k - 64)];
    }

    float* hcol0 = h + (size_t)b * WC * SB + s0;
    float* hcol1 = hcol0 + 256;
    float acc0[64], acc1[64];
    #pragma unroll
    for (int o = 0; o < 64; ++o) { acc0[o] = pwb[o]; acc1[o] = pwb[o]; }
    __syncthreads();

    // pointwise part: K = 64, chunks of 8
    for (int kc = 0; kc < 8; ++kc) {
        float xs0[8], xs1[8];
        #pragma unroll
        for (int u = 0; u < 8; ++u) {
            xs0[u] = hcol0[(size_t)(kc * 8 + u) * SB];
            xs1[u] = hcol1[(size_t)(kc * 8 + u) * SB];
        }
        #pragma unroll
        for (int u = 0; u < 8; ++u) {
            const float4* arow = (const float4*)At[kc * 8 + u];
            #pragma unroll
            for (int o4 = 0; o4 < 16; ++o4) {
                float4 a = arow[o4];
                acc0[o4*4+0] = fmaf(a.x, xs0[u], acc0[o4*4+0]);
                acc0[o4*4+1] = fmaf(a.y, xs0[u], acc0[o4*4+1]);
                acc0[o4*4+2] = fmaf(a.z, xs0[u], acc0[o4*4+2]);
                acc0[o4*4+3] = fmaf(a.w, xs0[u], acc0[o4*4+3]);
                acc1[o4*4+0] = fmaf(a.x, xs1[u], acc1[o4*4+0]);
                acc1[o4*4+1] = fmaf(a.y, xs1[u], acc1[o4*4+1]);
                acc1[o4*4+2] = fmaf(a.z, xs1[u], acc1[o4*4+2]);
                acc1[o4*4+3] = fmaf(a.w, xs1[u], acc1[o4*4+3]);
            }
        }
    }
    // inverse-DFT part: K = 32, chunks of 8
    const float4* Trow0 = (const float4*)(T + (size_t)s0 * NKC);
    const float4* Trow1 = (const float4*)(T + (size_t)(s0 + 256) * NKC);
    for (int kc = 0; kc < 4; ++kc) {
        float4 v0 = Trow0[kc * 2], v1 = Trow0[kc * 2 + 1];
        float4 w0 = Trow1[kc * 2], w1v = Trow1[kc * 2 + 1];
        float xs0[8] = {v0.x, v0.y, v0.z, v0.w, v1.x, v1.y, v1.z, v1.w};
        float xs1[8] = {w0.x, w0.y, w0.z, w0.w, w1v.x, w1v.y, w1v.z, w1v.w};
        #pragma unroll
        for (int u = 0; u < 8; ++u) {
            const float4* arow = (const float4*)At[64 + kc * 8 + u];
            #pragma unroll
            for (int o4 = 0; o4 < 16; ++o4) {
                float4 a = arow[o4];
                acc0[o4*4+0] = fmaf(a.x, xs0[u], acc0[o4*4+0]);
                acc0[o4*4+1] = fmaf(a.y, xs0[u], acc0[o4*4+1]);
                acc0[o4*4+2] = fmaf(a.z, xs0[u], acc0[o4*4+2]);
                acc0[o4*4+3] = fmaf(a.w, xs0[u], acc0[o4*4+3]);
                acc1[o4*4+0] = fmaf(a.x, xs1[u], acc1[o4*4+0]);
                acc1[o4*4+1] = fmaf(a.y, xs1[u], acc1[o4*4+1]);
                acc1[o4*4+2] = fmaf(a.z, xs1[u], acc1[o4*4+2]);
                acc1[o4*4+3] = fmaf(a.w, xs1[u], acc1[o4*4+3]);
            }
        }
    }

    #pragma unroll
    for (int o = 0; o < 64; ++o) {
        float v0 = acc0[o], v1 = acc1[o];
        if (relu) { v0 = fmaxf(v0, 0.f); v1 = fmaxf(v1, 0.f); }
        hcol0[(size_t)o * SB] = v0;
        hcol1[(size_t)o * SB] = v1;
    }
}

// final: explicit c-chunk-32 blocking. Declared live set = tv[32]+xs[8]+acc[24]
// (~72 VGPR) so the allocator has no pressure motive to re-chunk; h is
// explicitly re-streamed only 4x (vs compiler's previous 16x re-stream at
// 1.07 GB L2 traffic). Weight rows read c-contiguous (s_load_dwordx8-friendly).
__global__ __launch_bounds__(256) void k_final(const float* __restrict__ h,
                                               const float* __restrict__ fc1_w,
                                               const float* __restrict__ fc1_b,
                                               const float* __restrict__ icaT,
                                               const float* __restrict__ ica_b,
                                               float* __restrict__ out,
                                               float* __restrict__ tc) {
    int b = blockIdx.y;
    int s = blockIdx.x * 256 + threadIdx.x;
    const float* hcol = h + (size_t)b * WC * SB + s;

    float acc[NP];
    #pragma unroll
    for (int p = 0; p < NP; ++p) acc[p] = ica_b[p];

    for (int half = 0; half < 4; ++half) {       // c in chunks of 32
        float tv[32];
        #pragma unroll
        for (int c = 0; c < 32; ++c) tv[c] = fc1_b[half * 32 + c];

        for (int ic = 0; ic < 8; ++ic) {         // i in chunks of 8
            float xs[8];
            #pragma unroll
            for (int u = 0; u < 8; ++u) {
                xs[u] = hcol[(size_t)(ic * 8 + u) * SB];
                asm volatile("" : "+v"(xs[u]));  // discourage load re-execution
            }
            #pragma unroll
            for (int c = 0; c < 32; ++c) {
                const float* w = fc1_w + (half * 32 + c) * WC + ic * 8;  // 8 contiguous
                tv[c] = fmaf(w[0], xs[0],
                        fmaf(w[1], xs[1],
                        fmaf(w[2], xs[2],
                        fmaf(w[3], xs[3],
                        fmaf(w[4], xs[4],
                        fmaf(w[5], xs[5],
                        fmaf(w[6], xs[6],
                        fmaf(w[7], xs[7], tv[c]))))))));
            }
        }

        #pragma unroll
        for (int c = 0; c < 32; ++c) {
            float t = fmaxf(tv[c], 0.f);
            const float* e = icaT + (half * 32 + c) * NP;
            #pragma unroll
            for (int p = 0; p < NP; ++p)
                acc[p] = fmaf(t, e[p], acc[p]);
        }
    }

    float osum = 0.f;
    #pragma unroll
    for (int p = 0; p < NP; ++p) osum += acc[p];
    size_t idx = (size_t)b * SB + s;
    out[idx] = osum;

    float4* t4 = (float4*)(tc + idx * NP);   // 96B stride; wave covers 6KB densely
    t4[0] = make_float4(acc[0],  acc[1],  acc[2],  acc[3]);
    t4[1] = make_float4(acc[4],  acc[5],  acc[6],  acc[7]);
    t4[2] = make_float4(acc[8],  acc[9],  acc[10], acc[11]);
    t4[3] = make_float4(acc[12], acc[13], acc[14], acc[15]);
    t4[4] = make_float4(acc[16], acc[17], acc[18], acc[19]);
    t4[5] = make_float4(acc[20], acc[21], acc[22], acc[23]);
}

extern "C" void kernel_launch(void* const* d_in, const int* in_sizes, int n_in,
                              void* d_out, int out_size, void* d_ws, size_t ws_size,
                              hipStream_t stream) {
    const float* x     = (const float*)d_in[0];
    const float* fc0_w = (const float*)d_in[1];
    const float* fc0_b = (const float*)d_in[2];
    const float* cwr   = (const float*)d_in[3];
    const float* cwi   = (const float*)d_in[4];
    const float* pw_w  = (const float*)d_in[5];
    const float* pw_b  = (const float*)d_in[6];
    const float* fc1_w = (const float*)d_in[7];
    const float* fc1_b = (const float*)d_in[8];
    const float* fc2_w = (const float*)d_in[9];
    const float* ica_w = (const float*)d_in[10];
    const float* ica_b = (const float*)d_in[11];

    float* out = (float*)d_out;            // (B,S,1) = 262144
    float* tc  = out + (size_t)NB * SB;    // (B,S,1,24) = 6291456

    float* ws   = (float*)d_ws;
    float* h    = ws;
    float* T    = ws + 16777216;
    float* xf   = ws + 17039360;
    float* of   = ws + 17104896;
    float* icaT = ws + 17170432;
    float* xfp  = tc;                      // k_dft partials scratch (dead until k_final)

    k_table<<<32, 256, 0, stream>>>(T);
    k_prep<<<12, 256, 0, stream>>>(ica_w, fc2_w, icaT);
    k_lift<<<dim3(32, 32), 256, 0, stream>>>(x, fc0_w, fc0_b, h);

    for (int l = 0; l < 4; ++l) {
        k_dft<<<NB * NSC, 256, 0, stream>>>(h, T, xfp);
        k_red<<<256, 256, 0, stream>>>(xfp, xf);
        k_mix<<<128, 256, 0, stream>>>(xf, cwr + (size_t)l * WC * WC * NM,
                                       cwi + (size_t)l * WC * WC * NM, of);
        k_update<<<dim3(16, 32), 256, 0, stream>>>(h, T, of,
                                                   pw_w + (size_t)l * WC * WC,
                                                   pw_b + (size_t)l * WC,
                                                   (l < 3) ? 1 : 0);
    }

    k_final<<<dim3(32, 32), 256, 0, stream>>>(h, fc1_w, fc1_b, icaT, ica_b, out, tc);
}

// Round 13
// 470.378 us; speedup vs baseline: 1.2113x; 1.2113x over previous
//
#include <hip/hip_runtime.h>
#include <math.h>

#define SB 8192
#define NB 32
#define WC 64
#define NM 16
#define NKC 32   // 2*NM (cos,sin interleaved)
#define NP 24
#define NSC 16   // K-split slices per batch for k_dft
#define LP 132   // padded LDS row length (128 + 4)

// h layout: h[b][ch][s] (s contiguous)
// ws layout (float offsets):
//   h    : 0         (B*W*S = 16777216)
//   T    : 16777216  (S*32  = 262144)
//   xf   : 17039360  (B*W*32 = 65536)
//   ofT  : 17104896  (B*32*W = 65536)   [j][o] transposed mode weights
//   icaT : 17170432  (128*24 = 3072)
//   pwT  : 17173504  (4*64*64 = 16384)  [l][k][o] transposed pointwise weights
// k_dft partials (32*16*2048 = 1M floats) live in the tc output region (dead until k_final).

__global__ __launch_bounds__(256) void k_table(float* __restrict__ T) {
    int s = blockIdx.x * 256 + threadIdx.x;   // exactly 8192 threads
    float* row = T + (size_t)s * NKC;
    #pragma unroll
    for (int k = 0; k < NM; ++k) {
        int m = (k * s) & (SB - 1);           // exact phase mod S
        double ang = (double)m * (6.283185307179586476925286766559 / (double)SB);
        row[2 * k]     = (float)cos(ang);
        row[2 * k + 1] = (float)sin(ang);
    }
}

// icaT[c][p] = fc2_w[0][c] * ica_w[p][c]
__global__ __launch_bounds__(256) void k_prep(const float* __restrict__ ica_w,
                                              const float* __restrict__ fc2_w,
                                              float* __restrict__ icaT) {
    int tid = blockIdx.x * 256 + threadIdx.x;   // exactly 3072
    int c = tid / NP;
    int p = tid - c * NP;
    icaT[c * NP + p] = ica_w[p * 128 + c] * fc2_w[c];
}

// pwT[l][k][o] = pw_w[l][o][k]  (transpose so a wave's 16 o-weights are contiguous)
__global__ __launch_bounds__(256) void k_prepw(const float* __restrict__ pw_w,
                                               float* __restrict__ pwT) {
    int tid = blockIdx.x * 256 + threadIdx.x;   // exactly 16384
    int l = tid >> 12, k = (tid >> 6) & 63, o = tid & 63;
    pwT[tid] = pw_w[(size_t)l * 4096 + o * 64 + k];
}

// lift: h[b][w][s] = x[b][s][0]*fc0_w[w][0] + x[b][s][1]*fc0_w[w][1] + fc0_b[w]
__global__ __launch_bounds__(256) void k_lift(const float* __restrict__ x,
                                              const float* __restrict__ fc0_w,
                                              const float* __restrict__ fc0_b,
                                              float* __restrict__ h) {
    int b = blockIdx.y;
    int s = blockIdx.x * 256 + threadIdx.x;
    float2 xv = ((const float2*)x)[(size_t)b * SB + s];
    #pragma unroll
    for (int w = 0; w < WC; ++w) {
        float v = fmaf(xv.x, fc0_w[2 * w], fmaf(xv.y, fc0_w[2 * w + 1], fc0_b[w]));
        h[((size_t)(b * WC + w)) * SB + s] = v;
    }
}

// forward DFT as LDS-staged GEMM (round-5/9 structure, NSC=16).
__global__ __launch_bounds__(256) void k_dft(const float* __restrict__ h,
                                             const float* __restrict__ T,
                                             float* __restrict__ xfp) {
    __shared__ float hT[64][LP];   // 33792 B
    __shared__ float Tt[32][LP];   // 16896 B
    int blk = blockIdx.x;          // b*NSC + sc
    int b  = blk >> 4;
    int sc = blk & (NSC - 1);
    int t  = threadIdx.x;
    int g = t >> 4, j = t & 15;

    float acc[4][2];
    #pragma unroll
    for (int i = 0; i < 4; ++i) { acc[i][0] = 0.f; acc[i][1] = 0.f; }

    const float* hb = h + (size_t)b * WC * SB;
    int ch   = t >> 2;
    int part = t & 3;
    int sl   = t >> 1;
    int jj0  = (t & 1) * 16;

    for (int st = 0; st < 4; ++st) {
        int s_base = sc * 512 + st * 128;

        const float* hrow = hb + (size_t)ch * SB + s_base;
        #pragma unroll
        for (int r = 0; r < 8; ++r) {
            int so = (part + 4 * r) * 4;
            *(float4*)&hT[ch][so] = *(const float4*)(hrow + so);
        }
        {
            const float4* src = (const float4*)(T + (size_t)(s_base + sl) * NKC + jj0);
            float4 a = src[0], c4 = src[1], d = src[2], e = src[3];
            Tt[jj0 +  0][sl] = a.x;  Tt[jj0 +  1][sl] = a.y;
            Tt[jj0 +  2][sl] = a.z;  Tt[jj0 +  3][sl] = a.w;
            Tt[jj0 +  4][sl] = c4.x; Tt[jj0 +  5][sl] = c4.y;
            Tt[jj0 +  6][sl] = c4.z; Tt[jj0 +  7][sl] = c4.w;
            Tt[jj0 +  8][sl] = d.x;  Tt[jj0 +  9][sl] = d.y;
            Tt[jj0 + 10][sl] = d.z;  Tt[jj0 + 11][sl] = d.w;
            Tt[jj0 + 12][sl] = e.x;  Tt[jj0 + 13][sl] = e.y;
            Tt[jj0 + 14][sl] = e.z;  Tt[jj0 + 15][sl] = e.w;
        }
        __syncthreads();

        #pragma unroll 4
        for (int step = 0; step < 32; ++step) {
            int s4 = step * 4;
            float4 ta = *(const float4*)&Tt[j][s4];
            float4 tb = *(const float4*)&Tt[j + 16][s4];
            #pragma unroll
            for (int i = 0; i < 4; ++i) {
                float4 hv = *(const float4*)&hT[g * 4 + i][s4];
                acc[i][0] = fmaf(hv.x, ta.x, fmaf(hv.y, ta.y,
                            fmaf(hv.z, ta.z, fmaf(hv.w, ta.w, acc[i][0]))));
                acc[i][1] = fmaf(hv.x, tb.x, fmaf(hv.y, tb.y,
                            fmaf(hv.z, tb.z, fmaf(hv.w, tb.w, acc[i][1]))));
            }
        }
        __syncthreads();
    }

    float* dst = xfp + ((size_t)(sc * NB + b)) * 2048;
    #pragma unroll
    for (int i = 0; i < 4; ++i) {
        dst[(g * 4 + i) * 32 + j]      = acc[i][0];
        dst[(g * 4 + i) * 32 + j + 16] = acc[i][1];
    }
}

// reduce K-split partials
__global__ __launch_bounds__(256) void k_red(const float* __restrict__ xfp,
                                             float* __restrict__ xf) {
    int idx = blockIdx.x * 256 + threadIdx.x;   // exactly 65536
    int b = idx >> 11;
    int r = idx & 2047;
    float s = 0.f;
    #pragma unroll
    for (int sc = 0; sc < NSC; ++sc)
        s += xfp[((size_t)(sc * NB + b)) * 2048 + r];
    xf[idx] = s;
}

// mode mix: ofT[b][2k][o] = alpha*Re, ofT[b][2k+1][o] = -alpha*Im  (TRANSPOSED out)
__global__ __launch_bounds__(256) void k_mix(const float* __restrict__ xf,
                                             const float* __restrict__ wr,
                                             const float* __restrict__ wi,
                                             float* __restrict__ ofT) {
    int tid = blockIdx.x * 256 + threadIdx.x;   // exactly 32768
    int k = tid & 15;
    int o = (tid >> 4) & 63;
    int b = tid >> 10;
    float orr = 0.f, oii = 0.f;
    const float2* xfb = (const float2*)(xf + (size_t)b * WC * NKC);
    #pragma unroll 4
    for (int i = 0; i < WC; ++i) {
        float2 cs = xfb[i * NM + k];
        float wrv = wr[(i * WC + o) * NM + k];
        float wiv = wi[(i * WC + o) * NM + k];
        orr = fmaf(cs.x, wrv, fmaf(cs.y, wiv, orr));    // xfr*wr - xfi*wi
        oii = fmaf(cs.x, wiv, fmaf(-cs.y, wrv, oii));   // xfr*wi + xfi*wr
    }
    float alpha = (k == 0 ? 1.f : 2.f) / (float)SB;
    ofT[((size_t)b * NKC + 2 * k) * 64 + o]     = alpha * orr;
    ofT[((size_t)b * NKC + 2 * k + 1) * 64 + o] = -alpha * oii;
}

// fused inverse-DFT + pointwise conv + bias + relu, in-place on h.
// Block = 64 s x all 96 k x all 64 o; wave owns a 16-o group (readfirstlane-uniform).
// Inner: 1 conflict-free ds_read_b32 -> 16 FMAs with SGPR weight operands
// (pwT/ofT are [k][o] so a wave's 16 weights are contiguous uniform s_loads).
// Declared live set acc[16] (~40 VGPR) -> high occupancy, no remat motive.
__global__ __launch_bounds__(256) void k_update(float* __restrict__ h,
                                                const float* __restrict__ T,
                                                const float* __restrict__ ofT,
                                                const float* __restrict__ pwT,
                                                const float* __restrict__ pwb,
                                                int relu) {
    __shared__ float hS[96][68];   // 26112 B: rows 0..63 = h ch, rows 64..95 = T modes
    int t = threadIdx.x;
    int b = blockIdx.y;
    int s0 = blockIdx.x * 64;
    int lane_s = t & 63;
    int g = __builtin_amdgcn_readfirstlane((t >> 6) & 3);
    int ob = g * 16;

    {   // stage h[64 ch][64 s]
        int ch = t >> 2, part = t & 3;
        const float* hrow = h + ((size_t)(b * WC + ch)) * SB + s0;
        #pragma unroll
        for (int r = 0; r < 4; ++r) {
            int so = (part + 4 * r) * 4;
            *(float4*)&hS[ch][so] = *(const float4*)(hrow + so);
        }
    }
    {   // stage T rows transposed: hS[64+j][s] = T[s0+s][j]
        int sl = t >> 2, q = t & 3;
        const float4* src = (const float4*)(T + (size_t)(s0 + sl) * NKC + q * 8);
        float4 a = src[0], c4 = src[1];
        hS[64 + q*8 + 0][sl] = a.x;  hS[64 + q*8 + 1][sl] = a.y;
        hS[64 + q*8 + 2][sl] = a.z;  hS[64 + q*8 + 3][sl] = a.w;
        hS[64 + q*8 + 4][sl] = c4.x; hS[64 + q*8 + 5][sl] = c4.y;
        hS[64 + q*8 + 6][sl] = c4.z; hS[64 + q*8 + 7][sl] = c4.w;
    }
    __syncthreads();

    float acc[16];
    #pragma unroll
    for (int o = 0; o < 16; ++o) acc[o] = pwb[ob + o];

    const float* wbase0 = pwT + ob;                       // [k][64]
    const float* wbase1 = ofT + ((size_t)b * NKC) * 64 + ob;  // [j][64]

    for (int kc = 0; kc < 8; ++kc) {        // pointwise: k = 0..63
        #pragma unroll
        for (int u = 0; u < 8; ++u) {
            int k = kc * 8 + u;
            float hval = hS[k][lane_s];
            const float* w = wbase0 + k * 64;
            #pragma unroll
            for (int o = 0; o < 16; ++o)
                acc[o] = fmaf(w[o], hval, acc[o]);
        }
    }
    for (int kc = 0; kc < 4; ++kc) {        // inverse-DFT: j = 0..31
        #pragma unroll
        for (int u = 0; u < 8; ++u) {
            int j = kc * 8 + u;
            float hval = hS[64 + j][lane_s];
            const float* w = wbase1 + j * 64;
            #pragma unroll
            for (int o = 0; o < 16; ++o)
                acc[o] = fmaf(w[o], hval, acc[o]);
        }
    }

    float* hw = h + (size_t)b * WC * SB + s0 + lane_s;
    #pragma unroll
    for (int o = 0; o < 16; ++o) {
        float v = acc[o];
        if (relu) v = fmaxf(v, 0.f);
        hw[(size_t)(ob + o) * SB] = v;
    }
}

// final (round-9 best-known form): NO LDS — weights via uniform s_load.
__global__ __launch_bounds__(256) void k_final(const float* __restrict__ h,
                                               const float* __restrict__ fc1_w,
                                               const float* __restrict__ fc1_b,
                                               const float* __restrict__ icaT,
                                               const float* __restrict__ ica_b,
                                               float* __restrict__ out,
                                               float* __restrict__ tc) {
    int b = blockIdx.y;
    int s = blockIdx.x * 256 + threadIdx.x;

    float hv[64];
    const float* hcol = h + (size_t)b * WC * SB + s;
    #pragma unroll
    for (int i = 0; i < 64; ++i) hv[i] = hcol[(size_t)i * SB];

    float acc[NP];
    #pragma unroll
    for (int p = 0; p < NP; ++p) acc[p] = ica_b[p];

    for (int cc = 0; cc < 16; ++cc) {
        float tv8[8];
        #pragma unroll
        for (int u = 0; u < 8; ++u) {
            int c = cc * 8 + u;
            float t = fc1_b[c];
            const float* w = fc1_w + c * WC;
            #pragma unroll
            for (int i = 0; i < 64; ++i) t = fmaf(w[i], hv[i], t);
            tv8[u] = fmaxf(t, 0.f);
        }
        #pragma unroll
        for (int u = 0; u < 8; ++u) {
            const float* e = icaT + (cc * 8 + u) * NP;
            #pragma unroll
            for (int p = 0; p < NP; ++p)
                acc[p] = fmaf(tv8[u], e[p], acc[p]);
        }
    }

    float osum = 0.f;
    #pragma unroll
    for (int p = 0; p < NP; ++p) osum += acc[p];
    size_t idx = (size_t)b * SB + s;
    out[idx] = osum;

    float4* t4 = (float4*)(tc + idx * NP);   // 96B stride; wave covers 6KB densely
    t4[0] = make_float4(acc[0],  acc[1],  acc[2],  acc[3]);
    t4[1] = make_float4(acc[4],  acc[5],  acc[6],  acc[7]);
    t4[2] = make_float4(acc[8],  acc[9],  acc[10], acc[11]);
    t4[3] = make_float4(acc[12], acc[13], acc[14], acc[15]);
    t4[4] = make_float4(acc[16], acc[17], acc[18], acc[19]);
    t4[5] = make_float4(acc[20], acc[21], acc[22], acc[23]);
}

extern "C" void kernel_launch(void* const* d_in, const int* in_sizes, int n_in,
                              void* d_out, int out_size, void* d_ws, size_t ws_size,
                              hipStream_t stream) {
    const float* x     = (const float*)d_in[0];
    const float* fc0_w = (const float*)d_in[1];
    const float* fc0_b = (const float*)d_in[2];
    const float* cwr   = (const float*)d_in[3];
    const float* cwi   = (const float*)d_in[4];
    const float* pw_w  = (const float*)d_in[5];
    const float* pw_b  = (const float*)d_in[6];
    const float* fc1_w = (const float*)d_in[7];
    const float* fc1_b = (const float*)d_in[8];
    const float* fc2_w = (const float*)d_in[9];
    const float* ica_w = (const float*)d_in[10];
    const float* ica_b = (const float*)d_in[11];

    float* out = (float*)d_out;            // (B,S,1) = 262144
    float* tc  = out + (size_t)NB * SB;    // (B,S,1,24) = 6291456

    float* ws   = (float*)d_ws;
    float* h    = ws;
    float* T    = ws + 16777216;
    float* xf   = ws + 17039360;
    float* ofT  = ws + 17104896;
    float* icaT = ws + 17170432;
    float* pwT  = ws + 17173504;
    float* xfp  = tc;                      // k_dft partials scratch (dead until k_final)

    k_table<<<32, 256, 0, stream>>>(T);
    k_prep<<<12, 256, 0, stream>>>(ica_w, fc2_w, icaT);
    k_prepw<<<64, 256, 0, stream>>>(pw_w, pwT);
    k_lift<<<dim3(32, 32), 256, 0, stream>>>(x, fc0_w, fc0_b, h);

    for (int l = 0; l < 4; ++l) {
        k_dft<<<NB * NSC, 256, 0, stream>>>(h, T, xfp);
        k_red<<<256, 256, 0, stream>>>(xfp, xf);
        k_mix<<<128, 256, 0, stream>>>(xf, cwr + (size_t)l * WC * WC * NM,
                                       cwi + (size_t)l * WC * WC * NM, ofT);
        k_update<<<dim3(128, 32), 256, 0, stream>>>(h, T, ofT,
                                                    pwT + (size_t)l * 4096,
                                                    pw_b + (size_t)l * WC,
                                                    (l < 3) ? 1 : 0);
    }

    k_final<<<dim3(32, 32), 256, 0, stream>>>(h, fc1_w, fc1_b, icaT, ica_b, out, tc);
}

// Round 14
// 465.068 us; speedup vs baseline: 1.2251x; 1.0114x over previous
//
#include <hip/hip_runtime.h>
#include <math.h>

#define SB 8192
#define NB 32
#define WC 64
#define NM 16
#define NKC 32   // 2*NM (cos,sin interleaved)
#define NP 24
#define NSC 16   // K-split slices per batch for k_dft
#define LP 132   // padded LDS row length (128 + 4)

// h layout: h[b][ch][s] (s contiguous)
// ws layout (float offsets):
//   h    : 0         (B*W*S = 16777216)
//   T    : 16777216  (S*32  = 262144)
//   xf   : 17039360  (B*W*32 = 65536)
//   ofT  : 17104896  (B*32*W = 65536)   [j][o] transposed mode weights
//   icaT : 17170432  (128*24 = 3072)
//   pwT  : 17173504  (4*64*64 = 16384)  [l][k][o] transposed pointwise weights
// k_dft partials (32*16*2048 = 1M floats) live in the tc output region (dead until k_final).

__global__ __launch_bounds__(256) void k_table(float* __restrict__ T) {
    int s = blockIdx.x * 256 + threadIdx.x;   // exactly 8192 threads
    float* row = T + (size_t)s * NKC;
    #pragma unroll
    for (int k = 0; k < NM; ++k) {
        int m = (k * s) & (SB - 1);           // exact phase mod S
        double ang = (double)m * (6.283185307179586476925286766559 / (double)SB);
        row[2 * k]     = (float)cos(ang);
        row[2 * k + 1] = (float)sin(ang);
    }
}

// icaT[c][p] = fc2_w[0][c] * ica_w[p][c]
__global__ __launch_bounds__(256) void k_prep(const float* __restrict__ ica_w,
                                              const float* __restrict__ fc2_w,
                                              float* __restrict__ icaT) {
    int tid = blockIdx.x * 256 + threadIdx.x;   // exactly 3072
    int c = tid / NP;
    int p = tid - c * NP;
    icaT[c * NP + p] = ica_w[p * 128 + c] * fc2_w[c];
}

// pwT[l][k][o] = pw_w[l][o][k]
__global__ __launch_bounds__(256) void k_prepw(const float* __restrict__ pw_w,
                                               float* __restrict__ pwT) {
    int tid = blockIdx.x * 256 + threadIdx.x;   // exactly 16384
    int l = tid >> 12, k = (tid >> 6) & 63, o = tid & 63;
    pwT[tid] = pw_w[(size_t)l * 4096 + o * 64 + k];
}

// lift: h[b][w][s] = x[b][s][0]*fc0_w[w][0] + x[b][s][1]*fc0_w[w][1] + fc0_b[w]
__global__ __launch_bounds__(256) void k_lift(const float* __restrict__ x,
                                              const float* __restrict__ fc0_w,
                                              const float* __restrict__ fc0_b,
                                              float* __restrict__ h) {
    int b = blockIdx.y;
    int s = blockIdx.x * 256 + threadIdx.x;
    float2 xv = ((const float2*)x)[(size_t)b * SB + s];
    #pragma unroll
    for (int w = 0; w < WC; ++w) {
        float v = fmaf(xv.x, fc0_w[2 * w], fmaf(xv.y, fc0_w[2 * w + 1], fc0_b[w]));
        h[((size_t)(b * WC + w)) * SB + s] = v;
    }
}

// forward DFT as LDS-staged GEMM (round-5/9 structure, NSC=16).
__global__ __launch_bounds__(256) void k_dft(const float* __restrict__ h,
                                             const float* __restrict__ T,
                                             float* __restrict__ xfp) {
    __shared__ float hT[64][LP];   // 33792 B
    __shared__ float Tt[32][LP];   // 16896 B
    int blk = blockIdx.x;          // b*NSC + sc
    int b  = blk >> 4;
    int sc = blk & (NSC - 1);
    int t  = threadIdx.x;
    int g = t >> 4, j = t & 15;

    float acc[4][2];
    #pragma unroll
    for (int i = 0; i < 4; ++i) { acc[i][0] = 0.f; acc[i][1] = 0.f; }

    const float* hb = h + (size_t)b * WC * SB;
    int ch   = t >> 2;
    int part = t & 3;
    int sl   = t >> 1;
    int jj0  = (t & 1) * 16;

    for (int st = 0; st < 4; ++st) {
        int s_base = sc * 512 + st * 128;

        const float* hrow = hb + (size_t)ch * SB + s_base;
        #pragma unroll
        for (int r = 0; r < 8; ++r) {
            int so = (part + 4 * r) * 4;
            *(float4*)&hT[ch][so] = *(const float4*)(hrow + so);
        }
        {
            const float4* src = (const float4*)(T + (size_t)(s_base + sl) * NKC + jj0);
            float4 a = src[0], c4 = src[1], d = src[2], e = src[3];
            Tt[jj0 +  0][sl] = a.x;  Tt[jj0 +  1][sl] = a.y;
            Tt[jj0 +  2][sl] = a.z;  Tt[jj0 +  3][sl] = a.w;
            Tt[jj0 +  4][sl] = c4.x; Tt[jj0 +  5][sl] = c4.y;
            Tt[jj0 +  6][sl] = c4.z; Tt[jj0 +  7][sl] = c4.w;
            Tt[jj0 +  8][sl] = d.x;  Tt[jj0 +  9][sl] = d.y;
            Tt[jj0 + 10][sl] = d.z;  Tt[jj0 + 11][sl] = d.w;
            Tt[jj0 + 12][sl] = e.x;  Tt[jj0 + 13][sl] = e.y;
            Tt[jj0 + 14][sl] = e.z;  Tt[jj0 + 15][sl] = e.w;
        }
        __syncthreads();

        #pragma unroll 4
        for (int step = 0; step < 32; ++step) {
            int s4 = step * 4;
            float4 ta = *(const float4*)&Tt[j][s4];
            float4 tb = *(const float4*)&Tt[j + 16][s4];
            #pragma unroll
            for (int i = 0; i < 4; ++i) {
                float4 hv = *(const float4*)&hT[g * 4 + i][s4];
                acc[i][0] = fmaf(hv.x, ta.x, fmaf(hv.y, ta.y,
                            fmaf(hv.z, ta.z, fmaf(hv.w, ta.w, acc[i][0]))));
                acc[i][1] = fmaf(hv.x, tb.x, fmaf(hv.y, tb.y,
                            fmaf(hv.z, tb.z, fmaf(hv.w, tb.w, acc[i][1]))));
            }
        }
        __syncthreads();
    }

    float* dst = xfp + ((size_t)(sc * NB + b)) * 2048;
    #pragma unroll
    for (int i = 0; i < 4; ++i) {
        dst[(g * 4 + i) * 32 + j]      = acc[i][0];
        dst[(g * 4 + i) * 32 + j + 16] = acc[i][1];
    }
}

// reduce K-split partials
__global__ __launch_bounds__(256) void k_red(const float* __restrict__ xfp,
                                             float* __restrict__ xf) {
    int idx = blockIdx.x * 256 + threadIdx.x;   // exactly 65536
    int b = idx >> 11;
    int r = idx & 2047;
    float s = 0.f;
    #pragma unroll
    for (int sc = 0; sc < NSC; ++sc)
        s += xfp[((size_t)(sc * NB + b)) * 2048 + r];
    xf[idx] = s;
}

// mode mix: ofT[b][2k][o] = alpha*Re, ofT[b][2k+1][o] = -alpha*Im  (transposed out)
__global__ __launch_bounds__(256) void k_mix(const float* __restrict__ xf,
                                             const float* __restrict__ wr,
                                             const float* __restrict__ wi,
                                             float* __restrict__ ofT) {
    int tid = blockIdx.x * 256 + threadIdx.x;   // exactly 32768
    int k = tid & 15;
    int o = (tid >> 4) & 63;
    int b = tid >> 10;
    float orr = 0.f, oii = 0.f;
    const float2* xfb = (const float2*)(xf + (size_t)b * WC * NKC);
    #pragma unroll 4
    for (int i = 0; i < WC; ++i) {
        float2 cs = xfb[i * NM + k];
        float wrv = wr[(i * WC + o) * NM + k];
        float wiv = wi[(i * WC + o) * NM + k];
        orr = fmaf(cs.x, wrv, fmaf(cs.y, wiv, orr));    // xfr*wr - xfi*wi
        oii = fmaf(cs.x, wiv, fmaf(-cs.y, wrv, oii));   // xfr*wi + xfi*wr
    }
    float alpha = (k == 0 ? 1.f : 2.f) / (float)SB;
    ofT[((size_t)b * NKC + 2 * k) * 64 + o]     = alpha * orr;
    ofT[((size_t)b * NKC + 2 * k + 1) * 64 + o] = -alpha * oii;
}

// fused inverse-DFT + pointwise conv + bias + relu, in-place on h (round-13 form).
__global__ __launch_bounds__(256) void k_update(float* __restrict__ h,
                                                const float* __restrict__ T,
                                                const float* __restrict__ ofT,
                                                const float* __restrict__ pwT,
                                                const float* __restrict__ pwb,
                                                int relu) {
    __shared__ float hS[96][68];   // 26112 B: rows 0..63 = h ch, rows 64..95 = T modes
    int t = threadIdx.x;
    int b = blockIdx.y;
    int s0 = blockIdx.x * 64;
    int lane_s = t & 63;
    int g = __builtin_amdgcn_readfirstlane((t >> 6) & 3);
    int ob = g * 16;

    {   // stage h[64 ch][64 s]
        int ch = t >> 2, part = t & 3;
        const float* hrow = h + ((size_t)(b * WC + ch)) * SB + s0;
        #pragma unroll
        for (int r = 0; r < 4; ++r) {
            int so = (part + 4 * r) * 4;
            *(float4*)&hS[ch][so] = *(const float4*)(hrow + so);
        }
    }
    {   // stage T rows transposed: hS[64+j][s] = T[s0+s][j]
        int sl = t >> 2, q = t & 3;
        const float4* src = (const float4*)(T + (size_t)(s0 + sl) * NKC + q * 8);
        float4 a = src[0], c4 = src[1];
        hS[64 + q*8 + 0][sl] = a.x;  hS[64 + q*8 + 1][sl] = a.y;
        hS[64 + q*8 + 2][sl] = a.z;  hS[64 + q*8 + 3][sl] = a.w;
        hS[64 + q*8 + 4][sl] = c4.x; hS[64 + q*8 + 5][sl] = c4.y;
        hS[64 + q*8 + 6][sl] = c4.z; hS[64 + q*8 + 7][sl] = c4.w;
    }
    __syncthreads();

    float acc[16];
    #pragma unroll
    for (int o = 0; o < 16; ++o) acc[o] = pwb[ob + o];

    const float* wbase0 = pwT + ob;                       // [k][64]
    const float* wbase1 = ofT + ((size_t)b * NKC) * 64 + ob;  // [j][64]

    for (int kc = 0; kc < 8; ++kc) {        // pointwise: k = 0..63
        #pragma unroll
        for (int u = 0; u < 8; ++u) {
            int k = kc * 8 + u;
            float hval = hS[k][lane_s];
            const float* w = wbase0 + k * 64;
            #pragma unroll
            for (int o = 0; o < 16; ++o)
                acc[o] = fmaf(w[o], hval, acc[o]);
        }
    }
    for (int kc = 0; kc < 4; ++kc) {        // inverse-DFT: j = 0..31
        #pragma unroll
        for (int u = 0; u < 8; ++u) {
            int j = kc * 8 + u;
            float hval = hS[64 + j][lane_s];
            const float* w = wbase1 + j * 64;
            #pragma unroll
            for (int o = 0; o < 16; ++o)
                acc[o] = fmaf(w[o], hval, acc[o]);
        }
    }

    float* hw = h + (size_t)b * WC * SB + s0 + lane_s;
    #pragma unroll
    for (int o = 0; o < 16; ++o) {
        float v = acc[o];
        if (relu) v = fmaxf(v, 0.f);
        hw[(size_t)(ob + o) * SB] = v;
    }
}

// final v2: LDS-staged h tile + c split across waves.
// Block = 64 s; hS[64][68] staged once; wave w owns c in [32w, 32w+32)
// (readfirstlane-uniform -> weight rows are scalar s_loads). Per-c re-reads of h
// come from LDS (cheap, co-issued) instead of the compiler's L2 re-stream.
// Cross-wave combine in the same LDS (union, after barrier); tc written as
// contiguous 1KB bursts.
__global__ __launch_bounds__(256) void k_final(const float* __restrict__ h,
                                               const float* __restrict__ fc1_w,
                                               const float* __restrict__ fc1_b,
                                               const float* __restrict__ icaT,
                                               const float* __restrict__ ica_b,
                                               float* __restrict__ out,
                                               float* __restrict__ tc) {
    __shared__ float u_lds[6144];          // 24.6 KB union: hS[64][68] then red[4][64][24]
    float (*hS)[68] = (float(*)[68])u_lds;
    int t = threadIdx.x;
    int b = blockIdx.y;
    int s0 = blockIdx.x * 64;
    int lane_s = t & 63;
    int wv = __builtin_amdgcn_readfirstlane((t >> 6) & 3);
    int c0 = wv * 32;

    {   // stage h[64 ch][64 s] once
        int ch = t >> 2, part = t & 3;
        const float* hrow = h + ((size_t)(b * WC + ch)) * SB + s0;
        #pragma unroll
        for (int r = 0; r < 4; ++r) {
            int so = (part + 4 * r) * 4;
            *(float4*)&hS[ch][so] = *(const float4*)(hrow + so);
        }
    }
    __syncthreads();

    float acc[NP];
    #pragma unroll
    for (int p = 0; p < NP; ++p) acc[p] = 0.f;

    // c processed in pairs: each LDS value feeds 2 FMAs
    for (int cp = 0; cp < 16; ++cp) {
        int c = c0 + 2 * cp;
        float tv0 = fc1_b[c];
        float tv1 = fc1_b[c + 1];
        const float* w0 = fc1_w + c * WC;
        const float* w1 = w0 + WC;
        for (int ioct = 0; ioct < 8; ++ioct) {
            float xs[8];
            #pragma unroll
            for (int u = 0; u < 8; ++u) xs[u] = hS[ioct * 8 + u][lane_s];
            #pragma unroll
            for (int u = 0; u < 8; ++u) {
                tv0 = fmaf(w0[ioct * 8 + u], xs[u], tv0);
                tv1 = fmaf(w1[ioct * 8 + u], xs[u], tv1);
            }
        }
        tv0 = fmaxf(tv0, 0.f);
        tv1 = fmaxf(tv1, 0.f);
        const float* e0 = icaT + c * NP;
        const float* e1 = e0 + NP;
        #pragma unroll
        for (int p = 0; p < NP; ++p)
            acc[p] = fmaf(tv0, e0[p], fmaf(tv1, e1[p], acc[p]));
    }

    __syncthreads();                        // hS dead; union becomes red[4][64][24]
    #pragma unroll
    for (int p = 0; p < NP; ++p)
        u_lds[((t >> 6) * 64 + lane_s) * NP + p] = acc[p];
    __syncthreads();

    // combine 4 wave-partials; write tc contiguously; stash combined in w=0 slot
    float* tcb = tc + ((size_t)b * SB + s0) * NP;
    #pragma unroll
    for (int r = 0; r < 6; ++r) {
        int e = t + r * 256;                // 0..1535; s = e/24, p = e%24
        int s = e / NP, p = e - s * NP;
        float v = u_lds[s * NP + p] + u_lds[(64 + s) * NP + p]
                + u_lds[(128 + s) * NP + p] + u_lds[(192 + s) * NP + p]
                + ica_b[p];
        tcb[e] = v;
        u_lds[s * NP + p] = v;              // own (s,p): no cross-thread hazard
    }
    __syncthreads();
    if (t < 64) {
        float osum = 0.f;
        #pragma unroll
        for (int p = 0; p < NP; ++p) osum += u_lds[t * NP + p];
        out[(size_t)b * SB + s0 + t] = osum;
    }
}

extern "C" void kernel_launch(void* const* d_in, const int* in_sizes, int n_in,
                              void* d_out, int out_size, void* d_ws, size_t ws_size,
                              hipStream_t stream) {
    const float* x     = (const float*)d_in[0];
    const float* fc0_w = (const float*)d_in[1];
    const float* fc0_b = (const float*)d_in[2];
    const float* cwr   = (const float*)d_in[3];
    const float* cwi   = (const float*)d_in[4];
    const float* pw_w  = (const float*)d_in[5];
    const float* pw_b  = (const float*)d_in[6];
    const float* fc1_w = (const float*)d_in[7];
    const float* fc1_b = (const float*)d_in[8];
    const float* fc2_w = (const float*)d_in[9];
    const float* ica_w = (const float*)d_in[10];
    const float* ica_b = (const float*)d_in[11];

    float* out = (float*)d_out;            // (B,S,1) = 262144
    float* tc  = out + (size_t)NB * SB;    // (B,S,1,24) = 6291456

    float* ws   = (float*)d_ws;
    float* h    = ws;
    float* T    = ws + 16777216;
    float* xf   = ws + 17039360;
    float* ofT  = ws + 17104896;
    float* icaT = ws + 17170432;
    float* pwT  = ws + 17173504;
    float* xfp  = tc;                      // k_dft partials scratch (dead until k_final)

    k_table<<<32, 256, 0, stream>>>(T);
    k_prep<<<12, 256, 0, stream>>>(ica_w, fc2_w, icaT);
    k_prepw<<<64, 256, 0, stream>>>(pw_w, pwT);
    k_lift<<<dim3(32, 32), 256, 0, stream>>>(x, fc0_w, fc0_b, h);

    for (int l = 0; l < 4; ++l) {
        k_dft<<<NB * NSC, 256, 0, stream>>>(h, T, xfp);
        k_red<<<256, 256, 0, stream>>>(xfp, xf);
        k_mix<<<128, 256, 0, stream>>>(xf, cwr + (size_t)l * WC * WC * NM,
                                       cwi + (size_t)l * WC * WC * NM, ofT);
        k_update<<<dim3(128, 32), 256, 0, stream>>>(h, T, ofT,
                                                    pwT + (size_t)l * 4096,
                                                    pw_b + (size_t)l * WC,
                                                    (l < 3) ? 1 : 0);
    }

    k_final<<<dim3(128, 32), 256, 0, stream>>>(h, fc1_w, fc1_b, icaT, ica_b, out, tc);
}

// Round 15
// 459.262 us; speedup vs baseline: 1.2406x; 1.0126x over previous
//
#include <hip/hip_runtime.h>
#include <math.h>

#define SB 8192
#define NB 32
#define WC 64
#define NM 16
#define NKC 32   // 2*NM (cos,sin interleaved)
#define NP 24
#define NSC 16   // K-split slices per batch for k_dft
#define LP 132   // padded LDS row length (128 + 4)

// h layout: h[b][ch][s] (s contiguous)
// ws layout (float offsets):
//   h    : 0         (B*W*S = 16777216)
//   T    : 16777216  (S*32  = 262144)
//   xf   : 17039360  (B*W*32 = 65536)
//   ofT  : 17104896  (B*32*W = 65536)   [j][o] transposed mode weights
//   icaT : 17170432  (128*24 = 3072)
//   pwT  : 17173504  (4*64*64 = 16384)  [l][k][o] transposed pointwise weights
// k_dft partials (32*16*2048 = 1M floats) live in the tc output region (dead until k_final).

__global__ __launch_bounds__(256) void k_table(float* __restrict__ T) {
    int s = blockIdx.x * 256 + threadIdx.x;   // exactly 8192 threads
    float* row = T + (size_t)s * NKC;
    #pragma unroll
    for (int k = 0; k < NM; ++k) {
        int m = (k * s) & (SB - 1);           // exact phase mod S
        double ang = (double)m * (6.283185307179586476925286766559 / (double)SB);
        row[2 * k]     = (float)cos(ang);
        row[2 * k + 1] = (float)sin(ang);
    }
}

// icaT[c][p] = fc2_w[0][c] * ica_w[p][c]
__global__ __launch_bounds__(256) void k_prep(const float* __restrict__ ica_w,
                                              const float* __restrict__ fc2_w,
                                              float* __restrict__ icaT) {
    int tid = blockIdx.x * 256 + threadIdx.x;   // exactly 3072
    int c = tid / NP;
    int p = tid - c * NP;
    icaT[c * NP + p] = ica_w[p * 128 + c] * fc2_w[c];
}

// pwT[l][k][o] = pw_w[l][o][k]
__global__ __launch_bounds__(256) void k_prepw(const float* __restrict__ pw_w,
                                               float* __restrict__ pwT) {
    int tid = blockIdx.x * 256 + threadIdx.x;   // exactly 16384
    int l = tid >> 12, k = (tid >> 6) & 63, o = tid & 63;
    pwT[tid] = pw_w[(size_t)l * 4096 + o * 64 + k];
}

// lift: h[b][w][s] = x[b][s][0]*fc0_w[w][0] + x[b][s][1]*fc0_w[w][1] + fc0_b[w]
__global__ __launch_bounds__(256) void k_lift(const float* __restrict__ x,
                                              const float* __restrict__ fc0_w,
                                              const float* __restrict__ fc0_b,
                                              float* __restrict__ h) {
    int b = blockIdx.y;
    int s = blockIdx.x * 256 + threadIdx.x;
    float2 xv = ((const float2*)x)[(size_t)b * SB + s];
    #pragma unroll
    for (int w = 0; w < WC; ++w) {
        float v = fmaf(xv.x, fc0_w[2 * w], fmaf(xv.y, fc0_w[2 * w + 1], fc0_b[w]));
        h[((size_t)(b * WC + w)) * SB + s] = v;
    }
}

// forward DFT as LDS-staged GEMM (round-5/9 structure, NSC=16).
__global__ __launch_bounds__(256) void k_dft(const float* __restrict__ h,
                                             const float* __restrict__ T,
                                             float* __restrict__ xfp) {
    __shared__ float hT[64][LP];   // 33792 B
    __shared__ float Tt[32][LP];   // 16896 B
    int blk = blockIdx.x;          // b*NSC + sc
    int b  = blk >> 4;
    int sc = blk & (NSC - 1);
    int t  = threadIdx.x;
    int g = t >> 4, j = t & 15;

    float acc[4][2];
    #pragma unroll
    for (int i = 0; i < 4; ++i) { acc[i][0] = 0.f; acc[i][1] = 0.f; }

    const float* hb = h + (size_t)b * WC * SB;
    int ch   = t >> 2;
    int part = t & 3;
    int sl   = t >> 1;
    int jj0  = (t & 1) * 16;

    for (int st = 0; st < 4; ++st) {
        int s_base = sc * 512 + st * 128;

        const float* hrow = hb + (size_t)ch * SB + s_base;
        #pragma unroll
        for (int r = 0; r < 8; ++r) {
            int so = (part + 4 * r) * 4;
            *(float4*)&hT[ch][so] = *(const float4*)(hrow + so);
        }
        {
            const float4* src = (const float4*)(T + (size_t)(s_base + sl) * NKC + jj0);
            float4 a = src[0], c4 = src[1], d = src[2], e = src[3];
            Tt[jj0 +  0][sl] = a.x;  Tt[jj0 +  1][sl] = a.y;
            Tt[jj0 +  2][sl] = a.z;  Tt[jj0 +  3][sl] = a.w;
            Tt[jj0 +  4][sl] = c4.x; Tt[jj0 +  5][sl] = c4.y;
            Tt[jj0 +  6][sl] = c4.z; Tt[jj0 +  7][sl] = c4.w;
            Tt[jj0 +  8][sl] = d.x;  Tt[jj0 +  9][sl] = d.y;
            Tt[jj0 + 10][sl] = d.z;  Tt[jj0 + 11][sl] = d.w;
            Tt[jj0 + 12][sl] = e.x;  Tt[jj0 + 13][sl] = e.y;
            Tt[jj0 + 14][sl] = e.z;  Tt[jj0 + 15][sl] = e.w;
        }
        __syncthreads();

        #pragma unroll 4
        for (int step = 0; step < 32; ++step) {
            int s4 = step * 4;
            float4 ta = *(const float4*)&Tt[j][s4];
            float4 tb = *(const float4*)&Tt[j + 16][s4];
            #pragma unroll
            for (int i = 0; i < 4; ++i) {
                float4 hv = *(const float4*)&hT[g * 4 + i][s4];
                acc[i][0] = fmaf(hv.x, ta.x, fmaf(hv.y, ta.y,
                            fmaf(hv.z, ta.z, fmaf(hv.w, ta.w, acc[i][0]))));
                acc[i][1] = fmaf(hv.x, tb.x, fmaf(hv.y, tb.y,
                            fmaf(hv.z, tb.z, fmaf(hv.w, tb.w, acc[i][1]))));
            }
        }
        __syncthreads();
    }

    float* dst = xfp + ((size_t)(sc * NB + b)) * 2048;
    #pragma unroll
    for (int i = 0; i < 4; ++i) {
        dst[(g * 4 + i) * 32 + j]      = acc[i][0];
        dst[(g * 4 + i) * 32 + j + 16] = acc[i][1];
    }
}

// reduce K-split partials
__global__ __launch_bounds__(256) void k_red(const float* __restrict__ xfp,
                                             float* __restrict__ xf) {
    int idx = blockIdx.x * 256 + threadIdx.x;   // exactly 65536
    int b = idx >> 11;
    int r = idx & 2047;
    float s = 0.f;
    #pragma unroll
    for (int sc = 0; sc < NSC; ++sc)
        s += xfp[((size_t)(sc * NB + b)) * 2048 + r];
    xf[idx] = s;
}

// mode mix: ofT[b][2k][o] = alpha*Re, ofT[b][2k+1][o] = -alpha*Im  (transposed out)
__global__ __launch_bounds__(256) void k_mix(const float* __restrict__ xf,
                                             const float* __restrict__ wr,
                                             const float* __restrict__ wi,
                                             float* __restrict__ ofT) {
    int tid = blockIdx.x * 256 + threadIdx.x;   // exactly 32768
    int k = tid & 15;
    int o = (tid >> 4) & 63;
    int b = tid >> 10;
    float orr = 0.f, oii = 0.f;
    const float2* xfb = (const float2*)(xf + (size_t)b * WC * NKC);
    #pragma unroll 4
    for (int i = 0; i < WC; ++i) {
        float2 cs = xfb[i * NM + k];
        float wrv = wr[(i * WC + o) * NM + k];
        float wiv = wi[(i * WC + o) * NM + k];
        orr = fmaf(cs.x, wrv, fmaf(cs.y, wiv, orr));    // xfr*wr - xfi*wi
        oii = fmaf(cs.x, wiv, fmaf(-cs.y, wrv, oii));   // xfr*wi + xfi*wr
    }
    float alpha = (k == 0 ? 1.f : 2.f) / (float)SB;
    ofT[((size_t)b * NKC + 2 * k) * 64 + o]     = alpha * orr;
    ofT[((size_t)b * NKC + 2 * k + 1) * 64 + o] = -alpha * oii;
}

// fused inverse-DFT + pointwise conv + bias + relu, in-place on h (round-13 form).
__global__ __launch_bounds__(256) void k_update(float* __restrict__ h,
                                                const float* __restrict__ T,
                                                const float* __restrict__ ofT,
                                                const float* __restrict__ pwT,
                                                const float* __restrict__ pwb,
                                                int relu) {
    __shared__ float hS[96][68];   // 26112 B: rows 0..63 = h ch, rows 64..95 = T modes
    int t = threadIdx.x;
    int b = blockIdx.y;
    int s0 = blockIdx.x * 64;
    int lane_s = t & 63;
    int g = __builtin_amdgcn_readfirstlane((t >> 6) & 3);
    int ob = g * 16;

    {   // stage h[64 ch][64 s]
        int ch = t >> 2, part = t & 3;
        const float* hrow = h + ((size_t)(b * WC + ch)) * SB + s0;
        #pragma unroll
        for (int r = 0; r < 4; ++r) {
            int so = (part + 4 * r) * 4;
            *(float4*)&hS[ch][so] = *(const float4*)(hrow + so);
        }
    }
    {   // stage T rows transposed: hS[64+j][s] = T[s0+s][j]
        int sl = t >> 2, q = t & 3;
        const float4* src = (const float4*)(T + (size_t)(s0 + sl) * NKC + q * 8);
        float4 a = src[0], c4 = src[1];
        hS[64 + q*8 + 0][sl] = a.x;  hS[64 + q*8 + 1][sl] = a.y;
        hS[64 + q*8 + 2][sl] = a.z;  hS[64 + q*8 + 3][sl] = a.w;
        hS[64 + q*8 + 4][sl] = c4.x; hS[64 + q*8 + 5][sl] = c4.y;
        hS[64 + q*8 + 6][sl] = c4.z; hS[64 + q*8 + 7][sl] = c4.w;
    }
    __syncthreads();

    float acc[16];
    #pragma unroll
    for (int o = 0; o < 16; ++o) acc[o] = pwb[ob + o];

    const float* wbase0 = pwT + ob;                       // [k][64]
    const float* wbase1 = ofT + ((size_t)b * NKC) * 64 + ob;  // [j][64]

    for (int kc = 0; kc < 8; ++kc) {        // pointwise: k = 0..63
        #pragma unroll
        for (int u = 0; u < 8; ++u) {
            int k = kc * 8 + u;
            float hval = hS[k][lane_s];
            const float* w = wbase0 + k * 64;
            #pragma unroll
            for (int o = 0; o < 16; ++o)
                acc[o] = fmaf(w[o], hval, acc[o]);
        }
    }
    for (int kc = 0; kc < 4; ++kc) {        // inverse-DFT: j = 0..31
        #pragma unroll
        for (int u = 0; u < 8; ++u) {
            int j = kc * 8 + u;
            float hval = hS[64 + j][lane_s];
            const float* w = wbase1 + j * 64;
            #pragma unroll
            for (int o = 0; o < 16; ++o)
                acc[o] = fmaf(w[o], hval, acc[o]);
        }
    }

    float* hw = h + (size_t)b * WC * SB + s0 + lane_s;
    #pragma unroll
    for (int o = 0; o < 16; ++o) {
        float v = acc[o];
        if (relu) v = fmaxf(v, 0.f);
        hw[(size_t)(ob + o) * SB] = v;
    }
}

// final v3: transposed LDS tile hS[s][68] (b128 reads, even bank spread),
// c-quad blocking (each LDS value feeds 4 FMAs; 128 ds_read_b128/thread vs
// 1024 b32), stride-25 reduction layout (odd stride -> conflict-free combine).
__global__ __launch_bounds__(256) void k_final(const float* __restrict__ h,
                                               const float* __restrict__ fc1_w,
                                               const float* __restrict__ fc1_b,
                                               const float* __restrict__ icaT,
                                               const float* __restrict__ ica_b,
                                               float* __restrict__ out,
                                               float* __restrict__ tc) {
    __shared__ float u_lds[6400];          // 25.6 KB: hS[64][68]=4352 then red[4][64][25]=6400
    float (*hS)[68] = (float(*)[68])u_lds;
    int t = threadIdx.x;
    int b = blockIdx.y;
    int s0 = blockIdx.x * 64;
    int lane_s = t & 63;
    int wv = __builtin_amdgcn_readfirstlane(t >> 6);
    int c0 = wv * 32;

    {   // stage transposed: hS[s][ch] = h[ch][s0+s]; global reads coalesced per inst
        int sl = t & 63, chg = t >> 6;
        const float* hb = h + (size_t)b * WC * SB + s0 + sl;
        #pragma unroll
        for (int cc = 0; cc < 16; ++cc) {
            int ch = chg * 16 + cc;
            hS[sl][ch] = hb[(size_t)ch * SB];
        }
    }
    __syncthreads();

    float acc[NP];
    #pragma unroll
    for (int p = 0; p < NP; ++p) acc[p] = 0.f;

    // c in quads: each b128-staged value feeds 4 FMAs
    for (int cq = 0; cq < 8; ++cq) {
        int c = c0 + 4 * cq;
        float tv0 = fc1_b[c], tv1 = fc1_b[c + 1], tv2 = fc1_b[c + 2], tv3 = fc1_b[c + 3];
        const float* w0 = fc1_w + (size_t)c * WC;
        const float* w1 = w0 + WC;
        const float* w2 = w1 + WC;
        const float* w3 = w2 + WC;
        for (int ioct = 0; ioct < 8; ++ioct) {
            float4 xa = *(const float4*)&hS[lane_s][ioct * 8];
            float4 xb = *(const float4*)&hS[lane_s][ioct * 8 + 4];
            float xs[8] = {xa.x, xa.y, xa.z, xa.w, xb.x, xb.y, xb.z, xb.w};
            #pragma unroll
            for (int u = 0; u < 8; ++u) {
                int i = ioct * 8 + u;
                tv0 = fmaf(w0[i], xs[u], tv0);
                tv1 = fmaf(w1[i], xs[u], tv1);
                tv2 = fmaf(w2[i], xs[u], tv2);
                tv3 = fmaf(w3[i], xs[u], tv3);
            }
        }
        tv0 = fmaxf(tv0, 0.f); tv1 = fmaxf(tv1, 0.f);
        tv2 = fmaxf(tv2, 0.f); tv3 = fmaxf(tv3, 0.f);
        const float* e0 = icaT + (size_t)c * NP;
        const float* e1 = e0 + NP;
        const float* e2 = e1 + NP;
        const float* e3 = e2 + NP;
        #pragma unroll
        for (int p = 0; p < NP; ++p)
            acc[p] = fmaf(tv0, e0[p], fmaf(tv1, e1[p],
                     fmaf(tv2, e2[p], fmaf(tv3, e3[p], acc[p]))));
    }

    __syncthreads();                        // hS dead; union becomes red[4][64] stride 25
    {
        float* slot = u_lds + ((t >> 6) * 64 + lane_s) * 25;
        #pragma unroll
        for (int p = 0; p < NP; ++p) slot[p] = acc[p];
    }
    __syncthreads();

    // combine 4 wave-partials; write tc contiguously; stash combined in w=0 slot
    float* tcb = tc + ((size_t)b * SB + s0) * NP;
    #pragma unroll
    for (int r = 0; r < 6; ++r) {
        int e = t + r * 256;                // 0..1535; s = e/24, p = e%24
        int s = e / NP, p = e - s * NP;
        float v = u_lds[s * 25 + p] + u_lds[(64 + s) * 25 + p]
                + u_lds[(128 + s) * 25 + p] + u_lds[(192 + s) * 25 + p]
                + ica_b[p];
        tcb[e] = v;
        u_lds[s * 25 + p] = v;              // own (s,p): no cross-thread hazard
    }
    __syncthreads();
    if (t < 64) {
        float osum = 0.f;
        #pragma unroll
        for (int p = 0; p < NP; ++p) osum += u_lds[t * 25 + p];
        out[(size_t)b * SB + s0 + t] = osum;
    }
}

extern "C" void kernel_launch(void* const* d_in, const int* in_sizes, int n_in,
                              void* d_out, int out_size, void* d_ws, size_t ws_size,
                              hipStream_t stream) {
    const float* x     = (const float*)d_in[0];
    const float* fc0_w = (const float*)d_in[1];
    const float* fc0_b = (const float*)d_in[2];
    const float* cwr   = (const float*)d_in[3];
    const float* cwi   = (const float*)d_in[4];
    const float* pw_w  = (const float*)d_in[5];
    const float* pw_b  = (const float*)d_in[6];
    const float* fc1_w = (const float*)d_in[7];
    const float* fc1_b = (const float*)d_in[8];
    const float* fc2_w = (const float*)d_in[9];
    const float* ica_w = (const float*)d_in[10];
    const float* ica_b = (const float*)d_in[11];

    float* out = (float*)d_out;            // (B,S,1) = 262144
    float* tc  = out + (size_t)NB * SB;    // (B,S,1,24) = 6291456

    float* ws   = (float*)d_ws;
    float* h    = ws;
    float* T    = ws + 16777216;
    float* xf   = ws + 17039360;
    float* ofT  = ws + 17104896;
    float* icaT = ws + 17170432;
    float* pwT  = ws + 17173504;
    float* xfp  = tc;                      // k_dft partials scratch (dead until k_final)

    k_table<<<32, 256, 0, stream>>>(T);
    k_prep<<<12, 256, 0, stream>>>(ica_w, fc2_w, icaT);
    k_prepw<<<64, 256, 0, stream>>>(pw_w, pwT);
    k_lift<<<dim3(32, 32), 256, 0, stream>>>(x, fc0_w, fc0_b, h);

    for (int l = 0; l < 4; ++l) {
        k_dft<<<NB * NSC, 256, 0, stream>>>(h, T, xfp);
        k_red<<<256, 256, 0, stream>>>(xfp, xf);
        k_mix<<<128, 256, 0, stream>>>(xf, cwr + (size_t)l * WC * WC * NM,
                                       cwi + (size_t)l * WC * WC * NM, ofT);
        k_update<<<dim3(128, 32), 256, 0, stream>>>(h, T, ofT,
                                                    pwT + (size_t)l * 4096,
                                                    pw_b + (size_t)l * WC,
                                                    (l < 3) ? 1 : 0);
    }

    k_final<<<dim3(128, 32), 256, 0, stream>>>(h, fc1_w, fc1_b, icaT, ica_b, out, tc);
}

// Round 16
// 443.838 us; speedup vs baseline: 1.2837x; 1.0348x over previous
//
#include <hip/hip_runtime.h>
#include <math.h>

#define SB 8192
#define NB 32
#define WC 64
#define NM 16
#define NKC 32   // 2*NM (cos,sin interleaved)
#define NP 24
#define NSC 16   // K-split slices per batch for k_dft
#define LP 132   // padded LDS row length (128 + 4)

// h layout: h[b][ch][s] (s contiguous)
// ws layout (float offsets):
//   h    : 0         (B*W*S = 16777216)
//   T    : 16777216  (S*32  = 262144)
//   xf   : 17039360  (B*W*32 = 65536)
//   ofT  : 17104896  (B*32*W = 65536)   [j][o] transposed mode weights
//   icaT : 17170432  (128*24 = 3072)
//   pwT  : 17173504  (4*64*64 = 16384)  [l][k][o] transposed pointwise weights
// k_dft partials (32*16*2048 = 1M floats) live in the tc output region (dead until k_final).

__global__ __launch_bounds__(256) void k_table(float* __restrict__ T) {
    int s = blockIdx.x * 256 + threadIdx.x;   // exactly 8192 threads
    float* row = T + (size_t)s * NKC;
    #pragma unroll
    for (int k = 0; k < NM; ++k) {
        int m = (k * s) & (SB - 1);           // exact phase mod S
        double ang = (double)m * (6.283185307179586476925286766559 / (double)SB);
        row[2 * k]     = (float)cos(ang);
        row[2 * k + 1] = (float)sin(ang);
    }
}

// icaT[c][p] = fc2_w[0][c] * ica_w[p][c]
__global__ __launch_bounds__(256) void k_prep(const float* __restrict__ ica_w,
                                              const float* __restrict__ fc2_w,
                                              float* __restrict__ icaT) {
    int tid = blockIdx.x * 256 + threadIdx.x;   // exactly 3072
    int c = tid / NP;
    int p = tid - c * NP;
    icaT[c * NP + p] = ica_w[p * 128 + c] * fc2_w[c];
}

// pwT[l][k][o] = pw_w[l][o][k]
__global__ __launch_bounds__(256) void k_prepw(const float* __restrict__ pw_w,
                                               float* __restrict__ pwT) {
    int tid = blockIdx.x * 256 + threadIdx.x;   // exactly 16384
    int l = tid >> 12, k = (tid >> 6) & 63, o = tid & 63;
    pwT[tid] = pw_w[(size_t)l * 4096 + o * 64 + k];
}

// lift: h[b][w][s] = x[b][s][0]*fc0_w[w][0] + x[b][s][1]*fc0_w[w][1] + fc0_b[w]
__global__ __launch_bounds__(256) void k_lift(const float* __restrict__ x,
                                              const float* __restrict__ fc0_w,
                                              const float* __restrict__ fc0_b,
                                              float* __restrict__ h) {
    int b = blockIdx.y;
    int s = blockIdx.x * 256 + threadIdx.x;
    float2 xv = ((const float2*)x)[(size_t)b * SB + s];
    #pragma unroll
    for (int w = 0; w < WC; ++w) {
        float v = fmaf(xv.x, fc0_w[2 * w], fmaf(xv.y, fc0_w[2 * w + 1], fc0_b[w]));
        h[((size_t)(b * WC + w)) * SB + s] = v;
    }
}

// forward DFT as LDS-staged GEMM (round-5/9 structure, NSC=16).
__global__ __launch_bounds__(256) void k_dft(const float* __restrict__ h,
                                             const float* __restrict__ T,
                                             float* __restrict__ xfp) {
    __shared__ float hT[64][LP];   // 33792 B
    __shared__ float Tt[32][LP];   // 16896 B
    int blk = blockIdx.x;          // b*NSC + sc
    int b  = blk >> 4;
    int sc = blk & (NSC - 1);
    int t  = threadIdx.x;
    int g = t >> 4, j = t & 15;

    float acc[4][2];
    #pragma unroll
    for (int i = 0; i < 4; ++i) { acc[i][0] = 0.f; acc[i][1] = 0.f; }

    const float* hb = h + (size_t)b * WC * SB;
    int ch   = t >> 2;
    int part = t & 3;
    int sl   = t >> 1;
    int jj0  = (t & 1) * 16;

    for (int st = 0; st < 4; ++st) {
        int s_base = sc * 512 + st * 128;

        const float* hrow = hb + (size_t)ch * SB + s_base;
        #pragma unroll
        for (int r = 0; r < 8; ++r) {
            int so = (part + 4 * r) * 4;
            *(float4*)&hT[ch][so] = *(const float4*)(hrow + so);
        }
        {
            const float4* src = (const float4*)(T + (size_t)(s_base + sl) * NKC + jj0);
            float4 a = src[0], c4 = src[1], d = src[2], e = src[3];
            Tt[jj0 +  0][sl] = a.x;  Tt[jj0 +  1][sl] = a.y;
            Tt[jj0 +  2][sl] = a.z;  Tt[jj0 +  3][sl] = a.w;
            Tt[jj0 +  4][sl] = c4.x; Tt[jj0 +  5][sl] = c4.y;
            Tt[jj0 +  6][sl] = c4.z; Tt[jj0 +  7][sl] = c4.w;
            Tt[jj0 +  8][sl] = d.x;  Tt[jj0 +  9][sl] = d.y;
            Tt[jj0 + 10][sl] = d.z;  Tt[jj0 + 11][sl] = d.w;
            Tt[jj0 + 12][sl] = e.x;  Tt[jj0 + 13][sl] = e.y;
            Tt[jj0 + 14][sl] = e.z;  Tt[jj0 + 15][sl] = e.w;
        }
        __syncthreads();

        #pragma unroll 4
        for (int step = 0; step < 32; ++step) {
            int s4 = step * 4;
            float4 ta = *(const float4*)&Tt[j][s4];
            float4 tb = *(const float4*)&Tt[j + 16][s4];
            #pragma unroll
            for (int i = 0; i < 4; ++i) {
                float4 hv = *(const float4*)&hT[g * 4 + i][s4];
                acc[i][0] = fmaf(hv.x, ta.x, fmaf(hv.y, ta.y,
                            fmaf(hv.z, ta.z, fmaf(hv.w, ta.w, acc[i][0]))));
                acc[i][1] = fmaf(hv.x, tb.x, fmaf(hv.y, tb.y,
                            fmaf(hv.z, tb.z, fmaf(hv.w, tb.w, acc[i][1]))));
            }
        }
        __syncthreads();
    }

    float* dst = xfp + ((size_t)(sc * NB + b)) * 2048;
    #pragma unroll
    for (int i = 0; i < 4; ++i) {
        dst[(g * 4 + i) * 32 + j]      = acc[i][0];
        dst[(g * 4 + i) * 32 + j + 16] = acc[i][1];
    }
}

// reduce K-split partials
__global__ __launch_bounds__(256) void k_red(const float* __restrict__ xfp,
                                             float* __restrict__ xf) {
    int idx = blockIdx.x * 256 + threadIdx.x;   // exactly 65536
    int b = idx >> 11;
    int r = idx & 2047;
    float s = 0.f;
    #pragma unroll
    for (int sc = 0; sc < NSC; ++sc)
        s += xfp[((size_t)(sc * NB + b)) * 2048 + r];
    xf[idx] = s;
}

// mode mix: ofT[b][2k][o] = alpha*Re, ofT[b][2k+1][o] = -alpha*Im  (transposed out)
__global__ __launch_bounds__(256) void k_mix(const float* __restrict__ xf,
                                             const float* __restrict__ wr,
                                             const float* __restrict__ wi,
                                             float* __restrict__ ofT) {
    int tid = blockIdx.x * 256 + threadIdx.x;   // exactly 32768
    int k = tid & 15;
    int o = (tid >> 4) & 63;
    int b = tid >> 10;
    float orr = 0.f, oii = 0.f;
    const float2* xfb = (const float2*)(xf + (size_t)b * WC * NKC);
    #pragma unroll 4
    for (int i = 0; i < WC; ++i) {
        float2 cs = xfb[i * NM + k];
        float wrv = wr[(i * WC + o) * NM + k];
        float wiv = wi[(i * WC + o) * NM + k];
        orr = fmaf(cs.x, wrv, fmaf(cs.y, wiv, orr));    // xfr*wr - xfi*wi
        oii = fmaf(cs.x, wiv, fmaf(-cs.y, wrv, oii));   // xfr*wi + xfi*wr
    }
    float alpha = (k == 0 ? 1.f : 2.f) / (float)SB;
    ofT[((size_t)b * NKC + 2 * k) * 64 + o]     = alpha * orr;
    ofT[((size_t)b * NKC + 2 * k + 1) * 64 + o] = -alpha * oii;
}

// fused inverse-DFT + pointwise conv + bias + relu, in-place on h.
// v2: 2-column blocking — block covers 128 s; each scalar weight load
// (s_load_dwordx16, ~200cy L2 latency) now feeds 32 FMAs instead of 16,
// halving the SMEM-latency exposure that kept v1 at ~2x its FMA floor.
// hS[96][132] = 50.7 KB -> 3 blocks/CU; acc0[16]+acc1[16] ~ 45 VGPR.
__global__ __launch_bounds__(256) void k_update(float* __restrict__ h,
                                                const float* __restrict__ T,
                                                const float* __restrict__ ofT,
                                                const float* __restrict__ pwT,
                                                const float* __restrict__ pwb,
                                                int relu) {
    __shared__ float hS[96][LP];   // 50688 B: rows 0..63 = h ch (128 s), 64..95 = T modes
    int t = threadIdx.x;
    int b = blockIdx.y;
    int s0 = blockIdx.x * 128;
    int lane_s = t & 63;
    int g = __builtin_amdgcn_readfirstlane((t >> 6) & 3);
    int ob = g * 16;

    {   // stage h[64 ch][128 s]: 4 threads/row, 8 interleaved b128 each
        int ch = t >> 2, part = t & 3;
        const float* hrow = h + ((size_t)(b * WC + ch)) * SB + s0;
        #pragma unroll
        for (int r = 0; r < 8; ++r) {
            int so = (part + 4 * r) * 4;
            *(float4*)&hS[ch][so] = *(const float4*)(hrow + so);
        }
    }
    {   // stage T transposed: hS[64+j][s] = T[s0+s][j], s in 0..127
        int sl = t >> 1, jj0 = (t & 1) * 16;
        const float4* src = (const float4*)(T + (size_t)(s0 + sl) * NKC + jj0);
        float4 a = src[0], c4 = src[1], d = src[2], e = src[3];
        hS[64 + jj0 +  0][sl] = a.x;  hS[64 + jj0 +  1][sl] = a.y;
        hS[64 + jj0 +  2][sl] = a.z;  hS[64 + jj0 +  3][sl] = a.w;
        hS[64 + jj0 +  4][sl] = c4.x; hS[64 + jj0 +  5][sl] = c4.y;
        hS[64 + jj0 +  6][sl] = c4.z; hS[64 + jj0 +  7][sl] = c4.w;
        hS[64 + jj0 +  8][sl] = d.x;  hS[64 + jj0 +  9][sl] = d.y;
        hS[64 + jj0 + 10][sl] = d.z;  hS[64 + jj0 + 11][sl] = d.w;
        hS[64 + jj0 + 12][sl] = e.x;  hS[64 + jj0 + 13][sl] = e.y;
        hS[64 + jj0 + 14][sl] = e.z;  hS[64 + jj0 + 15][sl] = e.w;
    }
    __syncthreads();

    float acc0[16], acc1[16];
    #pragma unroll
    for (int o = 0; o < 16; ++o) { acc0[o] = pwb[ob + o]; acc1[o] = pwb[ob + o]; }

    const float* wbase0 = pwT + ob;                       // [k][64]
    const float* wbase1 = ofT + ((size_t)b * NKC) * 64 + ob;  // [j][64]

    for (int kc = 0; kc < 8; ++kc) {        // pointwise: k = 0..63
        #pragma unroll
        for (int u = 0; u < 8; ++u) {
            int k = kc * 8 + u;
            float h0 = hS[k][lane_s];
            float h1 = hS[k][64 + lane_s];
            const float* w = wbase0 + k * 64;
            #pragma unroll
            for (int o = 0; o < 16; ++o) {
                acc0[o] = fmaf(w[o], h0, acc0[o]);
                acc1[o] = fmaf(w[o], h1, acc1[o]);
            }
        }
    }
    for (int kc = 0; kc < 4; ++kc) {        // inverse-DFT: j = 0..31
        #pragma unroll
        for (int u = 0; u < 8; ++u) {
            int j = kc * 8 + u;
            float h0 = hS[64 + j][lane_s];
            float h1 = hS[64 + j][64 + lane_s];
            const float* w = wbase1 + j * 64;
            #pragma unroll
            for (int o = 0; o < 16; ++o) {
                acc0[o] = fmaf(w[o], h0, acc0[o]);
                acc1[o] = fmaf(w[o], h1, acc1[o]);
            }
        }
    }

    float* hw0 = h + (size_t)b * WC * SB + s0 + lane_s;
    float* hw1 = hw0 + 64;
    #pragma unroll
    for (int o = 0; o < 16; ++o) {
        float v0 = acc0[o], v1 = acc1[o];
        if (relu) { v0 = fmaxf(v0, 0.f); v1 = fmaxf(v1, 0.f); }
        hw0[(size_t)(ob + o) * SB] = v0;
        hw1[(size_t)(ob + o) * SB] = v1;
    }
}

// final v3: transposed LDS tile hS[s][68] (b128 reads), c-quad blocking,
// stride-25 reduction layout (round-15 form, kept).
__global__ __launch_bounds__(256) void k_final(const float* __restrict__ h,
                                               const float* __restrict__ fc1_w,
                                               const float* __restrict__ fc1_b,
                                               const float* __restrict__ icaT,
                                               const float* __restrict__ ica_b,
                                               float* __restrict__ out,
                                               float* __restrict__ tc) {
    __shared__ float u_lds[6400];          // 25.6 KB: hS[64][68]=4352 then red[4][64][25]=6400
    float (*hS)[68] = (float(*)[68])u_lds;
    int t = threadIdx.x;
    int b = blockIdx.y;
    int s0 = blockIdx.x * 64;
    int lane_s = t & 63;
    int wv = __builtin_amdgcn_readfirstlane(t >> 6);
    int c0 = wv * 32;

    {   // stage transposed: hS[s][ch] = h[ch][s0+s]; global reads coalesced per inst
        int sl = t & 63, chg = t >> 6;
        const float* hb = h + (size_t)b * WC * SB + s0 + sl;
        #pragma unroll
        for (int cc = 0; cc < 16; ++cc) {
            int ch = chg * 16 + cc;
            hS[sl][ch] = hb[(size_t)ch * SB];
        }
    }
    __syncthreads();

    float acc[NP];
    #pragma unroll
    for (int p = 0; p < NP; ++p) acc[p] = 0.f;

    // c in quads: each b128-staged value feeds 4 FMAs
    for (int cq = 0; cq < 8; ++cq) {
        int c = c0 + 4 * cq;
        float tv0 = fc1_b[c], tv1 = fc1_b[c + 1], tv2 = fc1_b[c + 2], tv3 = fc1_b[c + 3];
        const float* w0 = fc1_w + (size_t)c * WC;
        const float* w1 = w0 + WC;
        const float* w2 = w1 + WC;
        const float* w3 = w2 + WC;
        for (int ioct = 0; ioct < 8; ++ioct) {
            float4 xa = *(const float4*)&hS[lane_s][ioct * 8];
            float4 xb = *(const float4*)&hS[lane_s][ioct * 8 + 4];
            float xs[8] = {xa.x, xa.y, xa.z, xa.w, xb.x, xb.y, xb.z, xb.w};
            #pragma unroll
            for (int u = 0; u < 8; ++u) {
                int i = ioct * 8 + u;
                tv0 = fmaf(w0[i], xs[u], tv0);
                tv1 = fmaf(w1[i], xs[u], tv1);
                tv2 = fmaf(w2[i], xs[u], tv2);
                tv3 = fmaf(w3[i], xs[u], tv3);
            }
        }
        tv0 = fmaxf(tv0, 0.f); tv1 = fmaxf(tv1, 0.f);
        tv2 = fmaxf(tv2, 0.f); tv3 = fmaxf(tv3, 0.f);
        const float* e0 = icaT + (size_t)c * NP;
        const float* e1 = e0 + NP;
        const float* e2 = e1 + NP;
        const float* e3 = e2 + NP;
        #pragma unroll
        for (int p = 0; p < NP; ++p)
            acc[p] = fmaf(tv0, e0[p], fmaf(tv1, e1[p],
                     fmaf(tv2, e2[p], fmaf(tv3, e3[p], acc[p]))));
    }

    __syncthreads();                        // hS dead; union becomes red[4][64] stride 25
    {
        float* slot = u_lds + ((t >> 6) * 64 + lane_s) * 25;
        #pragma unroll
        for (int p = 0; p < NP; ++p) slot[p] = acc[p];
    }
    __syncthreads();

    // combine 4 wave-partials; write tc contiguously; stash combined in w=0 slot
    float* tcb = tc + ((size_t)b * SB + s0) * NP;
    #pragma unroll
    for (int r = 0; r < 6; ++r) {
        int e = t + r * 256;                // 0..1535; s = e/24, p = e%24
        int s = e / NP, p = e - s * NP;
        float v = u_lds[s * 25 + p] + u_lds[(64 + s) * 25 + p]
                + u_lds[(128 + s) * 25 + p] + u_lds[(192 + s) * 25 + p]
                + ica_b[p];
        tcb[e] = v;
        u_lds[s * 25 + p] = v;              // own (s,p): no cross-thread hazard
    }
    __syncthreads();
    if (t < 64) {
        float osum = 0.f;
        #pragma unroll
        for (int p = 0; p < NP; ++p) osum += u_lds[t * 25 + p];
        out[(size_t)b * SB + s0 + t] = osum;
    }
}

extern "C" void kernel_launch(void* const* d_in, const int* in_sizes, int n_in,
                              void* d_out, int out_size, void* d_ws, size_t ws_size,
                              hipStream_t stream) {
    const float* x     = (const float*)d_in[0];
    const float* fc0_w = (const float*)d_in[1];
    const float* fc0_b = (const float*)d_in[2];
    const float* cwr   = (const float*)d_in[3];
    const float* cwi   = (const float*)d_in[4];
    const float* pw_w  = (const float*)d_in[5];
    const float* pw_b  = (const float*)d_in[6];
    const float* fc1_w = (const float*)d_in[7];
    const float* fc1_b = (const float*)d_in[8];
    const float* fc2_w = (const float*)d_in[9];
    const float* ica_w = (const float*)d_in[10];
    const float* ica_b = (const float*)d_in[11];

    float* out = (float*)d_out;            // (B,S,1) = 262144
    float* tc  = out + (size_t)NB * SB;    // (B,S,1,24) = 6291456

    float* ws   = (float*)d_ws;
    float* h    = ws;
    float* T    = ws + 16777216;
    float* xf   = ws + 17039360;
    float* ofT  = ws + 17104896;
    float* icaT = ws + 17170432;
    float* pwT  = ws + 17173504;
    float* xfp  = tc;                      // k_dft partials scratch (dead until k_final)

    k_table<<<32, 256, 0, stream>>>(T);
    k_prep<<<12, 256, 0, stream>>>(ica_w, fc2_w, icaT);
    k_prepw<<<64, 256, 0, stream>>>(pw_w, pwT);
    k_lift<<<dim3(32, 32), 256, 0, stream>>>(x, fc0_w, fc0_b, h);

    for (int l = 0; l < 4; ++l) {
        k_dft<<<NB * NSC, 256, 0, stream>>>(h, T, xfp);
        k_red<<<256, 256, 0, stream>>>(xfp, xf);
        k_mix<<<128, 256, 0, stream>>>(xf, cwr + (size_t)l * WC * WC * NM,
                                       cwi + (size_t)l * WC * WC * NM, ofT);
        k_update<<<dim3(64, 32), 256, 0, stream>>>(h, T, ofT,
                                                   pwT + (size_t)l * 4096,
                                                   pw_b + (size_t)l * WC,
                                                   (l < 3) ? 1 : 0);
    }

    k_final<<<dim3(128, 32), 256, 0, stream>>>(h, fc1_w, fc1_b, icaT, ica_b, out, tc);
}

// Round 17
// 434.770 us; speedup vs baseline: 1.3105x; 1.0209x over previous
//
#include <hip/hip_runtime.h>
#include <math.h>

#define SB 8192
#define NB 32
#define WC 64
#define NM 16
#define NKC 32   // 2*NM (cos,sin interleaved)
#define NP 24
#define NSC 16   // K-split slices per batch for k_dft
#define LP 132   // padded LDS row length (128 + 4)

// h layout: h[b][ch][s] (s contiguous)
// ws layout (float offsets):
//   h    : 0         (B*W*S = 16777216)
//   T    : 16777216  (S*32  = 262144)
//   xf   : 17039360  (B*W*32 = 65536)
//   ofT  : 17104896  (B*32*W = 65536)   [j][o] transposed mode weights
//   icaT : 17170432  (128*24 = 3072)
//   pwT  : 17173504  (4*64*64 = 16384)  [l][k][o] transposed pointwise weights
// k_dft partials (32*16*2048 = 1M floats) live in the tc output region (dead until k_final).

__global__ __launch_bounds__(256) void k_table(float* __restrict__ T) {
    int s = blockIdx.x * 256 + threadIdx.x;   // exactly 8192 threads
    float* row = T + (size_t)s * NKC;
    #pragma unroll
    for (int k = 0; k < NM; ++k) {
        int m = (k * s) & (SB - 1);           // exact phase mod S
        double ang = (double)m * (6.283185307179586476925286766559 / (double)SB);
        row[2 * k]     = (float)cos(ang);
        row[2 * k + 1] = (float)sin(ang);
    }
}

// icaT[c][p] = fc2_w[0][c] * ica_w[p][c]
__global__ __launch_bounds__(256) void k_prep(const float* __restrict__ ica_w,
                                              const float* __restrict__ fc2_w,
                                              float* __restrict__ icaT) {
    int tid = blockIdx.x * 256 + threadIdx.x;   // exactly 3072
    int c = tid / NP;
    int p = tid - c * NP;
    icaT[c * NP + p] = ica_w[p * 128 + c] * fc2_w[c];
}

// pwT[l][k][o] = pw_w[l][o][k]
__global__ __launch_bounds__(256) void k_prepw(const float* __restrict__ pw_w,
                                               float* __restrict__ pwT) {
    int tid = blockIdx.x * 256 + threadIdx.x;   // exactly 16384
    int l = tid >> 12, k = (tid >> 6) & 63, o = tid & 63;
    pwT[tid] = pw_w[(size_t)l * 4096 + o * 64 + k];
}

// lift: h[b][w][s] = x[b][s][0]*fc0_w[w][0] + x[b][s][1]*fc0_w[w][1] + fc0_b[w]
__global__ __launch_bounds__(256) void k_lift(const float* __restrict__ x,
                                              const float* __restrict__ fc0_w,
                                              const float* __restrict__ fc0_b,
                                              float* __restrict__ h) {
    int b = blockIdx.y;
    int s = blockIdx.x * 256 + threadIdx.x;
    float2 xv = ((const float2*)x)[(size_t)b * SB + s];
    #pragma unroll
    for (int w = 0; w < WC; ++w) {
        float v = fmaf(xv.x, fc0_w[2 * w], fmaf(xv.y, fc0_w[2 * w + 1], fc0_b[w]));
        h[((size_t)(b * WC + w)) * SB + s] = v;
    }
}

// forward DFT v2: wave owns the FULL 64x32 C-tile (lane = 8 ch-groups x 8
// mode-quads, acc[8][4]); the 4 waves split s and reduce at the end.
// Inner step (1 s): 2 b128 (h) + 1 b128 (T) per 32 FMA = 1.5 B/FMA —
// half the LDS traffic of v1 (which was LDS-BW-bound at ~23us/dispatch).
// hS transposed [s][68] -> 2-way reads (free); Tt natural [s][32] -> j8
// lanes span all 32 banks (conflict-free); reduction rows stride 33.
__global__ __launch_bounds__(256) void k_dft(const float* __restrict__ h,
                                             const float* __restrict__ T,
                                             float* __restrict__ xfp) {
    __shared__ float u[12800];     // 51200 B: hS[128][68]=8704 | Tt[128][32]=4096
    int blk = blockIdx.x;          // b*NSC + sc
    int b  = blk >> 4;
    int sc = blk & (NSC - 1);
    int t  = threadIdx.x;
    int lane = t & 63;
    int wv = __builtin_amdgcn_readfirstlane(t >> 6);   // wave 0..3
    int g  = lane >> 3;            // ch-group 0..7 (ch = g*8+i)
    int j8 = lane & 7;             // mode-quad 0..7 (mode = j8*4+m)

    float acc[8][4];
    #pragma unroll
    for (int i = 0; i < 8; ++i)
        #pragma unroll
        for (int m = 0; m < 4; ++m) acc[i][m] = 0.f;

    int ch_s = t >> 2, part = t & 3;   // staging roles
    const float* hb = h + ((size_t)(b * WC + ch_s)) * SB;

    for (int st = 0; st < 4; ++st) {
        int s_base = sc * 512 + st * 128;

        // stage hS[s][ch] (transposed): b128 ch-major loads, 4-scatter each (2-way writes)
        const float* hrow = hb + s_base;
        #pragma unroll
        for (int r = 0; r < 8; ++r) {
            int so = (part + 4 * r) * 4;
            float4 v = *(const float4*)(hrow + so);
            u[(so + 0) * 68 + ch_s] = v.x;
            u[(so + 1) * 68 + ch_s] = v.y;
            u[(so + 2) * 68 + ch_s] = v.z;
            u[(so + 3) * 68 + ch_s] = v.w;
        }
        // stage Tt[s][32]: straight 16KB copy (layout identical to T)
        {
            const float4* tsrc = (const float4*)(T + (size_t)s_base * NKC);
            float4* tdst = (float4*)(u + 8704);
            #pragma unroll
            for (int r = 0; r < 4; ++r) tdst[t + r * 256] = tsrc[t + r * 256];
        }
        __syncthreads();

        // wave wv computes s in [wv*32, wv*32+32)
        #pragma unroll 4
        for (int ss = 0; ss < 32; ++ss) {
            int s = wv * 32 + ss;
            float4 tv = *(const float4*)&u[8704 + s * 32 + j8 * 4];
            float4 h0 = *(const float4*)&u[s * 68 + g * 8];
            float4 h1 = *(const float4*)&u[s * 68 + g * 8 + 4];
            float hh[8] = {h0.x, h0.y, h0.z, h0.w, h1.x, h1.y, h1.z, h1.w};
            #pragma unroll
            for (int i = 0; i < 8; ++i) {
                acc[i][0] = fmaf(hh[i], tv.x, acc[i][0]);
                acc[i][1] = fmaf(hh[i], tv.y, acc[i][1]);
                acc[i][2] = fmaf(hh[i], tv.z, acc[i][2]);
                acc[i][3] = fmaf(hh[i], tv.w, acc[i][3]);
            }
        }
        __syncthreads();
    }

    // cross-wave reduce: red[wv][lane][v] stride-33 rows (conflict-free writes)
    {
        float* slot = u + (wv * 64 + lane) * 33;
        #pragma unroll
        for (int i = 0; i < 8; ++i)
            #pragma unroll
            for (int m = 0; m < 4; ++m) slot[i * 4 + m] = acc[i][m];
    }
    __syncthreads();

    float* dst = xfp + ((size_t)(sc * NB + b)) * 2048;
    float res[8];
    #pragma unroll
    for (int e = 0; e < 8; ++e) {
        int idx = t * 8 + e;               // C index: ch*32 + mode
        int ch = idx >> 5, mode = idx & 31;
        int g2 = ch >> 3, i2 = ch & 7;
        int q2 = mode >> 2, m2 = mode & 3;
        int lane2 = g2 * 8 + q2;
        int v2 = i2 * 4 + m2;
        res[e] = u[lane2 * 33 + v2] + u[(64 + lane2) * 33 + v2]
               + u[(128 + lane2) * 33 + v2] + u[(192 + lane2) * 33 + v2];
    }
    float4* d4 = (float4*)(dst + t * 8);
    d4[0] = make_float4(res[0], res[1], res[2], res[3]);
    d4[1] = make_float4(res[4], res[5], res[6], res[7]);
}

// reduce K-split partials
__global__ __launch_bounds__(256) void k_red(const float* __restrict__ xfp,
                                             float* __restrict__ xf) {
    int idx = blockIdx.x * 256 + threadIdx.x;   // exactly 65536
    int b = idx >> 11;
    int r = idx & 2047;
    float s = 0.f;
    #pragma unroll
    for (int sc = 0; sc < NSC; ++sc)
        s += xfp[((size_t)(sc * NB + b)) * 2048 + r];
    xf[idx] = s;
}

// mode mix: ofT[b][2k][o] = alpha*Re, ofT[b][2k+1][o] = -alpha*Im  (transposed out)
__global__ __launch_bounds__(256) void k_mix(const float* __restrict__ xf,
                                             const float* __restrict__ wr,
                                             const float* __restrict__ wi,
                                             float* __restrict__ ofT) {
    int tid = blockIdx.x * 256 + threadIdx.x;   // exactly 32768
    int k = tid & 15;
    int o = (tid >> 4) & 63;
    int b = tid >> 10;
    float orr = 0.f, oii = 0.f;
    const float2* xfb = (const float2*)(xf + (size_t)b * WC * NKC);
    #pragma unroll 4
    for (int i = 0; i < WC; ++i) {
        float2 cs = xfb[i * NM + k];
        float wrv = wr[(i * WC + o) * NM + k];
        float wiv = wi[(i * WC + o) * NM + k];
        orr = fmaf(cs.x, wrv, fmaf(cs.y, wiv, orr));    // xfr*wr - xfi*wi
        oii = fmaf(cs.x, wiv, fmaf(-cs.y, wrv, oii));   // xfr*wi + xfi*wr
    }
    float alpha = (k == 0 ? 1.f : 2.f) / (float)SB;
    ofT[((size_t)b * NKC + 2 * k) * 64 + o]     = alpha * orr;
    ofT[((size_t)b * NKC + 2 * k + 1) * 64 + o] = -alpha * oii;
}

// fused inverse-DFT + pointwise conv + bias + relu, in-place on h (round-16 form).
__global__ __launch_bounds__(256) void k_update(float* __restrict__ h,
                                                const float* __restrict__ T,
                                                const float* __restrict__ ofT,
                                                const float* __restrict__ pwT,
                                                const float* __restrict__ pwb,
                                                int relu) {
    __shared__ float hS[96][LP];   // 50688 B: rows 0..63 = h ch (128 s), 64..95 = T modes
    int t = threadIdx.x;
    int b = blockIdx.y;
    int s0 = blockIdx.x * 128;
    int lane_s = t & 63;
    int g = __builtin_amdgcn_readfirstlane((t >> 6) & 3);
    int ob = g * 16;

    {   // stage h[64 ch][128 s]: 4 threads/row, 8 interleaved b128 each
        int ch = t >> 2, part = t & 3;
        const float* hrow = h + ((size_t)(b * WC + ch)) * SB + s0;
        #pragma unroll
        for (int r = 0; r < 8; ++r) {
            int so = (part + 4 * r) * 4;
            *(float4*)&hS[ch][so] = *(const float4*)(hrow + so);
        }
    }
    {   // stage T transposed: hS[64+j][s] = T[s0+s][j], s in 0..127
        int sl = t >> 1, jj0 = (t & 1) * 16;
        const float4* src = (const float4*)(T + (size_t)(s0 + sl) * NKC + jj0);
        float4 a = src[0], c4 = src[1], d = src[2], e = src[3];
        hS[64 + jj0 +  0][sl] = a.x;  hS[64 + jj0 +  1][sl] = a.y;
        hS[64 + jj0 +  2][sl] = a.z;  hS[64 + jj0 +  3][sl] = a.w;
        hS[64 + jj0 +  4][sl] = c4.x; hS[64 + jj0 +  5][sl] = c4.y;
        hS[64 + jj0 +  6][sl] = c4.z; hS[64 + jj0 +  7][sl] = c4.w;
        hS[64 + jj0 +  8][sl] = d.x;  hS[64 + jj0 +  9][sl] = d.y;
        hS[64 + jj0 + 10][sl] = d.z;  hS[64 + jj0 + 11][sl] = d.w;
        hS[64 + jj0 + 12][sl] = e.x;  hS[64 + jj0 + 13][sl] = e.y;
        hS[64 + jj0 + 14][sl] = e.z;  hS[64 + jj0 + 15][sl] = e.w;
    }
    __syncthreads();

    float acc0[16], acc1[16];
    #pragma unroll
    for (int o = 0; o < 16; ++o) { acc0[o] = pwb[ob + o]; acc1[o] = pwb[ob + o]; }

    const float* wbase0 = pwT + ob;                       // [k][64]
    const float* wbase1 = ofT + ((size_t)b * NKC) * 64 + ob;  // [j][64]

    for (int kc = 0; kc < 8; ++kc) {        // pointwise: k = 0..63
        #pragma unroll
        for (int u = 0; u < 8; ++u) {
            int k = kc * 8 + u;
            float h0 = hS[k][lane_s];
            float h1 = hS[k][64 + lane_s];
            const float* w = wbase0 + k * 64;
            #pragma unroll
            for (int o = 0; o < 16; ++o) {
                acc0[o] = fmaf(w[o], h0, acc0[o]);
                acc1[o] = fmaf(w[o], h1, acc1[o]);
            }
        }
    }
    for (int kc = 0; kc < 4; ++kc) {        // inverse-DFT: j = 0..31
        #pragma unroll
        for (int u = 0; u < 8; ++u) {
            int j = kc * 8 + u;
            float h0 = hS[64 + j][lane_s];
            float h1 = hS[64 + j][64 + lane_s];
            const float* w = wbase1 + j * 64;
            #pragma unroll
            for (int o = 0; o < 16; ++o) {
                acc0[o] = fmaf(w[o], h0, acc0[o]);
                acc1[o] = fmaf(w[o], h1, acc1[o]);
            }
        }
    }

    float* hw0 = h + (size_t)b * WC * SB + s0 + lane_s;
    float* hw1 = hw0 + 64;
    #pragma unroll
    for (int o = 0; o < 16; ++o) {
        float v0 = acc0[o], v1 = acc1[o];
        if (relu) { v0 = fmaxf(v0, 0.f); v1 = fmaxf(v1, 0.f); }
        hw0[(size_t)(ob + o) * SB] = v0;
        hw1[(size_t)(ob + o) * SB] = v1;
    }
}

// final v3: transposed LDS tile hS[s][68] (b128 reads), c-quad blocking,
// stride-25 reduction layout (round-15 form, kept).
__global__ __launch_bounds__(256) void k_final(const float* __restrict__ h,
                                               const float* __restrict__ fc1_w,
                                               const float* __restrict__ fc1_b,
                                               const float* __restrict__ icaT,
                                               const float* __restrict__ ica_b,
                                               float* __restrict__ out,
                                               float* __restrict__ tc) {
    __shared__ float u_lds[6400];          // 25.6 KB: hS[64][68]=4352 then red[4][64][25]=6400
    float (*hS)[68] = (float(*)[68])u_lds;
    int t = threadIdx.x;
    int b = blockIdx.y;
    int s0 = blockIdx.x * 64;
    int lane_s = t & 63;
    int wv = __builtin_amdgcn_readfirstlane(t >> 6);
    int c0 = wv * 32;

    {   // stage transposed: hS[s][ch] = h[ch][s0+s]; global reads coalesced per inst
        int sl = t & 63, chg = t >> 6;
        const float* hb = h + (size_t)b * WC * SB + s0 + sl;
        #pragma unroll
        for (int cc = 0; cc < 16; ++cc) {
            int ch = chg * 16 + cc;
            hS[sl][ch] = hb[(size_t)ch * SB];
        }
    }
    __syncthreads();

    float acc[NP];
    #pragma unroll
    for (int p = 0; p < NP; ++p) acc[p] = 0.f;

    // c in quads: each b128-staged value feeds 4 FMAs
    for (int cq = 0; cq < 8; ++cq) {
        int c = c0 + 4 * cq;
        float tv0 = fc1_b[c], tv1 = fc1_b[c + 1], tv2 = fc1_b[c + 2], tv3 = fc1_b[c + 3];
        const float* w0 = fc1_w + (size_t)c * WC;
        const float* w1 = w0 + WC;
        const float* w2 = w1 + WC;
        const float* w3 = w2 + WC;
        for (int ioct = 0; ioct < 8; ++ioct) {
            float4 xa = *(const float4*)&hS[lane_s][ioct * 8];
            float4 xb = *(const float4*)&hS[lane_s][ioct * 8 + 4];
            float xs[8] = {xa.x, xa.y, xa.z, xa.w, xb.x, xb.y, xb.z, xb.w};
            #pragma unroll
            for (int u = 0; u < 8; ++u) {
                int i = ioct * 8 + u;
                tv0 = fmaf(w0[i], xs[u], tv0);
                tv1 = fmaf(w1[i], xs[u], tv1);
                tv2 = fmaf(w2[i], xs[u], tv2);
                tv3 = fmaf(w3[i], xs[u], tv3);
            }
        }
        tv0 = fmaxf(tv0, 0.f); tv1 = fmaxf(tv1, 0.f);
        tv2 = fmaxf(tv2, 0.f); tv3 = fmaxf(tv3, 0.f);
        const float* e0 = icaT + (size_t)c * NP;
        const float* e1 = e0 + NP;
        const float* e2 = e1 + NP;
        const float* e3 = e2 + NP;
        #pragma unroll
        for (int p = 0; p < NP; ++p)
            acc[p] = fmaf(tv0, e0[p], fmaf(tv1, e1[p],
                     fmaf(tv2, e2[p], fmaf(tv3, e3[p], acc[p]))));
    }

    __syncthreads();                        // hS dead; union becomes red[4][64] stride 25
    {
        float* slot = u_lds + ((t >> 6) * 64 + lane_s) * 25;
        #pragma unroll
        for (int p = 0; p < NP; ++p) slot[p] = acc[p];
    }
    __syncthreads();

    // combine 4 wave-partials; write tc contiguously; stash combined in w=0 slot
    float* tcb = tc + ((size_t)b * SB + s0) * NP;
    #pragma unroll
    for (int r = 0; r < 6; ++r) {
        int e = t + r * 256;                // 0..1535; s = e/24, p = e%24
        int s = e / NP, p = e - s * NP;
        float v = u_lds[s * 25 + p] + u_lds[(64 + s) * 25 + p]
                + u_lds[(128 + s) * 25 + p] + u_lds[(192 + s) * 25 + p]
                + ica_b[p];
        tcb[e] = v;
        u_lds[s * 25 + p] = v;              // own (s,p): no cross-thread hazard
    }
    __syncthreads();
    if (t < 64) {
        float osum = 0.f;
        #pragma unroll
        for (int p = 0; p < NP; ++p) osum += u_lds[t * 25 + p];
        out[(size_t)b * SB + s0 + t] = osum;
    }
}

extern "C" void kernel_launch(void* const* d_in, const int* in_sizes, int n_in,
                              void* d_out, int out_size, void* d_ws, size_t ws_size,
                              hipStream_t stream) {
    const float* x     = (const float*)d_in[0];
    const float* fc0_w = (const float*)d_in[1];
    const float* fc0_b = (const float*)d_in[2];
    const float* cwr   = (const float*)d_in[3];
    const float* cwi   = (const float*)d_in[4];
    const float* pw_w  = (const float*)d_in[5];
    const float* pw_b  = (const float*)d_in[6];
    const float* fc1_w = (const float*)d_in[7];
    const float* fc1_b = (const float*)d_in[8];
    const float* fc2_w = (const float*)d_in[9];
    const float* ica_w = (const float*)d_in[10];
    const float* ica_b = (const float*)d_in[11];

    float* out = (float*)d_out;            // (B,S,1) = 262144
    float* tc  = out + (size_t)NB * SB;    // (B,S,1,24) = 6291456

    float* ws   = (float*)d_ws;
    float* h    = ws;
    float* T    = ws + 16777216;
    float* xf   = ws + 17039360;
    float* ofT  = ws + 17104896;
    float* icaT = ws + 17170432;
    float* pwT  = ws + 17173504;
    float* xfp  = tc;                      // k_dft partials scratch (dead until k_final)

    k_table<<<32, 256, 0, stream>>>(T);
    k_prep<<<12, 256, 0, stream>>>(ica_w, fc2_w, icaT);
    k_prepw<<<64, 256, 0, stream>>>(pw_w, pwT);
    k_lift<<<dim3(32, 32), 256, 0, stream>>>(x, fc0_w, fc0_b, h);

    for (int l = 0; l < 4; ++l) {
        k_dft<<<NB * NSC, 256, 0, stream>>>(h, T, xfp);
        k_red<<<256, 256, 0, stream>>>(xfp, xf);
        k_mix<<<128, 256, 0, stream>>>(xf, cwr + (size_t)l * WC * WC * NM,
                                       cwi + (size_t)l * WC * WC * NM, ofT);
        k_update<<<dim3(64, 32), 256, 0, stream>>>(h, T, ofT,
                                                   pwT + (size_t)l * 4096,
                                                   pw_b + (size_t)l * WC,
                                                   (l < 3) ? 1 : 0);
    }

    k_final<<<dim3(128, 32), 256, 0, stream>>>(h, fc1_w, fc1_b, icaT, ica_b, out, tc);
}

// Round 18
// 425.817 us; speedup vs baseline: 1.3380x; 1.0210x over previous
//
#include <hip/hip_runtime.h>
#include <math.h>

#define SB 8192
#define NB 32
#define WC 64
#define NM 16
#define NKC 32   // 2*NM (cos,sin interleaved)
#define NP 24
#define NSC 16   // K-split slices for layer-0 k_dft
#define LP 132   // padded LDS row length (128 + 4)

// h layout: h[b][ch][s] (s contiguous)
// ws layout (float offsets):
//   h    : 0         (B*W*S = 16777216)
//   T    : 16777216  (S*32  = 262144)
//   xf   : 17039360  (B*W*32 = 65536)
//   ofT  : 17104896  (B*32*W = 65536)   [j][o] transposed mode weights
//   icaT : 17170432  (128*24 = 3072)
//   pwT  : 17173504  (4*64*64 = 16384)  [l][k][o] transposed pointwise weights
// DFT partials live in the tc output region (dead until k_final):
//   layer 0: 16 slices (k_dft), layers 1-3: 64 slices (fused in k_update).

__global__ __launch_bounds__(256) void k_table(float* __restrict__ T) {
    int s = blockIdx.x * 256 + threadIdx.x;   // exactly 8192 threads
    float* row = T + (size_t)s * NKC;
    #pragma unroll
    for (int k = 0; k < NM; ++k) {
        int m = (k * s) & (SB - 1);           // exact phase mod S
        double ang = (double)m * (6.283185307179586476925286766559 / (double)SB);
        row[2 * k]     = (float)cos(ang);
        row[2 * k + 1] = (float)sin(ang);
    }
}

// icaT[c][p] = fc2_w[0][c] * ica_w[p][c]
__global__ __launch_bounds__(256) void k_prep(const float* __restrict__ ica_w,
                                              const float* __restrict__ fc2_w,
                                              float* __restrict__ icaT) {
    int tid = blockIdx.x * 256 + threadIdx.x;   // exactly 3072
    int c = tid / NP;
    int p = tid - c * NP;
    icaT[c * NP + p] = ica_w[p * 128 + c] * fc2_w[c];
}

// pwT[l][k][o] = pw_w[l][o][k]
__global__ __launch_bounds__(256) void k_prepw(const float* __restrict__ pw_w,
                                               float* __restrict__ pwT) {
    int tid = blockIdx.x * 256 + threadIdx.x;   // exactly 16384
    int l = tid >> 12, k = (tid >> 6) & 63, o = tid & 63;
    pwT[tid] = pw_w[(size_t)l * 4096 + o * 64 + k];
}

// lift: h[b][w][s] = x[b][s][0]*fc0_w[w][0] + x[b][s][1]*fc0_w[w][1] + fc0_b[w]
__global__ __launch_bounds__(256) void k_lift(const float* __restrict__ x,
                                              const float* __restrict__ fc0_w,
                                              const float* __restrict__ fc0_b,
                                              float* __restrict__ h) {
    int b = blockIdx.y;
    int s = blockIdx.x * 256 + threadIdx.x;
    float2 xv = ((const float2*)x)[(size_t)b * SB + s];
    #pragma unroll
    for (int w = 0; w < WC; ++w) {
        float v = fmaf(xv.x, fc0_w[2 * w], fmaf(xv.y, fc0_w[2 * w + 1], fc0_b[w]));
        h[((size_t)(b * WC + w)) * SB + s] = v;
    }
}

// forward DFT v2 (round-17 form) — used only for layer 0 (lift output).
__global__ __launch_bounds__(256) void k_dft(const float* __restrict__ h,
                                             const float* __restrict__ T,
                                             float* __restrict__ xfp) {
    __shared__ float u[12800];     // 51200 B: hS[128][68]=8704 | Tt[128][32]=4096
    int blk = blockIdx.x;          // b*NSC + sc
    int b  = blk >> 4;
    int sc = blk & (NSC - 1);
    int t  = threadIdx.x;
    int lane = t & 63;
    int wv = __builtin_amdgcn_readfirstlane(t >> 6);   // wave 0..3
    int g  = lane >> 3;            // ch-group 0..7 (ch = g*8+i)
    int j8 = lane & 7;             // mode-quad 0..7 (mode = j8*4+m)

    float acc[8][4];
    #pragma unroll
    for (int i = 0; i < 8; ++i)
        #pragma unroll
        for (int m = 0; m < 4; ++m) acc[i][m] = 0.f;

    int ch_s = t >> 2, part = t & 3;   // staging roles
    const float* hb = h + ((size_t)(b * WC + ch_s)) * SB;

    for (int st = 0; st < 4; ++st) {
        int s_base = sc * 512 + st * 128;

        const float* hrow = hb + s_base;
        #pragma unroll
        for (int r = 0; r < 8; ++r) {
            int so = (part + 4 * r) * 4;
            float4 v = *(const float4*)(hrow + so);
            u[(so + 0) * 68 + ch_s] = v.x;
            u[(so + 1) * 68 + ch_s] = v.y;
            u[(so + 2) * 68 + ch_s] = v.z;
            u[(so + 3) * 68 + ch_s] = v.w;
        }
        {
            const float4* tsrc = (const float4*)(T + (size_t)s_base * NKC);
            float4* tdst = (float4*)(u + 8704);
            #pragma unroll
            for (int r = 0; r < 4; ++r) tdst[t + r * 256] = tsrc[t + r * 256];
        }
        __syncthreads();

        #pragma unroll 4
        for (int ss = 0; ss < 32; ++ss) {
            int s = wv * 32 + ss;
            float4 tv = *(const float4*)&u[8704 + s * 32 + j8 * 4];
            float4 h0 = *(const float4*)&u[s * 68 + g * 8];
            float4 h1 = *(const float4*)&u[s * 68 + g * 8 + 4];
            float hh[8] = {h0.x, h0.y, h0.z, h0.w, h1.x, h1.y, h1.z, h1.w};
            #pragma unroll
            for (int i = 0; i < 8; ++i) {
                acc[i][0] = fmaf(hh[i], tv.x, acc[i][0]);
                acc[i][1] = fmaf(hh[i], tv.y, acc[i][1]);
                acc[i][2] = fmaf(hh[i], tv.z, acc[i][2]);
                acc[i][3] = fmaf(hh[i], tv.w, acc[i][3]);
            }
        }
        __syncthreads();
    }

    {
        float* slot = u + (wv * 64 + lane) * 33;
        #pragma unroll
        for (int i = 0; i < 8; ++i)
            #pragma unroll
            for (int m = 0; m < 4; ++m) slot[i * 4 + m] = acc[i][m];
    }
    __syncthreads();

    float* dst = xfp + ((size_t)(sc * NB + b)) * 2048;
    float res[8];
    #pragma unroll
    for (int e = 0; e < 8; ++e) {
        int idx = t * 8 + e;
        int ch = idx >> 5, mode = idx & 31;
        int g2 = ch >> 3, i2 = ch & 7;
        int q2 = mode >> 2, m2 = mode & 3;
        int lane2 = g2 * 8 + q2;
        int v2 = i2 * 4 + m2;
        res[e] = u[lane2 * 33 + v2] + u[(64 + lane2) * 33 + v2]
               + u[(128 + lane2) * 33 + v2] + u[(192 + lane2) * 33 + v2];
    }
    float4* d4 = (float4*)(dst + t * 8);
    d4[0] = make_float4(res[0], res[1], res[2], res[3]);
    d4[1] = make_float4(res[4], res[5], res[6], res[7]);
}

// reduce K-split partials (nsc slices)
__global__ __launch_bounds__(256) void k_red(const float* __restrict__ xfp,
                                             float* __restrict__ xf, int nsc) {
    int idx = blockIdx.x * 256 + threadIdx.x;   // exactly 65536
    int b = idx >> 11;
    int r = idx & 2047;
    float s = 0.f;
    #pragma unroll 8
    for (int sc = 0; sc < nsc; ++sc)
        s += xfp[((size_t)(sc * NB + b)) * 2048 + r];
    xf[idx] = s;
}

// mode mix: ofT[b][2k][o] = alpha*Re, ofT[b][2k+1][o] = -alpha*Im  (transposed out)
__global__ __launch_bounds__(256) void k_mix(const float* __restrict__ xf,
                                             const float* __restrict__ wr,
                                             const float* __restrict__ wi,
                                             float* __restrict__ ofT) {
    int tid = blockIdx.x * 256 + threadIdx.x;   // exactly 32768
    int k = tid & 15;
    int o = (tid >> 4) & 63;
    int b = tid >> 10;
    float orr = 0.f, oii = 0.f;
    const float2* xfb = (const float2*)(xf + (size_t)b * WC * NKC);
    #pragma unroll 4
    for (int i = 0; i < WC; ++i) {
        float2 cs = xfb[i * NM + k];
        float wrv = wr[(i * WC + o) * NM + k];
        float wiv = wi[(i * WC + o) * NM + k];
        orr = fmaf(cs.x, wrv, fmaf(cs.y, wiv, orr));    // xfr*wr - xfi*wi
        oii = fmaf(cs.x, wiv, fmaf(-cs.y, wrv, oii));   // xfr*wi + xfi*wr
    }
    float alpha = (k == 0 ? 1.f : 2.f) / (float)SB;
    ofT[((size_t)b * NKC + 2 * k) * 64 + o]     = alpha * orr;
    ofT[((size_t)b * NKC + 2 * k + 1) * 64 + o] = -alpha * oii;
}

// fused update (+ forward DFT of the OUTPUT tile when dodft):
// phase 1: inverse-DFT + pointwise conv + bias + relu (round-16 2-col form);
// phase 2: store h_new transposed into the dead h-old LDS region [s][65],
//          then k_dft-v2-style DFT (wave owns full 64x32 C-tile, s uniform),
//          emitting the 128-s-chunk partial to xfp[chunk][b]. Removes the
//          separate k_dft's 64MB h re-read + re-staging for layers 1-3.
__global__ __launch_bounds__(256) void k_update(float* __restrict__ h,
                                                const float* __restrict__ T,
                                                const float* __restrict__ ofT,
                                                const float* __restrict__ pwT,
                                                const float* __restrict__ pwb,
                                                int relu, float* __restrict__ xfp,
                                                int dodft) {
    __shared__ float u[96 * LP];   // 50688 B; phase1: hS[96][132]; phase2 reuse
    float (*hS)[LP] = (float(*)[LP])u;
    int t = threadIdx.x;
    int b = blockIdx.y;
    int s0 = blockIdx.x * 128;
    int lane_s = t & 63;
    int g4 = __builtin_amdgcn_readfirstlane((t >> 6) & 3);
    int ob = g4 * 16;

    {   // stage h[64 ch][128 s]: 4 threads/row, 8 interleaved b128 each
        int ch = t >> 2, part = t & 3;
        const float* hrow = h + ((size_t)(b * WC + ch)) * SB + s0;
        #pragma unroll
        for (int r = 0; r < 8; ++r) {
            int so = (part + 4 * r) * 4;
            *(float4*)&hS[ch][so] = *(const float4*)(hrow + so);
        }
    }
    {   // stage T transposed: hS[64+j][s] = T[s0+s][j], s in 0..127
        int sl = t >> 1, jj0 = (t & 1) * 16;
        const float4* src = (const float4*)(T + (size_t)(s0 + sl) * NKC + jj0);
        float4 a = src[0], c4 = src[1], d = src[2], e = src[3];
        hS[64 + jj0 +  0][sl] = a.x;  hS[64 + jj0 +  1][sl] = a.y;
        hS[64 + jj0 +  2][sl] = a.z;  hS[64 + jj0 +  3][sl] = a.w;
        hS[64 + jj0 +  4][sl] = c4.x; hS[64 + jj0 +  5][sl] = c4.y;
        hS[64 + jj0 +  6][sl] = c4.z; hS[64 + jj0 +  7][sl] = c4.w;
        hS[64 + jj0 +  8][sl] = d.x;  hS[64 + jj0 +  9][sl] = d.y;
        hS[64 + jj0 + 10][sl] = d.z;  hS[64 + jj0 + 11][sl] = d.w;
        hS[64 + jj0 + 12][sl] = e.x;  hS[64 + jj0 + 13][sl] = e.y;
        hS[64 + jj0 + 14][sl] = e.z;  hS[64 + jj0 + 15][sl] = e.w;
    }
    __syncthreads();

    float acc0[16], acc1[16];
    #pragma unroll
    for (int o = 0; o < 16; ++o) { acc0[o] = pwb[ob + o]; acc1[o] = pwb[ob + o]; }

    const float* wbase0 = pwT + ob;                       // [k][64]
    const float* wbase1 = ofT + ((size_t)b * NKC) * 64 + ob;  // [j][64]

    for (int kc = 0; kc < 8; ++kc) {        // pointwise: k = 0..63
        #pragma unroll
        for (int uu = 0; uu < 8; ++uu) {
            int k = kc * 8 + uu;
            float h0 = hS[k][lane_s];
            float h1 = hS[k][64 + lane_s];
            const float* w = wbase0 + k * 64;
            #pragma unroll
            for (int o = 0; o < 16; ++o) {
                acc0[o] = fmaf(w[o], h0, acc0[o]);
                acc1[o] = fmaf(w[o], h1, acc1[o]);
            }
        }
    }
    for (int kc = 0; kc < 4; ++kc) {        // inverse-DFT: j = 0..31
        #pragma unroll
        for (int uu = 0; uu < 8; ++uu) {
            int j = kc * 8 + uu;
            float h0 = hS[64 + j][lane_s];
            float h1 = hS[64 + j][64 + lane_s];
            const float* w = wbase1 + j * 64;
            #pragma unroll
            for (int o = 0; o < 16; ++o) {
                acc0[o] = fmaf(w[o], h0, acc0[o]);
                acc1[o] = fmaf(w[o], h1, acc1[o]);
            }
        }
    }

    if (relu) {
        #pragma unroll
        for (int o = 0; o < 16; ++o) {
            acc0[o] = fmaxf(acc0[o], 0.f);
            acc1[o] = fmaxf(acc1[o], 0.f);
        }
    }

    float* hw0 = h + (size_t)b * WC * SB + s0 + lane_s;
    float* hw1 = hw0 + 64;
    #pragma unroll
    for (int o = 0; o < 16; ++o) {
        hw0[(size_t)(ob + o) * SB] = acc0[o];
        hw1[(size_t)(ob + o) * SB] = acc1[o];
    }

    if (!dodft) return;

    // ---- fused forward DFT of the output tile ----
    __syncthreads();                 // all reads of h-old LDS rows done
    // store h_new transposed: hT2[s][65] in u[0..8320) (h-old region, dead).
    // T rows (u[8448..12672)) remain live. writes: lane stride 65 -> free.
    #pragma unroll
    for (int o = 0; o < 16; ++o) {
        u[lane_s * 65 + ob + o]        = acc0[o];
        u[(64 + lane_s) * 65 + ob + o] = acc1[o];
    }
    __syncthreads();

    int lane = t & 63;
    int wv = __builtin_amdgcn_readfirstlane(t >> 6);
    int g  = lane >> 3;              // ch-group (ch = g*8+i)
    int j8 = lane & 7;               // mode-quad (mode = j8*4+m)

    float dacc[8][4];
    #pragma unroll
    for (int i = 0; i < 8; ++i)
        #pragma unroll
        for (int m = 0; m < 4; ++m) dacc[i][m] = 0.f;

    // wave wv handles s = wv*32 + ss (uniform per iteration -> broadcast reads)
    #pragma unroll 4
    for (int ss = 0; ss < 32; ++ss) {
        int s = wv * 32 + ss;
        float tv0 = u[64 * LP + (j8 * 4 + 0) * LP + s];
        float tv1 = u[64 * LP + (j8 * 4 + 1) * LP + s];
        float tv2 = u[64 * LP + (j8 * 4 + 2) * LP + s];
        float tv3 = u[64 * LP + (j8 * 4 + 3) * LP + s];
        float4 h0 = *(const float4*)&u[s * 65 + g * 8];
        float4 h1 = *(const float4*)&u[s * 65 + g * 8 + 4];
        float hh[8] = {h0.x, h0.y, h0.z, h0.w, h1.x, h1.y, h1.z, h1.w};
        #pragma unroll
        for (int i = 0; i < 8; ++i) {
            dacc[i][0] = fmaf(hh[i], tv0, dacc[i][0]);
            dacc[i][1] = fmaf(hh[i], tv1, dacc[i][1]);
            dacc[i][2] = fmaf(hh[i], tv2, dacc[i][2]);
            dacc[i][3] = fmaf(hh[i], tv3, dacc[i][3]);
        }
    }

    __syncthreads();                 // hT2 + T dead; reduce region u[0..8448)
    {
        float* slot = u + (wv * 64 + lane) * 33;
        #pragma unroll
        for (int i = 0; i < 8; ++i)
            #pragma unroll
            for (int m = 0; m < 4; ++m) slot[i * 4 + m] = dacc[i][m];
    }
    __syncthreads();

    float* dst = xfp + ((size_t)(blockIdx.x * NB + b)) * 2048;
    float res[8];
    #pragma unroll
    for (int e = 0; e < 8; ++e) {
        int idx = t * 8 + e;
        int ch = idx >> 5, mode = idx & 31;
        int g2 = ch >> 3, i2 = ch & 7;
        int q2 = mode >> 2, m2 = mode & 3;
        int lane2 = g2 * 8 + q2;
        int v2 = i2 * 4 + m2;
        res[e] = u[lane2 * 33 + v2] + u[(64 + lane2) * 33 + v2]
               + u[(128 + lane2) * 33 + v2] + u[(192 + lane2) * 33 + v2];
    }
    float4* d4 = (float4*)(dst + t * 8);
    d4[0] = make_float4(res[0], res[1], res[2], res[3]);
    d4[1] = make_float4(res[4], res[5], res[6], res[7]);
}

// final v3 (round-15 form, kept)
__global__ __launch_bounds__(256) void k_final(const float* __restrict__ h,
                                               const float* __restrict__ fc1_w,
                                               const float* __restrict__ fc1_b,
                                               const float* __restrict__ icaT,
                                               const float* __restrict__ ica_b,
                                               float* __restrict__ out,
                                               float* __restrict__ tc) {
    __shared__ float u_lds[6400];          // 25.6 KB: hS[64][68]=4352 then red[4][64][25]=6400
    float (*hS)[68] = (float(*)[68])u_lds;
    int t = threadIdx.x;
    int b = blockIdx.y;
    int s0 = blockIdx.x * 64;
    int lane_s = t & 63;
    int wv = __builtin_amdgcn_readfirstlane(t >> 6);
    int c0 = wv * 32;

    {   // stage transposed: hS[s][ch] = h[ch][s0+s]
        int sl = t & 63, chg = t >> 6;
        const float* hb = h + (size_t)b * WC * SB + s0 + sl;
        #pragma unroll
        for (int cc = 0; cc < 16; ++cc) {
            int ch = chg * 16 + cc;
            hS[sl][ch] = hb[(size_t)ch * SB];
        }
    }
    __syncthreads();

    float acc[NP];
    #pragma unroll
    for (int p = 0; p < NP; ++p) acc[p] = 0.f;

    for (int cq = 0; cq < 8; ++cq) {
        int c = c0 + 4 * cq;
        float tv0 = fc1_b[c], tv1 = fc1_b[c + 1], tv2 = fc1_b[c + 2], tv3 = fc1_b[c + 3];
        const float* w0 = fc1_w + (size_t)c * WC;
        const float* w1 = w0 + WC;
        const float* w2 = w1 + WC;
        const float* w3 = w2 + WC;
        for (int ioct = 0; ioct < 8; ++ioct) {
            float4 xa = *(const float4*)&hS[lane_s][ioct * 8];
            float4 xb = *(const float4*)&hS[lane_s][ioct * 8 + 4];
            float xs[8] = {xa.x, xa.y, xa.z, xa.w, xb.x, xb.y, xb.z, xb.w};
            #pragma unroll
            for (int uu = 0; uu < 8; ++uu) {
                int i = ioct * 8 + uu;
                tv0 = fmaf(w0[i], xs[uu], tv0);
                tv1 = fmaf(w1[i], xs[uu], tv1);
                tv2 = fmaf(w2[i], xs[uu], tv2);
                tv3 = fmaf(w3[i], xs[uu], tv3);
            }
        }
        tv0 = fmaxf(tv0, 0.f); tv1 = fmaxf(tv1, 0.f);
        tv2 = fmaxf(tv2, 0.f); tv3 = fmaxf(tv3, 0.f);
        const float* e0 = icaT + (size_t)c * NP;
        const float* e1 = e0 + NP;
        const float* e2 = e1 + NP;
        const float* e3 = e2 + NP;
        #pragma unroll
        for (int p = 0; p < NP; ++p)
            acc[p] = fmaf(tv0, e0[p], fmaf(tv1, e1[p],
                     fmaf(tv2, e2[p], fmaf(tv3, e3[p], acc[p]))));
    }

    __syncthreads();
    {
        float* slot = u_lds + ((t >> 6) * 64 + lane_s) * 25;
        #pragma unroll
        for (int p = 0; p < NP; ++p) slot[p] = acc[p];
    }
    __syncthreads();

    float* tcb = tc + ((size_t)b * SB + s0) * NP;
    #pragma unroll
    for (int r = 0; r < 6; ++r) {
        int e = t + r * 256;
        int s = e / NP, p = e - s * NP;
        float v = u_lds[s * 25 + p] + u_lds[(64 + s) * 25 + p]
                + u_lds[(128 + s) * 25 + p] + u_lds[(192 + s) * 25 + p]
                + ica_b[p];
        tcb[e] = v;
        u_lds[s * 25 + p] = v;
    }
    __syncthreads();
    if (t < 64) {
        float osum = 0.f;
        #pragma unroll
        for (int p = 0; p < NP; ++p) osum += u_lds[t * 25 + p];
        out[(size_t)b * SB + s0 + t] = osum;
    }
}

extern "C" void kernel_launch(void* const* d_in, const int* in_sizes, int n_in,
                              void* d_out, int out_size, void* d_ws, size_t ws_size,
                              hipStream_t stream) {
    const float* x     = (const float*)d_in[0];
    const float* fc0_w = (const float*)d_in[1];
    const float* fc0_b = (const float*)d_in[2];
    const float* cwr   = (const float*)d_in[3];
    const float* cwi   = (const float*)d_in[4];
    const float* pw_w  = (const float*)d_in[5];
    const float* pw_b  = (const float*)d_in[6];
    const float* fc1_w = (const float*)d_in[7];
    const float* fc1_b = (const float*)d_in[8];
    const float* fc2_w = (const float*)d_in[9];
    const float* ica_w = (const float*)d_in[10];
    const float* ica_b = (const float*)d_in[11];

    float* out = (float*)d_out;            // (B,S,1) = 262144
    float* tc  = out + (size_t)NB * SB;    // (B,S,1,24) = 6291456

    float* ws   = (float*)d_ws;
    float* h    = ws;
    float* T    = ws + 16777216;
    float* xf   = ws + 17039360;
    float* ofT  = ws + 17104896;
    float* icaT = ws + 17170432;
    float* pwT  = ws + 17173504;
    float* xfp  = tc;                      // DFT partials scratch (dead until k_final)

    k_table<<<32, 256, 0, stream>>>(T);
    k_prep<<<12, 256, 0, stream>>>(ica_w, fc2_w, icaT);
    k_prepw<<<64, 256, 0, stream>>>(pw_w, pwT);
    k_lift<<<dim3(32, 32), 256, 0, stream>>>(x, fc0_w, fc0_b, h);

    for (int l = 0; l < 4; ++l) {
        if (l == 0) {
            k_dft<<<NB * NSC, 256, 0, stream>>>(h, T, xfp);
            k_red<<<256, 256, 0, stream>>>(xfp, xf, NSC);
        } else {
            k_red<<<256, 256, 0, stream>>>(xfp, xf, 64);   // fused partials
        }
        k_mix<<<128, 256, 0, stream>>>(xf, cwr + (size_t)l * WC * WC * NM,
                                       cwi + (size_t)l * WC * WC * NM, ofT);
        k_update<<<dim3(64, 32), 256, 0, stream>>>(h, T, ofT,
                                                   pwT + (size_t)l * 4096,
                                                   pw_b + (size_t)l * WC,
                                                   (l < 3) ? 1 : 0,
                                                   xfp, (l < 3) ? 1 : 0);
    }

    k_final<<<dim3(128, 32), 256, 0, stream>>>(h, fc1_w, fc1_b, icaT, ica_b, out, tc);
}

// Round 19
// 409.618 us; speedup vs baseline: 1.3910x; 1.0395x over previous
//
#include <hip/hip_runtime.h>
#include <math.h>

#define SB 8192
#define NB 32
#define WC 64
#define NM 16
#define NKC 32   // 2*NM (cos,sin interleaved)
#define NP 24
#define LP 132   // padded LDS row length (128 + 4)

// h layout: h[b][ch][s] (s contiguous)
// ws layout (float offsets):
//   h    : 0         (B*W*S = 16777216)
//   T    : 16777216  (S*32  = 262144)
//   xf   : 17039360  (B*W*32 = 65536)
//   ofT  : 17104896  (B*32*W = 65536)   [j][o] transposed mode weights
//   icaT : 17170432  (128*24 = 3072)
//   pwT  : 17173504  (4*64*64 = 16384)  [l][k][o] transposed pointwise weights
// DFT partials (64 slices x 32 b x 2048) live in the tc output region
// (dead until k_final). All layers produce them fused (lift for l=0,
// update for l=1..3).

__global__ __launch_bounds__(256) void k_table(float* __restrict__ T) {
    int s = blockIdx.x * 256 + threadIdx.x;   // exactly 8192 threads
    float* row = T + (size_t)s * NKC;
    #pragma unroll
    for (int k = 0; k < NM; ++k) {
        int m = (k * s) & (SB - 1);           // exact phase mod S
        double ang = (double)m * (6.283185307179586476925286766559 / (double)SB);
        row[2 * k]     = (float)cos(ang);
        row[2 * k + 1] = (float)sin(ang);
    }
}

// icaT[c][p] = fc2_w[0][c] * ica_w[p][c]
__global__ __launch_bounds__(256) void k_prep(const float* __restrict__ ica_w,
                                              const float* __restrict__ fc2_w,
                                              float* __restrict__ icaT) {
    int tid = blockIdx.x * 256 + threadIdx.x;   // exactly 3072
    int c = tid / NP;
    int p = tid - c * NP;
    icaT[c * NP + p] = ica_w[p * 128 + c] * fc2_w[c];
}

// pwT[l][k][o] = pw_w[l][o][k]
__global__ __launch_bounds__(256) void k_prepw(const float* __restrict__ pw_w,
                                               float* __restrict__ pwT) {
    int tid = blockIdx.x * 256 + threadIdx.x;   // exactly 16384
    int l = tid >> 12, k = (tid >> 6) & 63, o = tid & 63;
    pwT[tid] = pw_w[(size_t)l * 4096 + o * 64 + k];
}

// fused lift + forward DFT of the lifted tile.
// Block = (s-chunk of 128, b). Thread (sl = t&127, half = t>>7) computes 32 ch
// of h[·][s0+sl], writes global h AND transposed LDS hT2[s][65]; T staged
// [j][132]; then the verified wave-owns-64x32-tile DFT (k_update phase-2 form)
// emits this chunk's partial to xfp[chunk][b]. Removes the separate k_dft.
__global__ __launch_bounds__(256) void k_lift(const float* __restrict__ x,
                                              const float* __restrict__ fc0_w,
                                              const float* __restrict__ fc0_b,
                                              float* __restrict__ h,
                                              const float* __restrict__ T,
                                              float* __restrict__ xfp) {
    __shared__ float u[12544];     // 50176 B: hT2[128][65]=8320 | Tt[32][132]=4224
    int t = threadIdx.x;
    int b = blockIdx.y;
    int s0 = blockIdx.x * 128;
    int sl = t & 127, half = t >> 7;
    int cb = half * 32;

    float2 xv = ((const float2*)x)[(size_t)b * SB + s0 + sl];
    float* hcol = h + (size_t)b * WC * SB + s0 + sl;
    #pragma unroll
    for (int c = 0; c < 32; ++c) {
        int ch = cb + c;
        float v = fmaf(xv.x, fc0_w[2 * ch], fmaf(xv.y, fc0_w[2 * ch + 1], fc0_b[ch]));
        hcol[(size_t)ch * SB] = v;
        u[sl * 65 + ch] = v;
    }
    {   // stage T rows [j][132]: Tt[j][s] = T[s0+s][j]
        int sl2 = t >> 1, jj0 = (t & 1) * 16;
        const float4* src = (const float4*)(T + (size_t)(s0 + sl2) * NKC + jj0);
        float4 a = src[0], c4 = src[1], d = src[2], e = src[3];
        float* Tt = u + 8320;
        Tt[(jj0 +  0) * LP + sl2] = a.x;  Tt[(jj0 +  1) * LP + sl2] = a.y;
        Tt[(jj0 +  2) * LP + sl2] = a.z;  Tt[(jj0 +  3) * LP + sl2] = a.w;
        Tt[(jj0 +  4) * LP + sl2] = c4.x; Tt[(jj0 +  5) * LP + sl2] = c4.y;
        Tt[(jj0 +  6) * LP + sl2] = c4.z; Tt[(jj0 +  7) * LP + sl2] = c4.w;
        Tt[(jj0 +  8) * LP + sl2] = d.x;  Tt[(jj0 +  9) * LP + sl2] = d.y;
        Tt[(jj0 + 10) * LP + sl2] = d.z;  Tt[(jj0 + 11) * LP + sl2] = d.w;
        Tt[(jj0 + 12) * LP + sl2] = e.x;  Tt[(jj0 + 13) * LP + sl2] = e.y;
        Tt[(jj0 + 14) * LP + sl2] = e.z;  Tt[(jj0 + 15) * LP + sl2] = e.w;
    }
    __syncthreads();

    int lane = t & 63;
    int wv = __builtin_amdgcn_readfirstlane(t >> 6);
    int g  = lane >> 3;              // ch-group (ch = g*8+i)
    int j8 = lane & 7;               // mode-quad (mode = j8*4+m)

    float dacc[8][4];
    #pragma unroll
    for (int i = 0; i < 8; ++i)
        #pragma unroll
        for (int m = 0; m < 4; ++m) dacc[i][m] = 0.f;

    #pragma unroll 4
    for (int ss = 0; ss < 32; ++ss) {
        int s = wv * 32 + ss;        // wave-uniform -> broadcast reads
        float tv0 = u[8320 + (j8 * 4 + 0) * LP + s];
        float tv1 = u[8320 + (j8 * 4 + 1) * LP + s];
        float tv2 = u[8320 + (j8 * 4 + 2) * LP + s];
        float tv3 = u[8320 + (j8 * 4 + 3) * LP + s];
        float4 h0 = *(const float4*)&u[s * 65 + g * 8];
        float4 h1 = *(const float4*)&u[s * 65 + g * 8 + 4];
        float hh[8] = {h0.x, h0.y, h0.z, h0.w, h1.x, h1.y, h1.z, h1.w};
        #pragma unroll
        for (int i = 0; i < 8; ++i) {
            dacc[i][0] = fmaf(hh[i], tv0, dacc[i][0]);
            dacc[i][1] = fmaf(hh[i], tv1, dacc[i][1]);
            dacc[i][2] = fmaf(hh[i], tv2, dacc[i][2]);
            dacc[i][3] = fmaf(hh[i], tv3, dacc[i][3]);
        }
    }

    __syncthreads();                 // hT2 + T dead; reduce region u[0..8448)
    {
        float* slot = u + (wv * 64 + lane) * 33;
        #pragma unroll
        for (int i = 0; i < 8; ++i)
            #pragma unroll
            for (int m = 0; m < 4; ++m) slot[i * 4 + m] = dacc[i][m];
    }
    __syncthreads();

    float* dst = xfp + ((size_t)(blockIdx.x * NB + b)) * 2048;
    float res[8];
    #pragma unroll
    for (int e = 0; e < 8; ++e) {
        int idx = t * 8 + e;
        int ch = idx >> 5, mode = idx & 31;
        int g2 = ch >> 3, i2 = ch & 7;
        int q2 = mode >> 2, m2 = mode & 3;
        int lane2 = g2 * 8 + q2;
        int v2 = i2 * 4 + m2;
        res[e] = u[lane2 * 33 + v2] + u[(64 + lane2) * 33 + v2]
               + u[(128 + lane2) * 33 + v2] + u[(192 + lane2) * 33 + v2];
    }
    float4* d4 = (float4*)(dst + t * 8);
    d4[0] = make_float4(res[0], res[1], res[2], res[3]);
    d4[1] = make_float4(res[4], res[5], res[6], res[7]);
}

// reduce K-split partials (nsc slices)
__global__ __launch_bounds__(256) void k_red(const float* __restrict__ xfp,
                                             float* __restrict__ xf, int nsc) {
    int idx = blockIdx.x * 256 + threadIdx.x;   // exactly 65536
    int b = idx >> 11;
    int r = idx & 2047;
    float s = 0.f;
    #pragma unroll 8
    for (int sc = 0; sc < nsc; ++sc)
        s += xfp[((size_t)(sc * NB + b)) * 2048 + r];
    xf[idx] = s;
}

// mode mix: ofT[b][2k][o] = alpha*Re, ofT[b][2k+1][o] = -alpha*Im  (transposed out)
__global__ __launch_bounds__(256) void k_mix(const float* __restrict__ xf,
                                             const float* __restrict__ wr,
                                             const float* __restrict__ wi,
                                             float* __restrict__ ofT) {
    int tid = blockIdx.x * 256 + threadIdx.x;   // exactly 32768
    int k = tid & 15;
    int o = (tid >> 4) & 63;
    int b = tid >> 10;
    float orr = 0.f, oii = 0.f;
    const float2* xfb = (const float2*)(xf + (size_t)b * WC * NKC);
    #pragma unroll 4
    for (int i = 0; i < WC; ++i) {
        float2 cs = xfb[i * NM + k];
        float wrv = wr[(i * WC + o) * NM + k];
        float wiv = wi[(i * WC + o) * NM + k];
        orr = fmaf(cs.x, wrv, fmaf(cs.y, wiv, orr));    // xfr*wr - xfi*wi
        oii = fmaf(cs.x, wiv, fmaf(-cs.y, wrv, oii));   // xfr*wi + xfi*wr
    }
    float alpha = (k == 0 ? 1.f : 2.f) / (float)SB;
    ofT[((size_t)b * NKC + 2 * k) * 64 + o]     = alpha * orr;
    ofT[((size_t)b * NKC + 2 * k + 1) * 64 + o] = -alpha * oii;
}

// fused update (+ forward DFT of the OUTPUT tile when dodft) — round-18 form.
__global__ __launch_bounds__(256) void k_update(float* __restrict__ h,
                                                const float* __restrict__ T,
                                                const float* __restrict__ ofT,
                                                const float* __restrict__ pwT,
                                                const float* __restrict__ pwb,
                                                int relu, float* __restrict__ xfp,
                                                int dodft) {
    __shared__ float u[96 * LP];   // 50688 B; phase1: hS[96][132]; phase2 reuse
    float (*hS)[LP] = (float(*)[LP])u;
    int t = threadIdx.x;
    int b = blockIdx.y;
    int s0 = blockIdx.x * 128;
    int lane_s = t & 63;
    int g4 = __builtin_amdgcn_readfirstlane((t >> 6) & 3);
    int ob = g4 * 16;

    {   // stage h[64 ch][128 s]: 4 threads/row, 8 interleaved b128 each
        int ch = t >> 2, part = t & 3;
        const float* hrow = h + ((size_t)(b * WC + ch)) * SB + s0;
        #pragma unroll
        for (int r = 0; r < 8; ++r) {
            int so = (part + 4 * r) * 4;
            *(float4*)&hS[ch][so] = *(const float4*)(hrow + so);
        }
    }
    {   // stage T transposed: hS[64+j][s] = T[s0+s][j], s in 0..127
        int sl = t >> 1, jj0 = (t & 1) * 16;
        const float4* src = (const float4*)(T + (size_t)(s0 + sl) * NKC + jj0);
        float4 a = src[0], c4 = src[1], d = src[2], e = src[3];
        hS[64 + jj0 +  0][sl] = a.x;  hS[64 + jj0 +  1][sl] = a.y;
        hS[64 + jj0 +  2][sl] = a.z;  hS[64 + jj0 +  3][sl] = a.w;
        hS[64 + jj0 +  4][sl] = c4.x; hS[64 + jj0 +  5][sl] = c4.y;
        hS[64 + jj0 +  6][sl] = c4.z; hS[64 + jj0 +  7][sl] = c4.w;
        hS[64 + jj0 +  8][sl] = d.x;  hS[64 + jj0 +  9][sl] = d.y;
        hS[64 + jj0 + 10][sl] = d.z;  hS[64 + jj0 + 11][sl] = d.w;
        hS[64 + jj0 + 12][sl] = e.x;  hS[64 + jj0 + 13][sl] = e.y;
        hS[64 + jj0 + 14][sl] = e.z;  hS[64 + jj0 + 15][sl] = e.w;
    }
    __syncthreads();

    float acc0[16], acc1[16];
    #pragma unroll
    for (int o = 0; o < 16; ++o) { acc0[o] = pwb[ob + o]; acc1[o] = pwb[ob + o]; }

    const float* wbase0 = pwT + ob;                       // [k][64]
    const float* wbase1 = ofT + ((size_t)b * NKC) * 64 + ob;  // [j][64]

    for (int kc = 0; kc < 8; ++kc) {        // pointwise: k = 0..63
        #pragma unroll
        for (int uu = 0; uu < 8; ++uu) {
            int k = kc * 8 + uu;
            float h0 = hS[k][lane_s];
            float h1 = hS[k][64 + lane_s];
            const float* w = wbase0 + k * 64;
            #pragma unroll
            for (int o = 0; o < 16; ++o) {
                acc0[o] = fmaf(w[o], h0, acc0[o]);
                acc1[o] = fmaf(w[o], h1, acc1[o]);
            }
        }
    }
    for (int kc = 0; kc < 4; ++kc) {        // inverse-DFT: j = 0..31
        #pragma unroll
        for (int uu = 0; uu < 8; ++uu) {
            int j = kc * 8 + uu;
            float h0 = hS[64 + j][lane_s];
            float h1 = hS[64 + j][64 + lane_s];
            const float* w = wbase1 + j * 64;
            #pragma unroll
            for (int o = 0; o < 16; ++o) {
                acc0[o] = fmaf(w[o], h0, acc0[o]);
                acc1[o] = fmaf(w[o], h1, acc1[o]);
            }
        }
    }

    if (relu) {
        #pragma unroll
        for (int o = 0; o < 16; ++o) {
            acc0[o] = fmaxf(acc0[o], 0.f);
            acc1[o] = fmaxf(acc1[o], 0.f);
        }
    }

    float* hw0 = h + (size_t)b * WC * SB + s0 + lane_s;
    float* hw1 = hw0 + 64;
    #pragma unroll
    for (int o = 0; o < 16; ++o) {
        hw0[(size_t)(ob + o) * SB] = acc0[o];
        hw1[(size_t)(ob + o) * SB] = acc1[o];
    }

    if (!dodft) return;

    // ---- fused forward DFT of the output tile ----
    __syncthreads();                 // all reads of h-old LDS rows done
    #pragma unroll
    for (int o = 0; o < 16; ++o) {
        u[lane_s * 65 + ob + o]        = acc0[o];
        u[(64 + lane_s) * 65 + ob + o] = acc1[o];
    }
    __syncthreads();

    int lane = t & 63;
    int wv = __builtin_amdgcn_readfirstlane(t >> 6);
    int g  = lane >> 3;
    int j8 = lane & 7;

    float dacc[8][4];
    #pragma unroll
    for (int i = 0; i < 8; ++i)
        #pragma unroll
        for (int m = 0; m < 4; ++m) dacc[i][m] = 0.f;

    #pragma unroll 4
    for (int ss = 0; ss < 32; ++ss) {
        int s = wv * 32 + ss;
        float tv0 = u[64 * LP + (j8 * 4 + 0) * LP + s];
        float tv1 = u[64 * LP + (j8 * 4 + 1) * LP + s];
        float tv2 = u[64 * LP + (j8 * 4 + 2) * LP + s];
        float tv3 = u[64 * LP + (j8 * 4 + 3) * LP + s];
        float4 h0 = *(const float4*)&u[s * 65 + g * 8];
        float4 h1 = *(const float4*)&u[s * 65 + g * 8 + 4];
        float hh[8] = {h0.x, h0.y, h0.z, h0.w, h1.x, h1.y, h1.z, h1.w};
        #pragma unroll
        for (int i = 0; i < 8; ++i) {
            dacc[i][0] = fmaf(hh[i], tv0, dacc[i][0]);
            dacc[i][1] = fmaf(hh[i], tv1, dacc[i][1]);
            dacc[i][2] = fmaf(hh[i], tv2, dacc[i][2]);
            dacc[i][3] = fmaf(hh[i], tv3, dacc[i][3]);
        }
    }

    __syncthreads();
    {
        float* slot = u + (wv * 64 + lane) * 33;
        #pragma unroll
        for (int i = 0; i < 8; ++i)
            #pragma unroll
            for (int m = 0; m < 4; ++m) slot[i * 4 + m] = dacc[i][m];
    }
    __syncthreads();

    float* dst = xfp + ((size_t)(blockIdx.x * NB + b)) * 2048;
    float res[8];
    #pragma unroll
    for (int e = 0; e < 8; ++e) {
        int idx = t * 8 + e;
        int ch = idx >> 5, mode = idx & 31;
        int g2 = ch >> 3, i2 = ch & 7;
        int q2 = mode >> 2, m2 = mode & 3;
        int lane2 = g2 * 8 + q2;
        int v2 = i2 * 4 + m2;
        res[e] = u[lane2 * 33 + v2] + u[(64 + lane2) * 33 + v2]
               + u[(128 + lane2) * 33 + v2] + u[(192 + lane2) * 33 + v2];
    }
    float4* d4 = (float4*)(dst + t * 8);
    d4[0] = make_float4(res[0], res[1], res[2], res[3]);
    d4[1] = make_float4(res[4], res[5], res[6], res[7]);
}

// final v3 (round-15 form, kept)
__global__ __launch_bounds__(256) void k_final(const float* __restrict__ h,
                                               const float* __restrict__ fc1_w,
                                               const float* __restrict__ fc1_b,
                                               const float* __restrict__ icaT,
                                               const float* __restrict__ ica_b,
                                               float* __restrict__ out,
                                               float* __restrict__ tc) {
    __shared__ float u_lds[6400];          // 25.6 KB: hS[64][68]=4352 then red[4][64][25]=6400
    float (*hS)[68] = (float(*)[68])u_lds;
    int t = threadIdx.x;
    int b = blockIdx.y;
    int s0 = blockIdx.x * 64;
    int lane_s = t & 63;
    int wv = __builtin_amdgcn_readfirstlane(t >> 6);
    int c0 = wv * 32;

    {   // stage transposed: hS[s][ch] = h[ch][s0+s]
        int sl = t & 63, chg = t >> 6;
        const float* hb = h + (size_t)b * WC * SB + s0 + sl;
        #pragma unroll
        for (int cc = 0; cc < 16; ++cc) {
            int ch = chg * 16 + cc;
            hS[sl][ch] = hb[(size_t)ch * SB];
        }
    }
    __syncthreads();

    float acc[NP];
    #pragma unroll
    for (int p = 0; p < NP; ++p) acc[p] = 0.f;

    for (int cq = 0; cq < 8; ++cq) {
        int c = c0 + 4 * cq;
        float tv0 = fc1_b[c], tv1 = fc1_b[c + 1], tv2 = fc1_b[c + 2], tv3 = fc1_b[c + 3];
        const float* w0 = fc1_w + (size_t)c * WC;
        const float* w1 = w0 + WC;
        const float* w2 = w1 + WC;
        const float* w3 = w2 + WC;
        for (int ioct = 0; ioct < 8; ++ioct) {
            float4 xa = *(const float4*)&hS[lane_s][ioct * 8];
            float4 xb = *(const float4*)&hS[lane_s][ioct * 8 + 4];
            float xs[8] = {xa.x, xa.y, xa.z, xa.w, xb.x, xb.y, xb.z, xb.w};
            #pragma unroll
            for (int uu = 0; uu < 8; ++uu) {
                int i = ioct * 8 + uu;
                tv0 = fmaf(w0[i], xs[uu], tv0);
                tv1 = fmaf(w1[i], xs[uu], tv1);
                tv2 = fmaf(w2[i], xs[uu], tv2);
                tv3 = fmaf(w3[i], xs[uu], tv3);
            }
        }
        tv0 = fmaxf(tv0, 0.f); tv1 = fmaxf(tv1, 0.f);
        tv2 = fmaxf(tv2, 0.f); tv3 = fmaxf(tv3, 0.f);
        const float* e0 = icaT + (size_t)c * NP;
        const float* e1 = e0 + NP;
        const float* e2 = e1 + NP;
        const float* e3 = e2 + NP;
        #pragma unroll
        for (int p = 0; p < NP; ++p)
            acc[p] = fmaf(tv0, e0[p], fmaf(tv1, e1[p],
                     fmaf(tv2, e2[p], fmaf(tv3, e3[p], acc[p]))));
    }

    __syncthreads();
    {
        float* slot = u_lds + ((t >> 6) * 64 + lane_s) * 25;
        #pragma unroll
        for (int p = 0; p < NP; ++p) slot[p] = acc[p];
    }
    __syncthreads();

    float* tcb = tc + ((size_t)b * SB + s0) * NP;
    #pragma unroll
    for (int r = 0; r < 6; ++r) {
        int e = t + r * 256;
        int s = e / NP, p = e - s * NP;
        float v = u_lds[s * 25 + p] + u_lds[(64 + s) * 25 + p]
                + u_lds[(128 + s) * 25 + p] + u_lds[(192 + s) * 25 + p]
                + ica_b[p];
        tcb[e] = v;
        u_lds[s * 25 + p] = v;
    }
    __syncthreads();
    if (t < 64) {
        float osum = 0.f;
        #pragma unroll
        for (int p = 0; p < NP; ++p) osum += u_lds[t * 25 + p];
        out[(size_t)b * SB + s0 + t] = osum;
    }
}

extern "C" void kernel_launch(void* const* d_in, const int* in_sizes, int n_in,
                              void* d_out, int out_size, void* d_ws, size_t ws_size,
                              hipStream_t stream) {
    const float* x     = (const float*)d_in[0];
    const float* fc0_w = (const float*)d_in[1];
    const float* fc0_b = (const float*)d_in[2];
    const float* cwr   = (const float*)d_in[3];
    const float* cwi   = (const float*)d_in[4];
    const float* pw_w  = (const float*)d_in[5];
    const float* pw_b  = (const float*)d_in[6];
    const float* fc1_w = (const float*)d_in[7];
    const float* fc1_b = (const float*)d_in[8];
    const float* fc2_w = (const float*)d_in[9];
    const float* ica_w = (const float*)d_in[10];
    const float* ica_b = (const float*)d_in[11];

    float* out = (float*)d_out;            // (B,S,1) = 262144
    float* tc  = out + (size_t)NB * SB;    // (B,S,1,24) = 6291456

    float* ws   = (float*)d_ws;
    float* h    = ws;
    float* T    = ws + 16777216;
    float* xf   = ws + 17039360;
    float* ofT  = ws + 17104896;
    float* icaT = ws + 17170432;
    float* pwT  = ws + 17173504;
    float* xfp  = tc;                      // DFT partials scratch (dead until k_final)

    k_table<<<32, 256, 0, stream>>>(T);
    k_prep<<<12, 256, 0, stream>>>(ica_w, fc2_w, icaT);
    k_prepw<<<64, 256, 0, stream>>>(pw_w, pwT);
    k_lift<<<dim3(64, 32), 256, 0, stream>>>(x, fc0_w, fc0_b, h, T, xfp);

    for (int l = 0; l < 4; ++l) {
        k_red<<<256, 256, 0, stream>>>(xfp, xf, 64);
        k_mix<<<128, 256, 0, stream>>>(xf, cwr + (size_t)l * WC * WC * NM,
                                       cwi + (size_t)l * WC * WC * NM, ofT);
        k_update<<<dim3(64, 32), 256, 0, stream>>>(h, T, ofT,
                                                   pwT + (size_t)l * 4096,
                                                   pw_b + (size_t)l * WC,
                                                   (l < 3) ? 1 : 0,
                                                   xfp, (l < 3) ? 1 : 0);
    }

    k_final<<<dim3(128, 32), 256, 0, stream>>>(h, fc1_w, fc1_b, icaT, ica_b, out, tc);
}

// Round 20
// 399.531 us; speedup vs baseline: 1.4261x; 1.0252x over previous
//
#include <hip/hip_runtime.h>
#include <math.h>

#define SB 8192
#define NB 32
#define WC 64
#define NM 16
#define NKC 32   // 2*NM (cos,sin interleaved)
#define NP 24
#define LP 132   // padded LDS row length (128 + 4)

// h layout: h[b][ch][s] (s contiguous)
// ws layout (float offsets):
//   h    : 0         (B*W*S = 16777216)
//   T    : 16777216  (S*32  = 262144)
//   xf   : 17039360  (B*W*32 = 65536)
//   ofT  : 17104896  (B*32*W = 65536)   [j][o] transposed mode weights
//   icaT : 17170432  (128*24 = 3072)
//   pwT  : 17173504  (4*64*64 = 16384)  [l][k][o] transposed pointwise weights
// DFT partials (64 slices x 32 b x 2048) live in the tc output region
// (dead until k_final). All layers produce them fused (lift for l=0,
// update for l=1..3).

__global__ __launch_bounds__(256) void k_table(float* __restrict__ T) {
    int s = blockIdx.x * 256 + threadIdx.x;   // exactly 8192 threads
    float* row = T + (size_t)s * NKC;
    #pragma unroll
    for (int k = 0; k < NM; ++k) {
        int m = (k * s) & (SB - 1);           // exact phase mod S
        double ang = (double)m * (6.283185307179586476925286766559 / (double)SB);
        row[2 * k]     = (float)cos(ang);
        row[2 * k + 1] = (float)sin(ang);
    }
}

// icaT[c][p] = fc2_w[0][c] * ica_w[p][c]
__global__ __launch_bounds__(256) void k_prep(const float* __restrict__ ica_w,
                                              const float* __restrict__ fc2_w,
                                              float* __restrict__ icaT) {
    int tid = blockIdx.x * 256 + threadIdx.x;   // exactly 3072
    int c = tid / NP;
    int p = tid - c * NP;
    icaT[c * NP + p] = ica_w[p * 128 + c] * fc2_w[c];
}

// pwT[l][k][o] = pw_w[l][o][k]
__global__ __launch_bounds__(256) void k_prepw(const float* __restrict__ pw_w,
                                               float* __restrict__ pwT) {
    int tid = blockIdx.x * 256 + threadIdx.x;   // exactly 16384
    int l = tid >> 12, k = (tid >> 6) & 63, o = tid & 63;
    pwT[tid] = pw_w[(size_t)l * 4096 + o * 64 + k];
}

// fused lift + forward DFT of the lifted tile (round-18 form).
__global__ __launch_bounds__(256) void k_lift(const float* __restrict__ x,
                                              const float* __restrict__ fc0_w,
                                              const float* __restrict__ fc0_b,
                                              float* __restrict__ h,
                                              const float* __restrict__ T,
                                              float* __restrict__ xfp) {
    __shared__ float u[12544];     // 50176 B: hT2[128][65]=8320 | Tt[32][132]=4224
    int t = threadIdx.x;
    int b = blockIdx.y;
    int s0 = blockIdx.x * 128;
    int sl = t & 127, half = t >> 7;
    int cb = half * 32;

    float2 xv = ((const float2*)x)[(size_t)b * SB + s0 + sl];
    float* hcol = h + (size_t)b * WC * SB + s0 + sl;
    #pragma unroll
    for (int c = 0; c < 32; ++c) {
        int ch = cb + c;
        float v = fmaf(xv.x, fc0_w[2 * ch], fmaf(xv.y, fc0_w[2 * ch + 1], fc0_b[ch]));
        hcol[(size_t)ch * SB] = v;
        u[sl * 65 + ch] = v;
    }
    {   // stage T rows [j][132]: Tt[j][s] = T[s0+s][j]
        int sl2 = t >> 1, jj0 = (t & 1) * 16;
        const float4* src = (const float4*)(T + (size_t)(s0 + sl2) * NKC + jj0);
        float4 a = src[0], c4 = src[1], d = src[2], e = src[3];
        float* Tt = u + 8320;
        Tt[(jj0 +  0) * LP + sl2] = a.x;  Tt[(jj0 +  1) * LP + sl2] = a.y;
        Tt[(jj0 +  2) * LP + sl2] = a.z;  Tt[(jj0 +  3) * LP + sl2] = a.w;
        Tt[(jj0 +  4) * LP + sl2] = c4.x; Tt[(jj0 +  5) * LP + sl2] = c4.y;
        Tt[(jj0 +  6) * LP + sl2] = c4.z; Tt[(jj0 +  7) * LP + sl2] = c4.w;
        Tt[(jj0 +  8) * LP + sl2] = d.x;  Tt[(jj0 +  9) * LP + sl2] = d.y;
        Tt[(jj0 + 10) * LP + sl2] = d.z;  Tt[(jj0 + 11) * LP + sl2] = d.w;
        Tt[(jj0 + 12) * LP + sl2] = e.x;  Tt[(jj0 + 13) * LP + sl2] = e.y;
        Tt[(jj0 + 14) * LP + sl2] = e.z;  Tt[(jj0 + 15) * LP + sl2] = e.w;
    }
    __syncthreads();

    int lane = t & 63;
    int wv = __builtin_amdgcn_readfirstlane(t >> 6);
    int g  = lane >> 3;              // ch-group (ch = g*8+i)
    int j8 = lane & 7;               // mode-quad (mode = j8*4+m)

    float dacc[8][4];
    #pragma unroll
    for (int i = 0; i < 8; ++i)
        #pragma unroll
        for (int m = 0; m < 4; ++m) dacc[i][m] = 0.f;

    #pragma unroll 4
    for (int ss = 0; ss < 32; ++ss) {
        int s = wv * 32 + ss;        // wave-uniform -> broadcast reads
        float tv0 = u[8320 + (j8 * 4 + 0) * LP + s];
        float tv1 = u[8320 + (j8 * 4 + 1) * LP + s];
        float tv2 = u[8320 + (j8 * 4 + 2) * LP + s];
        float tv3 = u[8320 + (j8 * 4 + 3) * LP + s];
        float4 h0 = *(const float4*)&u[s * 65 + g * 8];
        float4 h1 = *(const float4*)&u[s * 65 + g * 8 + 4];
        float hh[8] = {h0.x, h0.y, h0.z, h0.w, h1.x, h1.y, h1.z, h1.w};
        #pragma unroll
        for (int i = 0; i < 8; ++i) {
            dacc[i][0] = fmaf(hh[i], tv0, dacc[i][0]);
            dacc[i][1] = fmaf(hh[i], tv1, dacc[i][1]);
            dacc[i][2] = fmaf(hh[i], tv2, dacc[i][2]);
            dacc[i][3] = fmaf(hh[i], tv3, dacc[i][3]);
        }
    }

    __syncthreads();                 // hT2 + T dead; reduce region u[0..8448)
    {
        float* slot = u + (wv * 64 + lane) * 33;
        #pragma unroll
        for (int i = 0; i < 8; ++i)
            #pragma unroll
            for (int m = 0; m < 4; ++m) slot[i * 4 + m] = dacc[i][m];
    }
    __syncthreads();

    float* dst = xfp + ((size_t)(blockIdx.x * NB + b)) * 2048;
    float res[8];
    #pragma unroll
    for (int e = 0; e < 8; ++e) {
        int idx = t * 8 + e;
        int ch = idx >> 5, mode = idx & 31;
        int g2 = ch >> 3, i2 = ch & 7;
        int q2 = mode >> 2, m2 = mode & 3;
        int lane2 = g2 * 8 + q2;
        int v2 = i2 * 4 + m2;
        res[e] = u[lane2 * 33 + v2] + u[(64 + lane2) * 33 + v2]
               + u[(128 + lane2) * 33 + v2] + u[(192 + lane2) * 33 + v2];
    }
    float4* d4 = (float4*)(dst + t * 8);
    d4[0] = make_float4(res[0], res[1], res[2], res[3]);
    d4[1] = make_float4(res[4], res[5], res[6], res[7]);
}

// reduce K-split partials (nsc slices)
__global__ __launch_bounds__(256) void k_red(const float* __restrict__ xfp,
                                             float* __restrict__ xf, int nsc) {
    int idx = blockIdx.x * 256 + threadIdx.x;   // exactly 65536
    int b = idx >> 11;
    int r = idx & 2047;
    float s = 0.f;
    #pragma unroll 8
    for (int sc = 0; sc < nsc; ++sc)
        s += xfp[((size_t)(sc * NB + b)) * 2048 + r];
    xf[idx] = s;
}

// mode mix: ofT[b][2k][o] = alpha*Re, ofT[b][2k+1][o] = -alpha*Im  (transposed out)
__global__ __launch_bounds__(256) void k_mix(const float* __restrict__ xf,
                                             const float* __restrict__ wr,
                                             const float* __restrict__ wi,
                                             float* __restrict__ ofT) {
    int tid = blockIdx.x * 256 + threadIdx.x;   // exactly 32768
    int k = tid & 15;
    int o = (tid >> 4) & 63;
    int b = tid >> 10;
    float orr = 0.f, oii = 0.f;
    const float2* xfb = (const float2*)(xf + (size_t)b * WC * NKC);
    #pragma unroll 4
    for (int i = 0; i < WC; ++i) {
        float2 cs = xfb[i * NM + k];
        float wrv = wr[(i * WC + o) * NM + k];
        float wiv = wi[(i * WC + o) * NM + k];
        orr = fmaf(cs.x, wrv, fmaf(cs.y, wiv, orr));    // xfr*wr - xfi*wi
        oii = fmaf(cs.x, wiv, fmaf(-cs.y, wrv, oii));   // xfr*wi + xfi*wr
    }
    float alpha = (k == 0 ? 1.f : 2.f) / (float)SB;
    ofT[((size_t)b * NKC + 2 * k) * 64 + o]     = alpha * orr;
    ofT[((size_t)b * NKC + 2 * k + 1) * 64 + o] = -alpha * oii;
}

// fused update (+ forward DFT of the OUTPUT tile when dodft) — round-18 form.
__global__ __launch_bounds__(256) void k_update(float* __restrict__ h,
                                                const float* __restrict__ T,
                                                const float* __restrict__ ofT,
                                                const float* __restrict__ pwT,
                                                const float* __restrict__ pwb,
                                                int relu, float* __restrict__ xfp,
                                                int dodft) {
    __shared__ float u[96 * LP];   // 50688 B; phase1: hS[96][132]; phase2 reuse
    float (*hS)[LP] = (float(*)[LP])u;
    int t = threadIdx.x;
    int b = blockIdx.y;
    int s0 = blockIdx.x * 128;
    int lane_s = t & 63;
    int g4 = __builtin_amdgcn_readfirstlane((t >> 6) & 3);
    int ob = g4 * 16;

    {   // stage h[64 ch][128 s]: 4 threads/row, 8 interleaved b128 each
        int ch = t >> 2, part = t & 3;
        const float* hrow = h + ((size_t)(b * WC + ch)) * SB + s0;
        #pragma unroll
        for (int r = 0; r < 8; ++r) {
            int so = (part + 4 * r) * 4;
            *(float4*)&hS[ch][so] = *(const float4*)(hrow + so);
        }
    }
    {   // stage T transposed: hS[64+j][s] = T[s0+s][j], s in 0..127
        int sl = t >> 1, jj0 = (t & 1) * 16;
        const float4* src = (const float4*)(T + (size_t)(s0 + sl) * NKC + jj0);
        float4 a = src[0], c4 = src[1], d = src[2], e = src[3];
        hS[64 + jj0 +  0][sl] = a.x;  hS[64 + jj0 +  1][sl] = a.y;
        hS[64 + jj0 +  2][sl] = a.z;  hS[64 + jj0 +  3][sl] = a.w;
        hS[64 + jj0 +  4][sl] = c4.x; hS[64 + jj0 +  5][sl] = c4.y;
        hS[64 + jj0 +  6][sl] = c4.z; hS[64 + jj0 +  7][sl] = c4.w;
        hS[64 + jj0 +  8][sl] = d.x;  hS[64 + jj0 +  9][sl] = d.y;
        hS[64 + jj0 + 10][sl] = d.z;  hS[64 + jj0 + 11][sl] = d.w;
        hS[64 + jj0 + 12][sl] = e.x;  hS[64 + jj0 + 13][sl] = e.y;
        hS[64 + jj0 + 14][sl] = e.z;  hS[64 + jj0 + 15][sl] = e.w;
    }
    __syncthreads();

    float acc0[16], acc1[16];
    #pragma unroll
    for (int o = 0; o < 16; ++o) { acc0[o] = pwb[ob + o]; acc1[o] = pwb[ob + o]; }

    const float* wbase0 = pwT + ob;                       // [k][64]
    const float* wbase1 = ofT + ((size_t)b * NKC) * 64 + ob;  // [j][64]

    for (int kc = 0; kc < 8; ++kc) {        // pointwise: k = 0..63
        #pragma unroll
        for (int uu = 0; uu < 8; ++uu) {
            int k = kc * 8 + uu;
            float h0 = hS[k][lane_s];
            float h1 = hS[k][64 + lane_s];
            const float* w = wbase0 + k * 64;
            #pragma unroll
            for (int o = 0; o < 16; ++o) {
                acc0[o] = fmaf(w[o], h0, acc0[o]);
                acc1[o] = fmaf(w[o], h1, acc1[o]);
            }
        }
    }
    for (int kc = 0; kc < 4; ++kc) {        // inverse-DFT: j = 0..31
        #pragma unroll
        for (int uu = 0; uu < 8; ++uu) {
            int j = kc * 8 + uu;
            float h0 = hS[64 + j][lane_s];
            float h1 = hS[64 + j][64 + lane_s];
            const float* w = wbase1 + j * 64;
            #pragma unroll
            for (int o = 0; o < 16; ++o) {
                acc0[o] = fmaf(w[o], h0, acc0[o]);
                acc1[o] = fmaf(w[o], h1, acc1[o]);
            }
        }
    }

    if (relu) {
        #pragma unroll
        for (int o = 0; o < 16; ++o) {
            acc0[o] = fmaxf(acc0[o], 0.f);
            acc1[o] = fmaxf(acc1[o], 0.f);
        }
    }

    float* hw0 = h + (size_t)b * WC * SB + s0 + lane_s;
    float* hw1 = hw0 + 64;
    #pragma unroll
    for (int o = 0; o < 16; ++o) {
        hw0[(size_t)(ob + o) * SB] = acc0[o];
        hw1[(size_t)(ob + o) * SB] = acc1[o];
    }

    if (!dodft) return;

    // ---- fused forward DFT of the output tile ----
    __syncthreads();                 // all reads of h-old LDS rows done
    #pragma unroll
    for (int o = 0; o < 16; ++o) {
        u[lane_s * 65 + ob + o]        = acc0[o];
        u[(64 + lane_s) * 65 + ob + o] = acc1[o];
    }
    __syncthreads();

    int lane = t & 63;
    int wv = __builtin_amdgcn_readfirstlane(t >> 6);
    int g  = lane >> 3;
    int j8 = lane & 7;

    float dacc[8][4];
    #pragma unroll
    for (int i = 0; i < 8; ++i)
        #pragma unroll
        for (int m = 0; m < 4; ++m) dacc[i][m] = 0.f;

    #pragma unroll 4
    for (int ss = 0; ss < 32; ++ss) {
        int s = wv * 32 + ss;
        float tv0 = u[64 * LP + (j8 * 4 + 0) * LP + s];
        float tv1 = u[64 * LP + (j8 * 4 + 1) * LP + s];
        float tv2 = u[64 * LP + (j8 * 4 + 2) * LP + s];
        float tv3 = u[64 * LP + (j8 * 4 + 3) * LP + s];
        float4 h0 = *(const float4*)&u[s * 65 + g * 8];
        float4 h1 = *(const float4*)&u[s * 65 + g * 8 + 4];
        float hh[8] = {h0.x, h0.y, h0.z, h0.w, h1.x, h1.y, h1.z, h1.w};
        #pragma unroll
        for (int i = 0; i < 8; ++i) {
            dacc[i][0] = fmaf(hh[i], tv0, dacc[i][0]);
            dacc[i][1] = fmaf(hh[i], tv1, dacc[i][1]);
            dacc[i][2] = fmaf(hh[i], tv2, dacc[i][2]);
            dacc[i][3] = fmaf(hh[i], tv3, dacc[i][3]);
        }
    }

    __syncthreads();
    {
        float* slot = u + (wv * 64 + lane) * 33;
        #pragma unroll
        for (int i = 0; i < 8; ++i)
            #pragma unroll
            for (int m = 0; m < 4; ++m) slot[i * 4 + m] = dacc[i][m];
    }
    __syncthreads();

    float* dst = xfp + ((size_t)(blockIdx.x * NB + b)) * 2048;
    float res[8];
    #pragma unroll
    for (int e = 0; e < 8; ++e) {
        int idx = t * 8 + e;
        int ch = idx >> 5, mode = idx & 31;
        int g2 = ch >> 3, i2 = ch & 7;
        int q2 = mode >> 2, m2 = mode & 3;
        int lane2 = g2 * 8 + q2;
        int v2 = i2 * 4 + m2;
        res[e] = u[lane2 * 33 + v2] + u[(64 + lane2) * 33 + v2]
               + u[(128 + lane2) * 33 + v2] + u[(192 + lane2) * 33 + v2];
    }
    float4* d4 = (float4*)(dst + t * 8);
    d4[0] = make_float4(res[0], res[1], res[2], res[3]);
    d4[1] = make_float4(res[4], res[5], res[6], res[7]);
}

// final v4: same compute as v3, but the cross-wave combine is a 2-stage tree
// living inside the dead hS region -> LDS union 25.6KB -> 17.4KB (8 blocks/CU,
// occupancy-capped at 32 waves). Wave 0 ends with the full (s, :) result and
// alone writes tc (64 lanes x 6 dense float4) and out.
__global__ __launch_bounds__(256) void k_final(const float* __restrict__ h,
                                               const float* __restrict__ fc1_w,
                                               const float* __restrict__ fc1_b,
                                               const float* __restrict__ icaT,
                                               const float* __restrict__ ica_b,
                                               float* __restrict__ out,
                                               float* __restrict__ tc) {
    __shared__ float u_lds[4352];          // 17408 B: hS[64][68]; combine reuses [0..3200)
    float (*hS)[68] = (float(*)[68])u_lds;
    int t = threadIdx.x;
    int b = blockIdx.y;
    int s0 = blockIdx.x * 64;
    int lane_s = t & 63;
    int wv = __builtin_amdgcn_readfirstlane(t >> 6);
    int c0 = wv * 32;

    {   // stage transposed: hS[s][ch] = h[ch][s0+s]
        int sl = t & 63, chg = t >> 6;
        const float* hb = h + (size_t)b * WC * SB + s0 + sl;
        #pragma unroll
        for (int cc = 0; cc < 16; ++cc) {
            int ch = chg * 16 + cc;
            hS[sl][ch] = hb[(size_t)ch * SB];
        }
    }
    __syncthreads();

    float acc[NP];
    #pragma unroll
    for (int p = 0; p < NP; ++p) acc[p] = 0.f;

    for (int cq = 0; cq < 8; ++cq) {
        int c = c0 + 4 * cq;
        float tv0 = fc1_b[c], tv1 = fc1_b[c + 1], tv2 = fc1_b[c + 2], tv3 = fc1_b[c + 3];
        const float* w0 = fc1_w + (size_t)c * WC;
        const float* w1 = w0 + WC;
        const float* w2 = w1 + WC;
        const float* w3 = w2 + WC;
        for (int ioct = 0; ioct < 8; ++ioct) {
            float4 xa = *(const float4*)&hS[lane_s][ioct * 8];
            float4 xb = *(const float4*)&hS[lane_s][ioct * 8 + 4];
            float xs[8] = {xa.x, xa.y, xa.z, xa.w, xb.x, xb.y, xb.z, xb.w};
            #pragma unroll
            for (int uu = 0; uu < 8; ++uu) {
                int i = ioct * 8 + uu;
                tv0 = fmaf(w0[i], xs[uu], tv0);
                tv1 = fmaf(w1[i], xs[uu], tv1);
                tv2 = fmaf(w2[i], xs[uu], tv2);
                tv3 = fmaf(w3[i], xs[uu], tv3);
            }
        }
        tv0 = fmaxf(tv0, 0.f); tv1 = fmaxf(tv1, 0.f);
        tv2 = fmaxf(tv2, 0.f); tv3 = fmaxf(tv3, 0.f);
        const float* e0 = icaT + (size_t)c * NP;
        const float* e1 = e0 + NP;
        const float* e2 = e1 + NP;
        const float* e3 = e2 + NP;
        #pragma unroll
        for (int p = 0; p < NP; ++p)
            acc[p] = fmaf(tv0, e0[p], fmaf(tv1, e1[p],
                     fmaf(tv2, e2[p], fmaf(tv3, e3[p], acc[p]))));
    }

    // ---- 2-stage combine in the dead hS region (u_lds[0..3200)) ----
    __syncthreads();                       // hS dead
    if (wv >= 2) {                         // stage 1: waves 2,3 write
        float* slot = u_lds + ((wv - 2) * 64 + lane_s) * 25;
        #pragma unroll
        for (int p = 0; p < NP; ++p) slot[p] = acc[p];
    }
    __syncthreads();
    if (wv < 2) {                          // stage 2: waves 0,1 add partner (wv+2)
        const float* slot = u_lds + (wv * 64 + lane_s) * 25;
        #pragma unroll
        for (int p = 0; p < NP; ++p) acc[p] += slot[p];
    }
    __syncthreads();
    if (wv == 1) {                         // stage 3: wave 1 writes its 2-way sum
        float* slot = u_lds + (64 + lane_s) * 25;
        #pragma unroll
        for (int p = 0; p < NP; ++p) slot[p] = acc[p];
    }
    __syncthreads();
    if (wv == 0) {                         // wave 0: full sum, write tc + out
        const float* slot = u_lds + (64 + lane_s) * 25;
        #pragma unroll
        for (int p = 0; p < NP; ++p) acc[p] += slot[p] + ica_b[p];

        float osum = 0.f;
        #pragma unroll
        for (int p = 0; p < NP; ++p) osum += acc[p];
        size_t idx = (size_t)b * SB + s0 + lane_s;
        out[idx] = osum;

        float4* t4 = (float4*)(tc + idx * NP);   // 96B stride; wave covers 6KB densely
        t4[0] = make_float4(acc[0],  acc[1],  acc[2],  acc[3]);
        t4[1] = make_float4(acc[4],  acc[5],  acc[6],  acc[7]);
        t4[2] = make_float4(acc[8],  acc[9],  acc[10], acc[11]);
        t4[3] = make_float4(acc[12], acc[13], acc[14], acc[15]);
        t4[4] = make_float4(acc[16], acc[17], acc[18], acc[19]);
        t4[5] = make_float4(acc[20], acc[21], acc[22], acc[23]);
    }
}

extern "C" void kernel_launch(void* const* d_in, const int* in_sizes, int n_in,
                              void* d_out, int out_size, void* d_ws, size_t ws_size,
                              hipStream_t stream) {
    const float* x     = (const float*)d_in[0];
    const float* fc0_w = (const float*)d_in[1];
    const float* fc0_b = (const float*)d_in[2];
    const float* cwr   = (const float*)d_in[3];
    const float* cwi   = (const float*)d_in[4];
    const float* pw_w  = (const float*)d_in[5];
    const float* pw_b  = (const float*)d_in[6];
    const float* fc1_w = (const float*)d_in[7];
    const float* fc1_b = (const float*)d_in[8];
    const float* fc2_w = (const float*)d_in[9];
    const float* ica_w = (const float*)d_in[10];
    const float* ica_b = (const float*)d_in[11];

    float* out = (float*)d_out;            // (B,S,1) = 262144
    float* tc  = out + (size_t)NB * SB;    // (B,S,1,24) = 6291456

    float* ws   = (float*)d_ws;
    float* h    = ws;
    float* T    = ws + 16777216;
    float* xf   = ws + 17039360;
    float* ofT  = ws + 17104896;
    float* icaT = ws + 17170432;
    float* pwT  = ws + 17173504;
    float* xfp  = tc;                      // DFT partials scratch (dead until k_final)

    k_table<<<32, 256, 0, stream>>>(T);
    k_prep<<<12, 256, 0, stream>>>(ica_w, fc2_w, icaT);
    k_prepw<<<64, 256, 0, stream>>>(pw_w, pwT);
    k_lift<<<dim3(64, 32), 256, 0, stream>>>(x, fc0_w, fc0_b, h, T, xfp);

    for (int l = 0; l < 4; ++l) {
        k_red<<<256, 256, 0, stream>>>(xfp, xf, 64);
        k_mix<<<128, 256, 0, stream>>>(xf, cwr + (size_t)l * WC * WC * NM,
                                       cwi + (size_t)l * WC * WC * NM, ofT);
        k_update<<<dim3(64, 32), 256, 0, stream>>>(h, T, ofT,
                                                   pwT + (size_t)l * 4096,
                                                   pw_b + (size_t)l * WC,
                                                   (l < 3) ? 1 : 0,
                                                   xfp, (l < 3) ? 1 : 0);
    }

    k_final<<<dim3(128, 32), 256, 0, stream>>>(h, fc1_w, fc1_b, icaT, ica_b, out, tc);
}

// Round 21
// 386.386 us; speedup vs baseline: 1.4746x; 1.0340x over previous
//
#include <hip/hip_runtime.h>
#include <math.h>

#define SB 8192
#define NB 32
#define WC 64
#define NM 16
#define NKC 32   // 2*NM (cos,sin interleaved)
#define NP 24
#define LP 132   // padded LDS row length (128 + 4)

// h layout: h[b][ch][s] (s contiguous)
// ws layout (float offsets):
//   h    : 0         (B*W*S = 16777216)
//   T    : 16777216  (S*32  = 262144)
//   xf   : 17039360  (B*W*32 = 65536)
//   ofT  : 17104896  (B*32*W = 65536)   [j][o] transposed mode weights
//   icaT : 17170432  (128*24 = 3072)
//   pwT  : 17173504  (4*64*64 = 16384)  [l][k][o] transposed pointwise weights
// DFT partials (64 slices x 32 b x 2048) live in the tc output region
// (dead until k_final). All layers produce them fused (lift for l=0,
// update for l=1..3).

__global__ __launch_bounds__(256) void k_table(float* __restrict__ T) {
    int s = blockIdx.x * 256 + threadIdx.x;   // exactly 8192 threads
    float* row = T + (size_t)s * NKC;
    #pragma unroll
    for (int k = 0; k < NM; ++k) {
        int m = (k * s) & (SB - 1);           // exact phase mod S
        double ang = (double)m * (6.283185307179586476925286766559 / (double)SB);
        row[2 * k]     = (float)cos(ang);
        row[2 * k + 1] = (float)sin(ang);
    }
}

// icaT[c][p] = fc2_w[0][c] * ica_w[p][c]
__global__ __launch_bounds__(256) void k_prep(const float* __restrict__ ica_w,
                                              const float* __restrict__ fc2_w,
                                              float* __restrict__ icaT) {
    int tid = blockIdx.x * 256 + threadIdx.x;   // exactly 3072
    int c = tid / NP;
    int p = tid - c * NP;
    icaT[c * NP + p] = ica_w[p * 128 + c] * fc2_w[c];
}

// pwT[l][k][o] = pw_w[l][o][k]
__global__ __launch_bounds__(256) void k_prepw(const float* __restrict__ pw_w,
                                               float* __restrict__ pwT) {
    int tid = blockIdx.x * 256 + threadIdx.x;   // exactly 16384
    int l = tid >> 12, k = (tid >> 6) & 63, o = tid & 63;
    pwT[tid] = pw_w[(size_t)l * 4096 + o * 64 + k];
}

// fused lift + forward DFT of the lifted tile (round-18 form, unchanged).
__global__ __launch_bounds__(256) void k_lift(const float* __restrict__ x,
                                              const float* __restrict__ fc0_w,
                                              const float* __restrict__ fc0_b,
                                              float* __restrict__ h,
                                              const float* __restrict__ T,
                                              float* __restrict__ xfp) {
    __shared__ float u[12544];     // 50176 B: hT2[128][65]=8320 | Tt[32][132]=4224
    int t = threadIdx.x;
    int b = blockIdx.y;
    int s0 = blockIdx.x * 128;
    int sl = t & 127, half = t >> 7;
    int cb = half * 32;

    float2 xv = ((const float2*)x)[(size_t)b * SB + s0 + sl];
    float* hcol = h + (size_t)b * WC * SB + s0 + sl;
    #pragma unroll
    for (int c = 0; c < 32; ++c) {
        int ch = cb + c;
        float v = fmaf(xv.x, fc0_w[2 * ch], fmaf(xv.y, fc0_w[2 * ch + 1], fc0_b[ch]));
        hcol[(size_t)ch * SB] = v;
        u[sl * 65 + ch] = v;
    }
    {   // stage T rows [j][132]: Tt[j][s] = T[s0+s][j]
        int sl2 = t >> 1, jj0 = (t & 1) * 16;
        const float4* src = (const float4*)(T + (size_t)(s0 + sl2) * NKC + jj0);
        float4 a = src[0], c4 = src[1], d = src[2], e = src[3];
        float* Tt = u + 8320;
        Tt[(jj0 +  0) * LP + sl2] = a.x;  Tt[(jj0 +  1) * LP + sl2] = a.y;
        Tt[(jj0 +  2) * LP + sl2] = a.z;  Tt[(jj0 +  3) * LP + sl2] = a.w;
        Tt[(jj0 +  4) * LP + sl2] = c4.x; Tt[(jj0 +  5) * LP + sl2] = c4.y;
        Tt[(jj0 +  6) * LP + sl2] = c4.z; Tt[(jj0 +  7) * LP + sl2] = c4.w;
        Tt[(jj0 +  8) * LP + sl2] = d.x;  Tt[(jj0 +  9) * LP + sl2] = d.y;
        Tt[(jj0 + 10) * LP + sl2] = d.z;  Tt[(jj0 + 11) * LP + sl2] = d.w;
        Tt[(jj0 + 12) * LP + sl2] = e.x;  Tt[(jj0 + 13) * LP + sl2] = e.y;
        Tt[(jj0 + 14) * LP + sl2] = e.z;  Tt[(jj0 + 15) * LP + sl2] = e.w;
    }
    __syncthreads();

    int lane = t & 63;
    int wv = __builtin_amdgcn_readfirstlane(t >> 6);
    int g  = lane >> 3;              // ch-group (ch = g*8+i)
    int j8 = lane & 7;               // mode-quad (mode = j8*4+m)

    float dacc[8][4];
    #pragma unroll
    for (int i = 0; i < 8; ++i)
        #pragma unroll
        for (int m = 0; m < 4; ++m) dacc[i][m] = 0.f;

    #pragma unroll 4
    for (int ss = 0; ss < 32; ++ss) {
        int s = wv * 32 + ss;        // wave-uniform -> broadcast reads
        float tv0 = u[8320 + (j8 * 4 + 0) * LP + s];
        float tv1 = u[8320 + (j8 * 4 + 1) * LP + s];
        float tv2 = u[8320 + (j8 * 4 + 2) * LP + s];
        float tv3 = u[8320 + (j8 * 4 + 3) * LP + s];
        float4 h0 = *(const float4*)&u[s * 65 + g * 8];
        float4 h1 = *(const float4*)&u[s * 65 + g * 8 + 4];
        float hh[8] = {h0.x, h0.y, h0.z, h0.w, h1.x, h1.y, h1.z, h1.w};
        #pragma unroll
        for (int i = 0; i < 8; ++i) {
            dacc[i][0] = fmaf(hh[i], tv0, dacc[i][0]);
            dacc[i][1] = fmaf(hh[i], tv1, dacc[i][1]);
            dacc[i][2] = fmaf(hh[i], tv2, dacc[i][2]);
            dacc[i][3] = fmaf(hh[i], tv3, dacc[i][3]);
        }
    }

    __syncthreads();                 // hT2 + T dead; reduce region u[0..8448)
    {
        float* slot = u + (wv * 64 + lane) * 33;
        #pragma unroll
        for (int i = 0; i < 8; ++i)
            #pragma unroll
            for (int m = 0; m < 4; ++m) slot[i * 4 + m] = dacc[i][m];
    }
    __syncthreads();

    float* dst = xfp + ((size_t)(blockIdx.x * NB + b)) * 2048;
    float res[8];
    #pragma unroll
    for (int e = 0; e < 8; ++e) {
        int idx = t * 8 + e;
        int ch = idx >> 5, mode = idx & 31;
        int g2 = ch >> 3, i2 = ch & 7;
        int q2 = mode >> 2, m2 = mode & 3;
        int lane2 = g2 * 8 + q2;
        int v2 = i2 * 4 + m2;
        res[e] = u[lane2 * 33 + v2] + u[(64 + lane2) * 33 + v2]
               + u[(128 + lane2) * 33 + v2] + u[(192 + lane2) * 33 + v2];
    }
    float4* d4 = (float4*)(dst + t * 8);
    d4[0] = make_float4(res[0], res[1], res[2], res[3]);
    d4[1] = make_float4(res[4], res[5], res[6], res[7]);
}

// reduce K-split partials (nsc slices)
__global__ __launch_bounds__(256) void k_red(const float* __restrict__ xfp,
                                             float* __restrict__ xf, int nsc) {
    int idx = blockIdx.x * 256 + threadIdx.x;   // exactly 65536
    int b = idx >> 11;
    int r = idx & 2047;
    float s = 0.f;
    #pragma unroll 8
    for (int sc = 0; sc < nsc; ++sc)
        s += xfp[((size_t)(sc * NB + b)) * 2048 + r];
    xf[idx] = s;
}

// mode mix: ofT[b][2k][o] = alpha*Re, ofT[b][2k+1][o] = -alpha*Im  (transposed out)
__global__ __launch_bounds__(256) void k_mix(const float* __restrict__ xf,
                                             const float* __restrict__ wr,
                                             const float* __restrict__ wi,
                                             float* __restrict__ ofT) {
    int tid = blockIdx.x * 256 + threadIdx.x;   // exactly 32768
    int k = tid & 15;
    int o = (tid >> 4) & 63;
    int b = tid >> 10;
    float orr = 0.f, oii = 0.f;
    const float2* xfb = (const float2*)(xf + (size_t)b * WC * NKC);
    #pragma unroll 4
    for (int i = 0; i < WC; ++i) {
        float2 cs = xfb[i * NM + k];
        float wrv = wr[(i * WC + o) * NM + k];
        float wiv = wi[(i * WC + o) * NM + k];
        orr = fmaf(cs.x, wrv, fmaf(cs.y, wiv, orr));    // xfr*wr - xfi*wi
        oii = fmaf(cs.x, wiv, fmaf(-cs.y, wrv, oii));   // xfr*wi + xfi*wr
    }
    float alpha = (k == 0 ? 1.f : 2.f) / (float)SB;
    ofT[((size_t)b * NKC + 2 * k) * 64 + o]     = alpha * orr;
    ofT[((size_t)b * NKC + 2 * k + 1) * 64 + o] = -alpha * oii;
}

// fused update (+ forward DFT when dodft) v4: T evicted from LDS.
// Phase-1 T: per-thread global float4 reads (round-9 proven pattern).
// Phase-2 T: per-lane float4 global loads at wave-uniform rows (L1-hot 16KB).
// LDS union = 8448 floats (33792 B): phase1 hS[64][132] | phase2 hT2[128][65]
// | reduce [256][33] (exact fit). 50.7 -> 33.8 KB => 3 -> 4 blocks/CU (+33%
// waves to hide the scalar weight-stream latency).
__global__ __launch_bounds__(256) void k_update(float* __restrict__ h,
                                                const float* __restrict__ T,
                                                const float* __restrict__ ofT,
                                                const float* __restrict__ pwT,
                                                const float* __restrict__ pwb,
                                                int relu, float* __restrict__ xfp,
                                                int dodft) {
    __shared__ float u[8448];      // 33792 B
    float (*hS)[LP] = (float(*)[LP])u;
    int t = threadIdx.x;
    int b = blockIdx.y;
    int s0 = blockIdx.x * 128;
    int lane_s = t & 63;
    int g4 = __builtin_amdgcn_readfirstlane((t >> 6) & 3);
    int ob = g4 * 16;

    {   // stage h[64 ch][128 s]: 4 threads/row, 8 interleaved b128 each
        int ch = t >> 2, part = t & 3;
        const float* hrow = h + ((size_t)(b * WC + ch)) * SB + s0;
        #pragma unroll
        for (int r = 0; r < 8; ++r) {
            int so = (part + 4 * r) * 4;
            *(float4*)&hS[ch][so] = *(const float4*)(hrow + so);
        }
    }
    __syncthreads();

    float acc0[16], acc1[16];
    #pragma unroll
    for (int o = 0; o < 16; ++o) { acc0[o] = pwb[ob + o]; acc1[o] = pwb[ob + o]; }

    const float* wbase0 = pwT + ob;                       // [k][64]
    const float* wbase1 = ofT + ((size_t)b * NKC) * 64 + ob;  // [j][64]

    for (int kc = 0; kc < 8; ++kc) {        // pointwise: k = 0..63
        #pragma unroll
        for (int uu = 0; uu < 8; ++uu) {
            int k = kc * 8 + uu;
            float h0 = hS[k][lane_s];
            float h1 = hS[k][64 + lane_s];
            const float* w = wbase0 + k * 64;
            #pragma unroll
            for (int o = 0; o < 16; ++o) {
                acc0[o] = fmaf(w[o], h0, acc0[o]);
                acc1[o] = fmaf(w[o], h1, acc1[o]);
            }
        }
    }
    // inverse-DFT: T from global (per-thread rows, L2-resident)
    const float4* Trow0 = (const float4*)(T + (size_t)(s0 + lane_s) * NKC);
    const float4* Trow1 = (const float4*)(T + (size_t)(s0 + 64 + lane_s) * NKC);
    for (int kc = 0; kc < 4; ++kc) {
        float4 v0 = Trow0[kc * 2], v1 = Trow0[kc * 2 + 1];
        float4 w0 = Trow1[kc * 2], w1v = Trow1[kc * 2 + 1];
        float xs0[8] = {v0.x, v0.y, v0.z, v0.w, v1.x, v1.y, v1.z, v1.w};
        float xs1[8] = {w0.x, w0.y, w0.z, w0.w, w1v.x, w1v.y, w1v.z, w1v.w};
        #pragma unroll
        for (int uu = 0; uu < 8; ++uu) {
            int j = kc * 8 + uu;
            const float* w = wbase1 + j * 64;
            #pragma unroll
            for (int o = 0; o < 16; ++o) {
                acc0[o] = fmaf(w[o], xs0[uu], acc0[o]);
                acc1[o] = fmaf(w[o], xs1[uu], acc1[o]);
            }
        }
    }

    if (relu) {
        #pragma unroll
        for (int o = 0; o < 16; ++o) {
            acc0[o] = fmaxf(acc0[o], 0.f);
            acc1[o] = fmaxf(acc1[o], 0.f);
        }
    }

    float* hw0 = h + (size_t)b * WC * SB + s0 + lane_s;
    float* hw1 = hw0 + 64;
    #pragma unroll
    for (int o = 0; o < 16; ++o) {
        hw0[(size_t)(ob + o) * SB] = acc0[o];
        hw1[(size_t)(ob + o) * SB] = acc1[o];
    }

    if (!dodft) return;

    // ---- fused forward DFT of the output tile ----
    __syncthreads();                 // all reads of hS done
    #pragma unroll
    for (int o = 0; o < 16; ++o) {
        u[lane_s * 65 + ob + o]        = acc0[o];
        u[(64 + lane_s) * 65 + ob + o] = acc1[o];
    }
    __syncthreads();

    int lane = t & 63;
    int wv = __builtin_amdgcn_readfirstlane(t >> 6);
    int g  = lane >> 3;
    int j8 = lane & 7;

    float dacc[8][4];
    #pragma unroll
    for (int i = 0; i < 8; ++i)
        #pragma unroll
        for (int m = 0; m < 4; ++m) dacc[i][m] = 0.f;

    #pragma unroll 4
    for (int ss = 0; ss < 32; ++ss) {
        int s = wv * 32 + ss;        // wave-uniform row; 8 lanes span 128B (L1-hot)
        float4 tv = *(const float4*)(T + (size_t)(s0 + s) * NKC + j8 * 4);
        float4 h0 = *(const float4*)&u[s * 65 + g * 8];
        float4 h1 = *(const float4*)&u[s * 65 + g * 8 + 4];
        float hh[8] = {h0.x, h0.y, h0.z, h0.w, h1.x, h1.y, h1.z, h1.w};
        #pragma unroll
        for (int i = 0; i < 8; ++i) {
            dacc[i][0] = fmaf(hh[i], tv.x, dacc[i][0]);
            dacc[i][1] = fmaf(hh[i], tv.y, dacc[i][1]);
            dacc[i][2] = fmaf(hh[i], tv.z, dacc[i][2]);
            dacc[i][3] = fmaf(hh[i], tv.w, dacc[i][3]);
        }
    }

    __syncthreads();                 // hT2 dead; reduce region u[0..8448)
    {
        float* slot = u + (wv * 64 + lane) * 33;
        #pragma unroll
        for (int i = 0; i < 8; ++i)
            #pragma unroll
            for (int m = 0; m < 4; ++m) slot[i * 4 + m] = dacc[i][m];
    }
    __syncthreads();

    float* dst = xfp + ((size_t)(blockIdx.x * NB + b)) * 2048;
    float res[8];
    #pragma unroll
    for (int e = 0; e < 8; ++e) {
        int idx = t * 8 + e;
        int ch = idx >> 5, mode = idx & 31;
        int g2 = ch >> 3, i2 = ch & 7;
        int q2 = mode >> 2, m2 = mode & 3;
        int lane2 = g2 * 8 + q2;
        int v2 = i2 * 4 + m2;
        res[e] = u[lane2 * 33 + v2] + u[(64 + lane2) * 33 + v2]
               + u[(128 + lane2) * 33 + v2] + u[(192 + lane2) * 33 + v2];
    }
    float4* d4 = (float4*)(dst + t * 8);
    d4[0] = make_float4(res[0], res[1], res[2], res[3]);
    d4[1] = make_float4(res[4], res[5], res[6], res[7]);
}

// final v4 (round-20 form, kept): 17.4 KB LDS, 2-stage tree combine.
__global__ __launch_bounds__(256) void k_final(const float* __restrict__ h,
                                               const float* __restrict__ fc1_w,
                                               const float* __restrict__ fc1_b,
                                               const float* __restrict__ icaT,
                                               const float* __restrict__ ica_b,
                                               float* __restrict__ out,
                                               float* __restrict__ tc) {
    __shared__ float u_lds[4352];          // 17408 B: hS[64][68]; combine reuses [0..3200)
    float (*hS)[68] = (float(*)[68])u_lds;
    int t = threadIdx.x;
    int b = blockIdx.y;
    int s0 = blockIdx.x * 64;
    int lane_s = t & 63;
    int wv = __builtin_amdgcn_readfirstlane(t >> 6);
    int c0 = wv * 32;

    {   // stage transposed: hS[s][ch] = h[ch][s0+s]
        int sl = t & 63, chg = t >> 6;
        const float* hb = h + (size_t)b * WC * SB + s0 + sl;
        #pragma unroll
        for (int cc = 0; cc < 16; ++cc) {
            int ch = chg * 16 + cc;
            hS[sl][ch] = hb[(size_t)ch * SB];
        }
    }
    __syncthreads();

    float acc[NP];
    #pragma unroll
    for (int p = 0; p < NP; ++p) acc[p] = 0.f;

    for (int cq = 0; cq < 8; ++cq) {
        int c = c0 + 4 * cq;
        float tv0 = fc1_b[c], tv1 = fc1_b[c + 1], tv2 = fc1_b[c + 2], tv3 = fc1_b[c + 3];
        const float* w0 = fc1_w + (size_t)c * WC;
        const float* w1 = w0 + WC;
        const float* w2 = w1 + WC;
        const float* w3 = w2 + WC;
        for (int ioct = 0; ioct < 8; ++ioct) {
            float4 xa = *(const float4*)&hS[lane_s][ioct * 8];
            float4 xb = *(const float4*)&hS[lane_s][ioct * 8 + 4];
            float xs[8] = {xa.x, xa.y, xa.z, xa.w, xb.x, xb.y, xb.z, xb.w};
            #pragma unroll
            for (int uu = 0; uu < 8; ++uu) {
                int i = ioct * 8 + uu;
                tv0 = fmaf(w0[i], xs[uu], tv0);
                tv1 = fmaf(w1[i], xs[uu], tv1);
                tv2 = fmaf(w2[i], xs[uu], tv2);
                tv3 = fmaf(w3[i], xs[uu], tv3);
            }
        }
        tv0 = fmaxf(tv0, 0.f); tv1 = fmaxf(tv1, 0.f);
        tv2 = fmaxf(tv2, 0.f); tv3 = fmaxf(tv3, 0.f);
        const float* e0 = icaT + (size_t)c * NP;
        const float* e1 = e0 + NP;
        const float* e2 = e1 + NP;
        const float* e3 = e2 + NP;
        #pragma unroll
        for (int p = 0; p < NP; ++p)
            acc[p] = fmaf(tv0, e0[p], fmaf(tv1, e1[p],
                     fmaf(tv2, e2[p], fmaf(tv3, e3[p], acc[p]))));
    }

    // ---- 2-stage combine in the dead hS region (u_lds[0..3200)) ----
    __syncthreads();                       // hS dead
    if (wv >= 2) {                         // stage 1: waves 2,3 write
        float* slot = u_lds + ((wv - 2) * 64 + lane_s) * 25;
        #pragma unroll
        for (int p = 0; p < NP; ++p) slot[p] = acc[p];
    }
    __syncthreads();
    if (wv < 2) {                          // stage 2: waves 0,1 add partner (wv+2)
        const float* slot = u_lds + (wv * 64 + lane_s) * 25;
        #pragma unroll
        for (int p = 0; p < NP; ++p) acc[p] += slot[p];
    }
    __syncthreads();
    if (wv == 1) {                         // stage 3: wave 1 writes its 2-way sum
        float* slot = u_lds + (64 + lane_s) * 25;
        #pragma unroll
        for (int p = 0; p < NP; ++p) slot[p] = acc[p];
    }
    __syncthreads();
    if (wv == 0) {                         // wave 0: full sum, write tc + out
        const float* slot = u_lds + (64 + lane_s) * 25;
        #pragma unroll
        for (int p = 0; p < NP; ++p) acc[p] += slot[p] + ica_b[p];

        float osum = 0.f;
        #pragma unroll
        for (int p = 0; p < NP; ++p) osum += acc[p];
        size_t idx = (size_t)b * SB + s0 + lane_s;
        out[idx] = osum;

        float4* t4 = (float4*)(tc + idx * NP);   // 96B stride; wave covers 6KB densely
        t4[0] = make_float4(acc[0],  acc[1],  acc[2],  acc[3]);
        t4[1] = make_float4(acc[4],  acc[5],  acc[6],  acc[7]);
        t4[2] = make_float4(acc[8],  acc[9],  acc[10], acc[11]);
        t4[3] = make_float4(acc[12], acc[13], acc[14], acc[15]);
        t4[4] = make_float4(acc[16], acc[17], acc[18], acc[19]);
        t4[5] = make_float4(acc[20], acc[21], acc[22], acc[23]);
    }
}

extern "C" void kernel_launch(void* const* d_in, const int* in_sizes, int n_in,
                              void* d_out, int out_size, void* d_ws, size_t ws_size,
                              hipStream_t stream) {
    const float* x     = (const float*)d_in[0];
    const float* fc0_w = (const float*)d_in[1];
    const float* fc0_b = (const float*)d_in[2];
    const float* cwr   = (const float*)d_in[3];
    const float* cwi   = (const float*)d_in[4];
    const float* pw_w  = (const float*)d_in[5];
    const float* pw_b  = (const float*)d_in[6];
    const float* fc1_w = (const float*)d_in[7];
    const float* fc1_b = (const float*)d_in[8];
    const float* fc2_w = (const float*)d_in[9];
    const float* ica_w = (const float*)d_in[10];
    const float* ica_b = (const float*)d_in[11];

    float* out = (float*)d_out;            // (B,S,1) = 262144
    float* tc  = out + (size_t)NB * SB;    // (B,S,1,24) = 6291456

    float* ws   = (float*)d_ws;
    float* h    = ws;
    float* T    = ws + 16777216;
    float* xf   = ws + 17039360;
    float* ofT  = ws + 17104896;
    float* icaT = ws + 17170432;
    float* pwT  = ws + 17173504;
    float* xfp  = tc;                      // DFT partials scratch (dead until k_final)

    k_table<<<32, 256, 0, stream>>>(T);
    k_prep<<<12, 256, 0, stream>>>(ica_w, fc2_w, icaT);
    k_prepw<<<64, 256, 0, stream>>>(pw_w, pwT);
    k_lift<<<dim3(64, 32), 256, 0, stream>>>(x, fc0_w, fc0_b, h, T, xfp);

    for (int l = 0; l < 4; ++l) {
        k_red<<<256, 256, 0, stream>>>(xfp, xf, 64);
        k_mix<<<128, 256, 0, stream>>>(xf, cwr + (size_t)l * WC * WC * NM,
                                       cwi + (size_t)l * WC * WC * NM, ofT);
        k_update<<<dim3(64, 32), 256, 0, stream>>>(h, T, ofT,
                                                   pwT + (size_t)l * 4096,
                                                   pw_b + (size_t)l * WC,
                                                   (l < 3) ? 1 : 0,
                                                   xfp, (l < 3) ? 1 : 0);
    }

    k_final<<<dim3(128, 32), 256, 0, stream>>>(h, fc1_w, fc1_b, icaT, ica_b, out, tc);
}